// Round 5
// baseline (731.587 us; speedup 1.0000x reference)
//
#include <hip/hip_runtime.h>
#include <hip/hip_fp16.h>

#define N_NODES 100000
#define N_EDGES 3200000
#define N_GRAPHS 1024
#define F_IN 4
#define H 16

#define NB 256       // dst buckets
#define NPB 391      // nodes per bucket (256*391 = 100096 >= 100000)
#define CHUNK 4096   // edges per block in k_bucket
#define EPT 16       // edges per thread in k_bucket

// ---------------- tiny utility kernels ----------------

__global__ void k_zero_f(float* __restrict__ p, int n) {
    int i = blockIdx.x * blockDim.x + threadIdx.x;
    if (i < n) p[i] = 0.0f;
}

__global__ void k_zero_i(int* __restrict__ p, int n) {
    int i = blockIdx.x * blockDim.x + threadIdx.x;
    if (i < n) p[i] = 0;
}

// ---------------- bucketed edge partition ----------------

__global__ void k_hist(const int* __restrict__ dst, int* __restrict__ bucketCnt, int e) {
    __shared__ int h[NB];
    for (int t = threadIdx.x; t < NB; t += blockDim.x) h[t] = 0;
    __syncthreads();
    for (int i = blockIdx.x * blockDim.x + threadIdx.x; i < e; i += gridDim.x * blockDim.x)
        atomicAdd(&h[dst[i] / NPB], 1);
    __syncthreads();
    for (int t = threadIdx.x; t < NB; t += blockDim.x) {
        int c = h[t];
        if (c) atomicAdd(&bucketCnt[t], c);
    }
}

// exclusive scan of NB bucket counts; one block of NB threads
__global__ void k_scan_buckets(const int* __restrict__ bucketCnt,
                               int* __restrict__ bucketBase,
                               int* __restrict__ bucketCursor) {
    __shared__ int sh[NB];
    int t = threadIdx.x;
    int v = bucketCnt[t];
    sh[t] = v;
    __syncthreads();
    for (int off = 1; off < NB; off <<= 1) {
        int x = (t >= off) ? sh[t - off] : 0;
        __syncthreads();
        sh[t] += x;
        __syncthreads();
    }
    int base = sh[t] - v;
    bucketBase[t] = base;
    bucketCursor[t] = base;
}

// payload packed: (local_dst << 20) | src   (local_dst < 391 -> 9 bits, src < 2^20)
__global__ void k_bucket(const int* __restrict__ src, const int* __restrict__ dst,
                         int* __restrict__ bucketCursor, int* __restrict__ ebuf, int e) {
    __shared__ int cnt[NB];
    __shared__ int lbase[NB];
    int t = threadIdx.x;
    for (int q = t; q < NB; q += blockDim.x) cnt[q] = 0;
    __syncthreads();
    int e0 = blockIdx.x * CHUNK;
    int vq[EPT], bq[EPT], rq[EPT];
#pragma unroll
    for (int q = 0; q < EPT; ++q) {
        int ei = e0 + t + q * 256;
        bq[q] = -1;
        if (ei < e) {
            int s = src[ei];
            int d = dst[ei];
            int b = d / NPB;
            int l = d - b * NPB;
            vq[q] = s | (l << 20);
            bq[q] = b;
            rq[q] = atomicAdd(&cnt[b], 1);
        }
    }
    __syncthreads();
    for (int q = t; q < NB; q += blockDim.x) {
        int c = cnt[q];
        lbase[q] = c ? atomicAdd(&bucketCursor[q], c) : 0;
    }
    __syncthreads();
#pragma unroll
    for (int q = 0; q < EPT; ++q)
        if (bq[q] >= 0) ebuf[lbase[bq[q]] + rq[q]] = vq[q];
}

// ---------------- per-bucket degree -> dinv, and ts0 = half(dinv*x) ----------------

__global__ void k_dinvb(const int* __restrict__ ebuf, const int* __restrict__ bucketBase,
                        const int* __restrict__ bucketCnt, const float* __restrict__ x,
                        float* __restrict__ dinv, __half* __restrict__ ts0) {
    __shared__ int cnt[NPB];
    __shared__ float sdinv[NPB];
    int t = threadIdx.x;
    int b = blockIdx.x;
    for (int q = t; q < NPB; q += 256) cnt[q] = 0;
    __syncthreads();
    int base = bucketBase[b];
    int m = bucketCnt[b];
    for (int idx = t; idx < m; idx += 256)
        atomicAdd(&cnt[ebuf[base + idx] >> 20], 1);
    __syncthreads();
    int nbase = b * NPB;
    for (int q = t; q < NPB; q += 256) {
        int node = nbase + q;
        if (node < N_NODES) {
            float dv = rsqrtf((float)cnt[q] + 1.0f);
            dinv[node] = dv;
            sdinv[q] = dv;
        }
    }
    __syncthreads();
    for (int idx = t; idx < NPB * F_IN; idx += 256) {
        int q = idx / F_IN;
        int node = nbase + q;
        if (node < N_NODES)
            ts0[node * F_IN + (idx % F_IN)] =
                __float2half(sdinv[q] * x[node * F_IN + (idx % F_IN)]);
    }
}

// ---------------- fused layer: LDS gather + transform (+ pool) ----------------
// One block per bucket. acc[l][k] = ts_in[self] + sum over in-edges of ts_in[src];
// then h = relu(dinv_i*acc @ W + b); non-pool: ts_out = half(dinv_i*h); pool: g += h.
template <int F, bool POOL>
__global__ __launch_bounds__(1024) void k_layer(
        const __half* __restrict__ ts_in, const float* __restrict__ dinv,
        const int* __restrict__ ebuf, const int* __restrict__ bucketBase,
        const int* __restrict__ bucketCnt, const float* __restrict__ W,
        const float* __restrict__ bias, __half* __restrict__ ts_out,
        const int* __restrict__ batch, float* __restrict__ g) {
    __shared__ float acc[NPB * F];
    __shared__ float sW[F * H];
    int t = threadIdx.x;
    int b = blockIdx.x;
    int nbase = b * NPB;
    if (t < F * H) sW[t] = W[t];
    // init with self-loop term
    for (int idx = t; idx < NPB * F; idx += 1024) {
        int node = nbase + idx / F;
        float v = 0.0f;
        if (node < N_NODES) v = __half2float(ts_in[nbase * F + idx]);
        acc[idx] = v;
    }
    __syncthreads();
    int base = bucketBase[b];
    int m = bucketCnt[b];
    int k = t & (F - 1);
    const int stp = 1024 / F;
    int j = t / F;
    for (; j + 3 * stp < m; j += 4 * stp) {
        int v0 = ebuf[base + j];
        int v1 = ebuf[base + j + stp];
        int v2 = ebuf[base + j + 2 * stp];
        int v3 = ebuf[base + j + 3 * stp];
        float f0 = __half2float(ts_in[(v0 & 0xFFFFF) * F + k]);
        float f1 = __half2float(ts_in[(v1 & 0xFFFFF) * F + k]);
        float f2 = __half2float(ts_in[(v2 & 0xFFFFF) * F + k]);
        float f3 = __half2float(ts_in[(v3 & 0xFFFFF) * F + k]);
        atomicAdd(&acc[(v0 >> 20) * F + k], f0);
        atomicAdd(&acc[(v1 >> 20) * F + k], f1);
        atomicAdd(&acc[(v2 >> 20) * F + k], f2);
        atomicAdd(&acc[(v3 >> 20) * F + k], f3);
    }
    for (; j < m; j += stp) {
        int v = ebuf[base + j];
        float f = __half2float(ts_in[(v & 0xFFFFF) * F + k]);
        atomicAdd(&acc[(v >> 20) * F + k], f);
    }
    __syncthreads();
    // transform: 16 lanes per node
    for (int idx = t; idx < NPB * H; idx += 1024) {
        int l = idx >> 4;
        int node = nbase + l;
        if (node >= N_NODES) continue;
        int ko = idx & 15;
        float dv = dinv[node];
        float a = bias[ko];
#pragma unroll
        for (int jj = 0; jj < F; jj++) a = fmaf(dv * acc[l * F + jj], sW[jj * H + ko], a);
        float h = fmaxf(a, 0.0f);
        if (POOL) {
            atomicAdd(&g[batch[node] * H + ko], h);
        } else {
            ts_out[node * H + ko] = __float2half(dv * h);
        }
    }
}

// ---------------- final MLP ----------------

__global__ void k_mlp(const float* __restrict__ g, const float* __restrict__ y,
                      const float* __restrict__ fcW1, const float* __restrict__ fcb1,
                      const float* __restrict__ fcW2, const float* __restrict__ fcb2,
                      const float* __restrict__ fcW3, const float* __restrict__ fcb3,
                      float* __restrict__ out, int ngraph) {
    int i = blockIdx.x * blockDim.x + threadIdx.x;
    if (i >= ngraph) return;
    float in[H + 4];
#pragma unroll
    for (int k = 0; k < H; k++) in[k] = g[i * H + k];
#pragma unroll
    for (int k = 0; k < 4; k++) in[H + k] = y[i * 4 + k];
    float z1[H];
#pragma unroll
    for (int o = 0; o < H; o++) {
        float a = fcb1[o];
#pragma unroll
        for (int j = 0; j < H + 4; j++) a += in[j] * fcW1[j * H + o];
        z1[o] = fmaxf(a, 0.0f);
    }
    float z2[H];
#pragma unroll
    for (int o = 0; o < H; o++) {
        float a = fcb2[o];
#pragma unroll
        for (int j = 0; j < H; j++) a += z1[j] * fcW2[j * H + o];
        z2[o] = fmaxf(a, 0.0f);
    }
    float a = fcb3[0];
#pragma unroll
    for (int j = 0; j < H; j++) a += z2[j] * fcW3[j];
    out[i] = a;
}

// ---------------- launch ----------------

extern "C" void kernel_launch(void* const* d_in, const int* in_sizes, int n_in,
                              void* d_out, int out_size, void* d_ws, size_t ws_size,
                              hipStream_t stream) {
    const float* x    = (const float*)d_in[0];
    const int*   ei   = (const int*)d_in[1];   // [2, E]: src then dst
    const float* y    = (const float*)d_in[2];
    const int*   bat  = (const int*)d_in[3];
    const float* W1   = (const float*)d_in[4];
    const float* b1   = (const float*)d_in[5];
    const float* W2   = (const float*)d_in[6];
    const float* b2   = (const float*)d_in[7];
    const float* W3   = (const float*)d_in[8];
    const float* b3   = (const float*)d_in[9];
    const float* fcW1 = (const float*)d_in[10];
    const float* fcb1 = (const float*)d_in[11];
    const float* fcW2 = (const float*)d_in[12];
    const float* fcb2 = (const float*)d_in[13];
    const float* fcW3 = (const float*)d_in[14];
    const float* fcb3 = (const float*)d_in[15];
    float* out = (float*)d_out;

    const int* src = ei;
    const int* dst = ei + N_EDGES;

    const int B = 256;
    const int GH = N_GRAPHS * H;

    // ---- workspace layout ----
    char* w = (char*)d_ws;
    size_t off = 0;
    int*    bucketCnt    = (int*)(w + off);    off += (size_t)NB * 4;
    int*    bucketBase   = (int*)(w + off);    off += (size_t)NB * 4;
    int*    bucketCursor = (int*)(w + off);    off += (size_t)NB * 4;
    float*  dinv         = (float*)(w + off);  off += (size_t)N_NODES * 4;
    int*    ebuf         = (int*)(w + off);    off += (size_t)N_EDGES * 4;
    __half* ts0          = (__half*)(w + off); off += (size_t)N_NODES * F_IN * 2;
    __half* ts1          = (__half*)(w + off); off += (size_t)N_NODES * H * 2;
    __half* ts2          = (__half*)(w + off); off += (size_t)N_NODES * H * 2;
    float*  g            = (float*)(w + off);  off += (size_t)GH * 4;
    (void)ws_size;

    // ---- build ----
    k_zero_i<<<1, NB, 0, stream>>>(bucketCnt, NB);
    k_hist<<<256, B, 0, stream>>>(dst, bucketCnt, N_EDGES);
    k_scan_buckets<<<1, NB, 0, stream>>>(bucketCnt, bucketBase, bucketCursor);
    k_bucket<<<(N_EDGES + CHUNK - 1) / CHUNK, B, 0, stream>>>(src, dst, bucketCursor,
                                                              ebuf, N_EDGES);
    k_dinvb<<<NB, B, 0, stream>>>(ebuf, bucketBase, bucketCnt, x, dinv, ts0);

    // ---- fused layers ----
    k_layer<F_IN, false><<<NB, 1024, 0, stream>>>(ts0, dinv, ebuf, bucketBase, bucketCnt,
                                                  W1, b1, ts1, nullptr, nullptr);
    k_layer<H, false><<<NB, 1024, 0, stream>>>(ts1, dinv, ebuf, bucketBase, bucketCnt,
                                               W2, b2, ts2, nullptr, nullptr);
    k_zero_f<<<(GH + B - 1) / B, B, 0, stream>>>(g, GH);
    k_layer<H, true><<<NB, 1024, 0, stream>>>(ts2, dinv, ebuf, bucketBase, bucketCnt,
                                              W3, b3, nullptr, bat, g);

    // ---- final MLP ----
    k_mlp<<<(N_GRAPHS + B - 1) / B, B, 0, stream>>>(g, y, fcW1, fcb1, fcW2, fcb2,
                                                    fcW3, fcb3, out, N_GRAPHS);
}

// Round 6
// 244.905 us; speedup vs baseline: 2.9872x; 2.9872x over previous
//
#include <hip/hip_runtime.h>
#include <hip/hip_fp16.h>

#define N_NODES 100000
#define N_EDGES 3200000
#define N_GRAPHS 1024
#define F_IN 4
#define H 16

#define NB 256       // dst buckets
#define NPB 391      // nodes per bucket (256*391 = 100096 >= 100000)
#define CAP 13312    // per-bucket LDS fast-path capacity (mean 12512, sigma ~111)
#define CHUNK 16384  // edges per block in k_bucket

// ---------------- tiny utility kernels ----------------

__global__ void k_zero_f(float* __restrict__ p, int n) {
    int i = blockIdx.x * blockDim.x + threadIdx.x;
    if (i < n) p[i] = 0.0f;
}

__global__ void k_zero_i(int* __restrict__ p, int n) {
    int i = blockIdx.x * blockDim.x + threadIdx.x;
    if (i < n) p[i] = 0;
}

// ---------------- bucketed edge partition ----------------

__global__ void k_hist(const int* __restrict__ dst, int* __restrict__ bucketCnt, int e) {
    __shared__ int h[NB];
    for (int t = threadIdx.x; t < NB; t += blockDim.x) h[t] = 0;
    __syncthreads();
    for (int i = blockIdx.x * blockDim.x + threadIdx.x; i < e; i += gridDim.x * blockDim.x)
        atomicAdd(&h[dst[i] / NPB], 1);
    __syncthreads();
    for (int t = threadIdx.x; t < NB; t += blockDim.x) {
        int c = h[t];
        if (c) atomicAdd(&bucketCnt[t], c);
    }
}

// exclusive scan of NB bucket counts; one block of NB threads
__global__ void k_scan_buckets(const int* __restrict__ bucketCnt,
                               int* __restrict__ bucketBase,
                               int* __restrict__ bucketCursor) {
    __shared__ int sh[NB];
    int t = threadIdx.x;
    int v = bucketCnt[t];
    sh[t] = v;
    __syncthreads();
    for (int off = 1; off < NB; off <<= 1) {
        int x = (t >= off) ? sh[t - off] : 0;
        __syncthreads();
        sh[t] += x;
        __syncthreads();
    }
    int base = sh[t] - v;
    bucketBase[t] = base;
    bucketCursor[t] = base;
}

// two-pass per-chunk distribute: count -> reserve runs -> place.
// payload packed: (local_dst << 20) | src   (local_dst < 391, src < 2^20)
__global__ __launch_bounds__(512) void k_bucket(const int* __restrict__ src,
                                                const int* __restrict__ dst,
                                                int* __restrict__ bucketCursor,
                                                int* __restrict__ ebuf, int e) {
    __shared__ int cnt[NB];
    __shared__ int lbase[NB];
    int t = threadIdx.x;
    for (int q = t; q < NB; q += 512) cnt[q] = 0;
    __syncthreads();
    int e0 = blockIdx.x * CHUNK;
    int e1 = min(e0 + CHUNK, e);
    for (int i = e0 + t; i < e1; i += 512)
        atomicAdd(&cnt[dst[i] / NPB], 1);
    __syncthreads();
    for (int q = t; q < NB; q += 512) {
        int c = cnt[q];
        lbase[q] = c ? atomicAdd(&bucketCursor[q], c) : 0;
    }
    __syncthreads();
    for (int q = t; q < NB; q += 512) cnt[q] = 0;
    __syncthreads();
    for (int i = e0 + t; i < e1; i += 512) {
        int s = src[i];
        int d = dst[i];
        int b = d / NPB;
        int l = d - b * NPB;
        int r = atomicAdd(&cnt[b], 1);
        ebuf[lbase[b] + r] = s | (l << 20);
    }
}

// one block per bucket: group by node, emit coalesced CSR + cursor + dinv
__global__ __launch_bounds__(512) void k_csrify(const int* __restrict__ ebuf,
                                                const int* __restrict__ bucketBase,
                                                const int* __restrict__ bucketCnt,
                                                int* __restrict__ csr,
                                                int* __restrict__ cursor,
                                                float* __restrict__ dinv) {
    __shared__ int cnt[NPB];
    __shared__ int st[NPB];
    __shared__ int cnt2[NPB];
    __shared__ int sc[512];
    __shared__ int lcsr[CAP];
    int t = threadIdx.x;
    int b = blockIdx.x;
    int base = bucketBase[b];
    int m = bucketCnt[b];
    int nbase = b * NPB;
    for (int q = t; q < NPB; q += 512) { cnt[q] = 0; cnt2[q] = 0; }
    __syncthreads();
    // pass 1: per-node count
    for (int i = t; i < m; i += 512)
        atomicAdd(&cnt[ebuf[base + i] >> 20], 1);
    __syncthreads();
    // scan (NPB <= 512): Hillis-Steele over 512 threads
    int v0 = (t < NPB) ? cnt[t] : 0;
    sc[t] = v0;
    __syncthreads();
    for (int off = 1; off < 512; off <<= 1) {
        int x = (t >= off) ? sc[t - off] : 0;
        __syncthreads();
        sc[t] += x;
        __syncthreads();
    }
    if (t < NPB) st[t] = sc[t] - v0;
    __syncthreads();
    if (t < NPB) {
        int node = nbase + t;
        if (node < N_NODES) {
            dinv[node] = rsqrtf((float)cnt[t] + 1.0f);
            cursor[node] = base + st[t] + cnt[t];
        }
    }
    // pass 2: place
    if (m <= CAP) {
        for (int i = t; i < m; i += 512) {
            int v = ebuf[base + i];
            int l = v >> 20;
            int r = atomicAdd(&cnt2[l], 1);
            lcsr[st[l] + r] = v & 0xFFFFF;
        }
        __syncthreads();
        for (int i = t; i < m; i += 512) csr[base + i] = lcsr[i];
    } else {
        // capacity-proof slow path (scattered global writes)
        for (int i = t; i < m; i += 512) {
            int v = ebuf[base + i];
            int l = v >> 20;
            int r = atomicAdd(&cnt2[l], 1);
            csr[base + st[l] + r] = v & 0xFFFFF;
        }
    }
}

// ---------------- prescale: ts0 = half(dinv[i] * x[i,k]) ----------------

__global__ void k_prescale(const float* __restrict__ x, const float* __restrict__ dinv,
                           __half* __restrict__ ts, int n4) {
    int t = blockIdx.x * blockDim.x + threadIdx.x;
    if (t < n4) ts[t] = __float2half(dinv[t >> 2] * x[t]);
}

// ---------------- CSR gather over pre-scaled fp16 features ----------------
// 2*F lanes per node: two halves walk alternate edges, recombined by shfl.
// agg[i,k] = dinv[i] * (ts[i,k] + sum_{s in N(i)} ts[s,k])
template <int F>
__global__ void k_gather(const __half* __restrict__ ts, const float* __restrict__ dinv,
                         const int* __restrict__ csr, const int* __restrict__ cursor,
                         float* __restrict__ agg, int n) {
    const int L = 2 * F;
    int i = blockIdx.x * (256 / L) + threadIdx.x / L;
    int lane = threadIdx.x % L;
    int k = lane % F;
    int h = lane / F;
    if (i >= n) return;
    int start = (i == 0) ? 0 : cursor[i - 1];
    int end = cursor[i];
    float a0 = 0.0f, a1 = 0.0f, a2 = 0.0f, a3 = 0.0f;
    int j = start + h;
    for (; j + 6 < end; j += 8) {
        int s0 = csr[j];
        int s1 = csr[j + 2];
        int s2 = csr[j + 4];
        int s3 = csr[j + 6];
        a0 += __half2float(ts[s0 * F + k]);
        a1 += __half2float(ts[s1 * F + k]);
        a2 += __half2float(ts[s2 * F + k]);
        a3 += __half2float(ts[s3 * F + k]);
    }
    for (; j < end; j += 2) a0 += __half2float(ts[csr[j] * F + k]);
    if (h == 0) a0 += __half2float(ts[i * F + k]);   // self-loop term
    float sum = (a0 + a1) + (a2 + a3);
    sum += __shfl_xor(sum, F, 64);                   // combine the two halves
    if (h == 0) agg[i * F + k] = dinv[i] * sum;
}

// ---------------- per-node transform: h = relu(agg @ W + b) ----------------
// 16 lanes per node. Non-pool: ts_out = half(dinv*h). Pool: g[batch[i]] += h.
template <int FI, bool POOL>
__global__ void k_transform(const float* __restrict__ agg, const float* __restrict__ W,
                            const float* __restrict__ bias, const float* __restrict__ dinv,
                            __half* __restrict__ ts_out, const int* __restrict__ batch,
                            float* __restrict__ g, int n) {
    __shared__ float sW[FI * H];
    for (int t = threadIdx.x; t < FI * H; t += blockDim.x) sW[t] = W[t];
    __syncthreads();
    int i = blockIdx.x * 16 + (threadIdx.x >> 4);
    int k = threadIdx.x & 15;
    if (i >= n) return;
    float acc = bias[k];
#pragma unroll
    for (int j = 0; j < FI; j++) acc = fmaf(agg[i * FI + j], sW[j * H + k], acc);
    float h = fmaxf(acc, 0.0f);
    if (POOL) {
        atomicAdd(&g[batch[i] * H + k], h);
    } else {
        ts_out[i * H + k] = __float2half(dinv[i] * h);
    }
}

// ---------------- final MLP ----------------

__global__ void k_mlp(const float* __restrict__ g, const float* __restrict__ y,
                      const float* __restrict__ fcW1, const float* __restrict__ fcb1,
                      const float* __restrict__ fcW2, const float* __restrict__ fcb2,
                      const float* __restrict__ fcW3, const float* __restrict__ fcb3,
                      float* __restrict__ out, int ngraph) {
    int i = blockIdx.x * blockDim.x + threadIdx.x;
    if (i >= ngraph) return;
    float in[H + 4];
#pragma unroll
    for (int k = 0; k < H; k++) in[k] = g[i * H + k];
#pragma unroll
    for (int k = 0; k < 4; k++) in[H + k] = y[i * 4 + k];
    float z1[H];
#pragma unroll
    for (int o = 0; o < H; o++) {
        float a = fcb1[o];
#pragma unroll
        for (int j = 0; j < H + 4; j++) a += in[j] * fcW1[j * H + o];
        z1[o] = fmaxf(a, 0.0f);
    }
    float z2[H];
#pragma unroll
    for (int o = 0; o < H; o++) {
        float a = fcb2[o];
#pragma unroll
        for (int j = 0; j < H; j++) a += z1[j] * fcW2[j * H + o];
        z2[o] = fmaxf(a, 0.0f);
    }
    float a = fcb3[0];
#pragma unroll
    for (int j = 0; j < H; j++) a += z2[j] * fcW3[j];
    out[i] = a;
}

// ---------------- launch ----------------

extern "C" void kernel_launch(void* const* d_in, const int* in_sizes, int n_in,
                              void* d_out, int out_size, void* d_ws, size_t ws_size,
                              hipStream_t stream) {
    const float* x    = (const float*)d_in[0];
    const int*   ei   = (const int*)d_in[1];   // [2, E]: src then dst
    const float* y    = (const float*)d_in[2];
    const int*   bat  = (const int*)d_in[3];
    const float* W1   = (const float*)d_in[4];
    const float* b1   = (const float*)d_in[5];
    const float* W2   = (const float*)d_in[6];
    const float* b2   = (const float*)d_in[7];
    const float* W3   = (const float*)d_in[8];
    const float* b3   = (const float*)d_in[9];
    const float* fcW1 = (const float*)d_in[10];
    const float* fcb1 = (const float*)d_in[11];
    const float* fcW2 = (const float*)d_in[12];
    const float* fcb2 = (const float*)d_in[13];
    const float* fcW3 = (const float*)d_in[14];
    const float* fcb3 = (const float*)d_in[15];
    float* out = (float*)d_out;

    const int* src = ei;
    const int* dst = ei + N_EDGES;

    const int B = 256;
    const int GH = N_GRAPHS * H;
    const int gNode16 = (N_NODES + 15) / 16;   // 16 lanes/node transform
    const int gGather4 = (N_NODES + 31) / 32;  // F=4 gather: 8 lanes/node, 32 nodes/blk
    const int gGather16 = (N_NODES + 7) / 8;   // F=16 gather: 32 lanes/node, 8 nodes/blk
    const int N4 = N_NODES * F_IN;

    // ---- workspace layout ----
    char* w = (char*)d_ws;
    size_t off = 0;
    int*    bucketCnt    = (int*)(w + off);    off += (size_t)NB * 4;
    int*    bucketBase   = (int*)(w + off);    off += (size_t)NB * 4;
    int*    bucketCursor = (int*)(w + off);    off += (size_t)NB * 4;
    int*    cursor       = (int*)(w + off);    off += (size_t)N_NODES * 4;
    float*  dinv         = (float*)(w + off);  off += (size_t)N_NODES * 4;
    int*    ebuf         = (int*)(w + off);    off += (size_t)N_EDGES * 4;
    int*    csr          = (int*)(w + off);    off += (size_t)N_EDGES * 4;
    __half* ts0          = (__half*)(w + off); off += (size_t)N4 * 2;
    __half* ts1          = (__half*)(w + off); off += (size_t)N_NODES * H * 2;
    __half* ts2          = (__half*)(w + off); off += (size_t)N_NODES * H * 2;
    float*  agg          = (float*)(w + off);  off += (size_t)N_NODES * H * 4;
    float*  g            = (float*)(w + off);  off += (size_t)GH * 4;
    (void)ws_size;

    // ---- build ----
    k_zero_i<<<1, NB, 0, stream>>>(bucketCnt, NB);
    k_hist<<<256, B, 0, stream>>>(dst, bucketCnt, N_EDGES);
    k_scan_buckets<<<1, NB, 0, stream>>>(bucketCnt, bucketBase, bucketCursor);
    k_bucket<<<(N_EDGES + CHUNK - 1) / CHUNK, 512, 0, stream>>>(src, dst, bucketCursor,
                                                                ebuf, N_EDGES);
    k_csrify<<<NB, 512, 0, stream>>>(ebuf, bucketBase, bucketCnt, csr, cursor, dinv);

    // ---- layer 1: gather raw x (4 features), then transform 4->16 ----
    k_prescale<<<(N4 + B - 1) / B, B, 0, stream>>>(x, dinv, ts0, N4);
    k_gather<F_IN><<<gGather4, B, 0, stream>>>(ts0, dinv, csr, cursor, agg, N_NODES);
    k_transform<F_IN, false><<<gNode16, B, 0, stream>>>(agg, W1, b1, dinv, ts1,
                                                        nullptr, nullptr, N_NODES);
    // ---- layer 2 ----
    k_gather<H><<<gGather16, B, 0, stream>>>(ts1, dinv, csr, cursor, agg, N_NODES);
    k_transform<H, false><<<gNode16, B, 0, stream>>>(agg, W2, b2, dinv, ts2,
                                                     nullptr, nullptr, N_NODES);
    // ---- layer 3 + fused pool ----
    k_gather<H><<<gGather16, B, 0, stream>>>(ts2, dinv, csr, cursor, agg, N_NODES);
    k_zero_f<<<(GH + B - 1) / B, B, 0, stream>>>(g, GH);
    k_transform<H, true><<<gNode16, B, 0, stream>>>(agg, W3, b3, dinv, nullptr,
                                                    bat, g, N_NODES);

    // ---- final MLP ----
    k_mlp<<<(N_GRAPHS + B - 1) / B, B, 0, stream>>>(g, y, fcW1, fcb1, fcW2, fcb2,
                                                    fcW3, fcb3, out, N_GRAPHS);
}

// Round 7
// 233.951 us; speedup vs baseline: 3.1271x; 1.0468x over previous
//
#include <hip/hip_runtime.h>
#include <hip/hip_fp16.h>

#define N_NODES 100000
#define N_EDGES 3200000
#define N_GRAPHS 1024
#define F_IN 4
#define H 16

#define NB 256       // dst buckets
#define NPB 391      // nodes per bucket (256*391 = 100096 >= 100000)
#define CAP 13312    // per-bucket LDS fast-path capacity (mean 12512, sigma ~112)
#define CHUNK 4096   // edges per block in k_bucket

// ---------------- tiny utility kernels ----------------

__global__ void k_zero_f(float* __restrict__ p, int n) {
    int i = blockIdx.x * blockDim.x + threadIdx.x;
    if (i < n) p[i] = 0.0f;
}

__global__ void k_zero_i(int* __restrict__ p, int n) {
    int i = blockIdx.x * blockDim.x + threadIdx.x;
    if (i < n) p[i] = 0;
}

// ---------------- bucketed edge partition ----------------

__global__ void k_hist(const int* __restrict__ dst, int* __restrict__ bucketCnt, int e) {
    __shared__ int h[NB];
    for (int t = threadIdx.x; t < NB; t += blockDim.x) h[t] = 0;
    __syncthreads();
    for (int i = blockIdx.x * blockDim.x + threadIdx.x; i < e; i += gridDim.x * blockDim.x)
        atomicAdd(&h[dst[i] / NPB], 1);
    __syncthreads();
    for (int t = threadIdx.x; t < NB; t += blockDim.x) {
        int c = h[t];
        if (c) atomicAdd(&bucketCnt[t], c);
    }
}

// exclusive scan of NB bucket counts; one block of NB threads
__global__ void k_scan_buckets(const int* __restrict__ bucketCnt,
                               int* __restrict__ bucketBase,
                               int* __restrict__ bucketCursor) {
    __shared__ int sh[NB];
    int t = threadIdx.x;
    int v = bucketCnt[t];
    sh[t] = v;
    __syncthreads();
    for (int off = 1; off < NB; off <<= 1) {
        int x = (t >= off) ? sh[t - off] : 0;
        __syncthreads();
        sh[t] += x;
        __syncthreads();
    }
    int base = sh[t] - v;
    bucketBase[t] = base;
    bucketCursor[t] = base;
}

// two-pass per-chunk distribute: count -> reserve runs -> place.
// payload packed: (local_dst << 20) | src   (local_dst < 391, src < 2^20)
__global__ __launch_bounds__(512) void k_bucket(const int* __restrict__ src,
                                                const int* __restrict__ dst,
                                                int* __restrict__ bucketCursor,
                                                int* __restrict__ ebuf, int e) {
    __shared__ int cnt[NB];
    __shared__ int lbase[NB];
    int t = threadIdx.x;
    for (int q = t; q < NB; q += 512) cnt[q] = 0;
    __syncthreads();
    int e0 = blockIdx.x * CHUNK;
    int e1 = min(e0 + CHUNK, e);
    for (int i = e0 + t; i < e1; i += 512)
        atomicAdd(&cnt[dst[i] / NPB], 1);
    __syncthreads();
    for (int q = t; q < NB; q += 512) {
        int c = cnt[q];
        lbase[q] = c ? atomicAdd(&bucketCursor[q], c) : 0;
    }
    __syncthreads();
    for (int q = t; q < NB; q += 512) cnt[q] = 0;
    __syncthreads();
    for (int i = e0 + t; i < e1; i += 512) {
        int s = src[i];
        int d = dst[i];
        int b = d / NPB;
        int l = d - b * NPB;
        int r = atomicAdd(&cnt[b], 1);
        ebuf[lbase[b] + r] = s | (l << 20);
    }
}

// one block per bucket: group by node -> coalesced CSR + cursor + dinv + ts0
__global__ __launch_bounds__(1024) void k_csrify(const int* __restrict__ ebuf,
                                                 const int* __restrict__ bucketBase,
                                                 const int* __restrict__ bucketCnt,
                                                 const float* __restrict__ x,
                                                 int* __restrict__ csr,
                                                 int* __restrict__ cursor,
                                                 float* __restrict__ dinv,
                                                 __half* __restrict__ ts0) {
    __shared__ int cnt[NPB];
    __shared__ int st[NPB];
    __shared__ int cnt2[NPB];
    __shared__ float sdv[NPB];
    __shared__ int sc[1024];
    __shared__ int lcsr[CAP];
    int t = threadIdx.x;
    int b = blockIdx.x;
    int base = bucketBase[b];
    int m = bucketCnt[b];
    int nbase = b * NPB;
    for (int q = t; q < NPB; q += 1024) { cnt[q] = 0; cnt2[q] = 0; }
    __syncthreads();
    // pass 1: per-node count
    for (int i = t; i < m; i += 1024)
        atomicAdd(&cnt[ebuf[base + i] >> 20], 1);
    __syncthreads();
    // scan (NPB <= 1024): Hillis-Steele
    int v0 = (t < NPB) ? cnt[t] : 0;
    sc[t] = v0;
    __syncthreads();
    for (int off = 1; off < 1024; off <<= 1) {
        int xv = (t >= off) ? sc[t - off] : 0;
        __syncthreads();
        sc[t] += xv;
        __syncthreads();
    }
    if (t < NPB) st[t] = sc[t] - v0;
    __syncthreads();
    if (t < NPB) {
        int node = nbase + t;
        if (node < N_NODES) {
            float dv = rsqrtf((float)cnt[t] + 1.0f);
            sdv[t] = dv;
            dinv[node] = dv;
            cursor[node] = base + st[t] + cnt[t];
        }
    }
    __syncthreads();
    // prescale layer-1 input: ts0 = half(dinv * x)
    for (int idx = t; idx < NPB * F_IN; idx += 1024) {
        int q = idx >> 2;
        int node = nbase + q;
        if (node < N_NODES)
            ts0[node * F_IN + (idx & 3)] =
                __float2half(sdv[q] * x[node * F_IN + (idx & 3)]);
    }
    // pass 2: place
    if (m <= CAP) {
        for (int i = t; i < m; i += 1024) {
            int v = ebuf[base + i];
            int l = v >> 20;
            int r = atomicAdd(&cnt2[l], 1);
            lcsr[st[l] + r] = v & 0xFFFFF;
        }
        __syncthreads();
        for (int i = t; i < m; i += 1024) csr[base + i] = lcsr[i];
    } else {
        // capacity-proof slow path (scattered global writes)
        for (int i = t; i < m; i += 1024) {
            int v = ebuf[base + i];
            int l = v >> 20;
            int r = atomicAdd(&cnt2[l], 1);
            csr[base + st[l] + r] = v & 0xFFFFF;
        }
    }
}

// ---------------- fused layer: CSR gather + shfl transform (+ pool) ----------------
// 2*F lanes per node: two halves walk alternate edges; after shfl-combine the
// node's F agg values live (replicated) in its lane group; transform via shfl.
template <int F, bool POOL>
__global__ void k_fused(const __half* __restrict__ ts_in, const float* __restrict__ dinv,
                        const int* __restrict__ csr, const int* __restrict__ cursor,
                        const float* __restrict__ W, const float* __restrict__ bias,
                        __half* __restrict__ ts_out, const int* __restrict__ batch,
                        float* __restrict__ g, int n) {
    __shared__ float sW[F * H];
    for (int t = threadIdx.x; t < F * H; t += blockDim.x) sW[t] = W[t];
    __syncthreads();
    const int L = 2 * F;
    int i = blockIdx.x * (256 / L) + threadIdx.x / L;
    int lane = threadIdx.x & 63;
    int sub = threadIdx.x % L;
    int k = sub % F;
    int h = sub / F;
    if (i >= n) return;
    int start = (i == 0) ? 0 : cursor[i - 1];
    int end = cursor[i];
    float a0 = 0.0f, a1 = 0.0f, a2 = 0.0f, a3 = 0.0f;
    int j = start + h;
    for (; j + 6 < end; j += 8) {
        int s0 = csr[j];
        int s1 = csr[j + 2];
        int s2 = csr[j + 4];
        int s3 = csr[j + 6];
        a0 += __half2float(ts_in[s0 * F + k]);
        a1 += __half2float(ts_in[s1 * F + k]);
        a2 += __half2float(ts_in[s2 * F + k]);
        a3 += __half2float(ts_in[s3 * F + k]);
    }
    for (; j < end; j += 2) a0 += __half2float(ts_in[csr[j] * F + k]);
    if (h == 0) a0 += __half2float(ts_in[i * F + k]);   // self-loop term
    float sum = (a0 + a1) + (a2 + a3);
    sum += __shfl_xor(sum, F, 64);                      // combine halves
    float dv = dinv[i];
    float agg = dv * sum;
    int base = lane & ~(L - 1);                         // node's first wave lane
    if (F == 16) {
        float a = bias[k];
#pragma unroll
        for (int jj = 0; jj < 16; jj++)
            a = fmaf(__shfl(agg, base + jj, 64), sW[jj * H + k], a);
        float hv = fmaxf(a, 0.0f);
        if (h == 0) {
            if (POOL) {
                atomicAdd(&g[batch[i] * H + k], hv);
            } else {
                ts_out[i * H + k] = __float2half(dv * hv);
            }
        }
    } else {  // F == 4, L == 8: each lane emits outputs sub and sub+8
        float aj[F];
#pragma unroll
        for (int jj = 0; jj < F; jj++) aj[jj] = __shfl(agg, base + jj, 64);
#pragma unroll
        for (int half = 0; half < 2; half++) {
            int ko = sub + 8 * half;
            float a = bias[ko];
#pragma unroll
            for (int jj = 0; jj < F; jj++) a = fmaf(aj[jj], sW[jj * H + ko], a);
            float hv = fmaxf(a, 0.0f);
            ts_out[i * H + ko] = __float2half(dv * hv);
        }
    }
}

// ---------------- final MLP ----------------

__global__ void k_mlp(const float* __restrict__ g, const float* __restrict__ y,
                      const float* __restrict__ fcW1, const float* __restrict__ fcb1,
                      const float* __restrict__ fcW2, const float* __restrict__ fcb2,
                      const float* __restrict__ fcW3, const float* __restrict__ fcb3,
                      float* __restrict__ out, int ngraph) {
    int i = blockIdx.x * blockDim.x + threadIdx.x;
    if (i >= ngraph) return;
    float in[H + 4];
#pragma unroll
    for (int k = 0; k < H; k++) in[k] = g[i * H + k];
#pragma unroll
    for (int k = 0; k < 4; k++) in[H + k] = y[i * 4 + k];
    float z1[H];
#pragma unroll
    for (int o = 0; o < H; o++) {
        float a = fcb1[o];
#pragma unroll
        for (int j = 0; j < H + 4; j++) a += in[j] * fcW1[j * H + o];
        z1[o] = fmaxf(a, 0.0f);
    }
    float z2[H];
#pragma unroll
    for (int o = 0; o < H; o++) {
        float a = fcb2[o];
#pragma unroll
        for (int j = 0; j < H; j++) a += z1[j] * fcW2[j * H + o];
        z2[o] = fmaxf(a, 0.0f);
    }
    float a = fcb3[0];
#pragma unroll
    for (int j = 0; j < H; j++) a += z2[j] * fcW3[j];
    out[i] = a;
}

// ---------------- launch ----------------

extern "C" void kernel_launch(void* const* d_in, const int* in_sizes, int n_in,
                              void* d_out, int out_size, void* d_ws, size_t ws_size,
                              hipStream_t stream) {
    const float* x    = (const float*)d_in[0];
    const int*   ei   = (const int*)d_in[1];   // [2, E]: src then dst
    const float* y    = (const float*)d_in[2];
    const int*   bat  = (const int*)d_in[3];
    const float* W1   = (const float*)d_in[4];
    const float* b1   = (const float*)d_in[5];
    const float* W2   = (const float*)d_in[6];
    const float* b2   = (const float*)d_in[7];
    const float* W3   = (const float*)d_in[8];
    const float* b3   = (const float*)d_in[9];
    const float* fcW1 = (const float*)d_in[10];
    const float* fcb1 = (const float*)d_in[11];
    const float* fcW2 = (const float*)d_in[12];
    const float* fcb2 = (const float*)d_in[13];
    const float* fcW3 = (const float*)d_in[14];
    const float* fcb3 = (const float*)d_in[15];
    float* out = (float*)d_out;

    const int* src = ei;
    const int* dst = ei + N_EDGES;

    const int B = 256;
    const int GH = N_GRAPHS * H;
    const int gF4  = (N_NODES * 8 + B - 1) / B;    // F=4: 8 lanes/node
    const int gF16 = (N_NODES * 32 + B - 1) / B;   // F=16: 32 lanes/node

    // ---- workspace layout ----
    char* w = (char*)d_ws;
    size_t off = 0;
    int*    bucketCnt    = (int*)(w + off);    off += (size_t)NB * 4;
    int*    bucketBase   = (int*)(w + off);    off += (size_t)NB * 4;
    int*    bucketCursor = (int*)(w + off);    off += (size_t)NB * 4;
    int*    cursor       = (int*)(w + off);    off += (size_t)N_NODES * 4;
    float*  dinv         = (float*)(w + off);  off += (size_t)N_NODES * 4;
    int*    ebuf         = (int*)(w + off);    off += (size_t)N_EDGES * 4;
    int*    csr          = (int*)(w + off);    off += (size_t)N_EDGES * 4;
    __half* ts0          = (__half*)(w + off); off += (size_t)N_NODES * F_IN * 2;
    __half* ts1          = (__half*)(w + off); off += (size_t)N_NODES * H * 2;
    __half* ts2          = (__half*)(w + off); off += (size_t)N_NODES * H * 2;
    float*  g            = (float*)(w + off);  off += (size_t)GH * 4;
    (void)ws_size;

    // ---- build ----
    k_zero_i<<<1, NB, 0, stream>>>(bucketCnt, NB);
    k_hist<<<512, B, 0, stream>>>(dst, bucketCnt, N_EDGES);
    k_scan_buckets<<<1, NB, 0, stream>>>(bucketCnt, bucketBase, bucketCursor);
    k_bucket<<<(N_EDGES + CHUNK - 1) / CHUNK, 512, 0, stream>>>(src, dst, bucketCursor,
                                                                ebuf, N_EDGES);
    k_csrify<<<NB, 1024, 0, stream>>>(ebuf, bucketBase, bucketCnt, x, csr, cursor,
                                      dinv, ts0);

    // ---- fused layers ----
    k_fused<F_IN, false><<<gF4, B, 0, stream>>>(ts0, dinv, csr, cursor, W1, b1, ts1,
                                                nullptr, nullptr, N_NODES);
    k_fused<H, false><<<gF16, B, 0, stream>>>(ts1, dinv, csr, cursor, W2, b2, ts2,
                                              nullptr, nullptr, N_NODES);
    k_zero_f<<<(GH + B - 1) / B, B, 0, stream>>>(g, GH);
    k_fused<H, true><<<gF16, B, 0, stream>>>(ts2, dinv, csr, cursor, W3, b3, nullptr,
                                             bat, g, N_NODES);

    // ---- final MLP ----
    k_mlp<<<(N_GRAPHS + B - 1) / B, B, 0, stream>>>(g, y, fcW1, fcb1, fcW2, fcb2,
                                                    fcW3, fcb3, out, N_GRAPHS);
}

// Round 8
// 233.241 us; speedup vs baseline: 3.1366x; 1.0030x over previous
//
#include <hip/hip_runtime.h>
#include <hip/hip_fp16.h>

#define N_NODES 100000
#define N_EDGES 3200000
#define N_GRAPHS 1024
#define F_IN 4
#define H 16

#define NB 256       // dst buckets
#define NPB 391      // nodes per bucket (256*391 = 100096 >= 100000)
#define CAP 13312    // per-bucket LDS fast-path capacity (mean 12512, sigma ~112)
#define CHUNK 4096   // edges per block in k_bucket

// ---------------- tiny utility kernels ----------------

__global__ void k_zero_f(float* __restrict__ p, int n) {
    int i = blockIdx.x * blockDim.x + threadIdx.x;
    if (i < n) p[i] = 0.0f;
}

__global__ void k_zero_i(int* __restrict__ p, int n) {
    int i = blockIdx.x * blockDim.x + threadIdx.x;
    if (i < n) p[i] = 0;
}

// ---------------- bucketed edge partition ----------------

__global__ void k_hist(const int* __restrict__ dst, int* __restrict__ bucketCnt, int e) {
    __shared__ int h[NB];
    for (int t = threadIdx.x; t < NB; t += blockDim.x) h[t] = 0;
    __syncthreads();
    for (int i = blockIdx.x * blockDim.x + threadIdx.x; i < e; i += gridDim.x * blockDim.x)
        atomicAdd(&h[dst[i] / NPB], 1);
    __syncthreads();
    for (int t = threadIdx.x; t < NB; t += blockDim.x) {
        int c = h[t];
        if (c) atomicAdd(&bucketCnt[t], c);
    }
}

// exclusive scan of NB bucket counts; one block of NB threads
__global__ void k_scan_buckets(const int* __restrict__ bucketCnt,
                               int* __restrict__ bucketBase,
                               int* __restrict__ bucketCursor) {
    __shared__ int sh[NB];
    int t = threadIdx.x;
    int v = bucketCnt[t];
    sh[t] = v;
    __syncthreads();
    for (int off = 1; off < NB; off <<= 1) {
        int x = (t >= off) ? sh[t - off] : 0;
        __syncthreads();
        sh[t] += x;
        __syncthreads();
    }
    int base = sh[t] - v;
    bucketBase[t] = base;
    bucketCursor[t] = base;
}

// two-pass per-chunk distribute: count -> reserve runs -> place.
// payload packed: (local_dst << 20) | src   (local_dst < 391, src < 2^20)
__global__ __launch_bounds__(512) void k_bucket(const int* __restrict__ src,
                                                const int* __restrict__ dst,
                                                int* __restrict__ bucketCursor,
                                                int* __restrict__ ebuf, int e) {
    __shared__ int cnt[NB];
    __shared__ int lbase[NB];
    int t = threadIdx.x;
    for (int q = t; q < NB; q += 512) cnt[q] = 0;
    __syncthreads();
    int e0 = blockIdx.x * CHUNK;
    int e1 = min(e0 + CHUNK, e);
    for (int i = e0 + t; i < e1; i += 512)
        atomicAdd(&cnt[dst[i] / NPB], 1);
    __syncthreads();
    for (int q = t; q < NB; q += 512) {
        int c = cnt[q];
        lbase[q] = c ? atomicAdd(&bucketCursor[q], c) : 0;
    }
    __syncthreads();
    for (int q = t; q < NB; q += 512) cnt[q] = 0;
    __syncthreads();
    for (int i = e0 + t; i < e1; i += 512) {
        int s = src[i];
        int d = dst[i];
        int b = d / NPB;
        int l = d - b * NPB;
        int r = atomicAdd(&cnt[b], 1);
        ebuf[lbase[b] + r] = s | (l << 20);
    }
}

// one block per bucket: group by node -> coalesced CSR + cursor + dinv + ts0
__global__ __launch_bounds__(1024) void k_csrify(const int* __restrict__ ebuf,
                                                 const int* __restrict__ bucketBase,
                                                 const int* __restrict__ bucketCnt,
                                                 const float* __restrict__ x,
                                                 int* __restrict__ csr,
                                                 int* __restrict__ cursor,
                                                 float* __restrict__ dinv,
                                                 __half* __restrict__ ts0) {
    __shared__ int cnt[NPB];
    __shared__ int st[NPB];
    __shared__ int cnt2[NPB];
    __shared__ float sdv[NPB];
    __shared__ int sc[1024];
    __shared__ int lcsr[CAP];
    int t = threadIdx.x;
    int b = blockIdx.x;
    int base = bucketBase[b];
    int m = bucketCnt[b];
    int nbase = b * NPB;
    for (int q = t; q < NPB; q += 1024) { cnt[q] = 0; cnt2[q] = 0; }
    __syncthreads();
    // pass 1: per-node count
    for (int i = t; i < m; i += 1024)
        atomicAdd(&cnt[ebuf[base + i] >> 20], 1);
    __syncthreads();
    // scan (NPB <= 1024): Hillis-Steele
    int v0 = (t < NPB) ? cnt[t] : 0;
    sc[t] = v0;
    __syncthreads();
    for (int off = 1; off < 1024; off <<= 1) {
        int xv = (t >= off) ? sc[t - off] : 0;
        __syncthreads();
        sc[t] += xv;
        __syncthreads();
    }
    if (t < NPB) st[t] = sc[t] - v0;
    __syncthreads();
    if (t < NPB) {
        int node = nbase + t;
        if (node < N_NODES) {
            float dv = rsqrtf((float)cnt[t] + 1.0f);
            sdv[t] = dv;
            dinv[node] = dv;
            cursor[node] = base + st[t] + cnt[t];
        }
    }
    __syncthreads();
    // prescale layer-1 input: ts0 = half(dinv * x)
    for (int idx = t; idx < NPB * F_IN; idx += 1024) {
        int q = idx >> 2;
        int node = nbase + q;
        if (node < N_NODES)
            ts0[node * F_IN + (idx & 3)] =
                __float2half(sdv[q] * x[node * F_IN + (idx & 3)]);
    }
    // pass 2: place
    if (m <= CAP) {
        for (int i = t; i < m; i += 1024) {
            int v = ebuf[base + i];
            int l = v >> 20;
            int r = atomicAdd(&cnt2[l], 1);
            lcsr[st[l] + r] = v & 0xFFFFF;
        }
        __syncthreads();
        for (int i = t; i < m; i += 1024) csr[base + i] = lcsr[i];
    } else {
        // capacity-proof slow path (scattered global writes)
        for (int i = t; i < m; i += 1024) {
            int v = ebuf[base + i];
            int l = v >> 20;
            int r = atomicAdd(&cnt2[l], 1);
            csr[base + st[l] + r] = v & 0xFFFFF;
        }
    }
}

// ---------------- CSR gather, half2 loads, WAYS-way edge split ----------------
// Lane group per node: (F/2) feature-pair lanes x WAYS edge ways.
// agg[i,:] = dinv[i] * (ts[i,:] + sum_{s in N(i)} ts[s,:])
template <int F, int WAYS>
__global__ void k_gather(const __half* __restrict__ ts, const float* __restrict__ dinv,
                         const int* __restrict__ csr, const int* __restrict__ cursor,
                         float* __restrict__ agg, int n) {
    const int FP = F / 2;            // feature pairs
    const int L = FP * WAYS;         // lanes per node
    int i = blockIdx.x * (256 / L) + threadIdx.x / L;
    int g = threadIdx.x % L;
    int k2 = g % FP;                 // feature-pair index
    int w = g / FP;                  // edge way
    if (i >= n) return;
    int start = (i == 0) ? 0 : cursor[i - 1];
    int end = cursor[i];
    float ax0 = 0.f, ay0 = 0.f, ax1 = 0.f, ay1 = 0.f;
    int j = start + w;
    for (; j + 3 * WAYS < end; j += 4 * WAYS) {
        int s0 = csr[j];
        int s1 = csr[j + WAYS];
        int s2 = csr[j + 2 * WAYS];
        int s3 = csr[j + 3 * WAYS];
        float2 f0 = __half22float2(*(const __half2*)&ts[s0 * F + 2 * k2]);
        float2 f1 = __half22float2(*(const __half2*)&ts[s1 * F + 2 * k2]);
        float2 f2 = __half22float2(*(const __half2*)&ts[s2 * F + 2 * k2]);
        float2 f3 = __half22float2(*(const __half2*)&ts[s3 * F + 2 * k2]);
        ax0 += f0.x + f2.x; ay0 += f0.y + f2.y;
        ax1 += f1.x + f3.x; ay1 += f1.y + f3.y;
    }
    for (; j < end; j += WAYS) {
        float2 f = __half22float2(*(const __half2*)&ts[csr[j] * F + 2 * k2]);
        ax0 += f.x; ay0 += f.y;
    }
    float sx = ax0 + ax1;
    float sy = ay0 + ay1;
    if (w == 0) {  // self-loop term
        float2 f = __half22float2(*(const __half2*)&ts[i * F + 2 * k2]);
        sx += f.x; sy += f.y;
    }
#pragma unroll
    for (int msk = FP; msk < L; msk <<= 1) {
        sx += __shfl_xor(sx, msk, 64);
        sy += __shfl_xor(sy, msk, 64);
    }
    if (w == 0) {
        float dv = dinv[i];
        *(float2*)&agg[i * F + 2 * k2] = make_float2(dv * sx, dv * sy);
    }
}

// ---------------- per-node transform: h = relu(agg @ W + b) ----------------
// 16 lanes per node. Non-pool: ts_out = half(dinv*h). Pool: g[batch[i]] += h.
template <int FI, bool POOL>
__global__ void k_transform(const float* __restrict__ agg, const float* __restrict__ W,
                            const float* __restrict__ bias, const float* __restrict__ dinv,
                            __half* __restrict__ ts_out, const int* __restrict__ batch,
                            float* __restrict__ g, int n) {
    __shared__ float sW[FI * H];
    for (int t = threadIdx.x; t < FI * H; t += blockDim.x) sW[t] = W[t];
    __syncthreads();
    int i = blockIdx.x * 16 + (threadIdx.x >> 4);
    int k = threadIdx.x & 15;
    if (i >= n) return;
    float acc = bias[k];
#pragma unroll
    for (int j = 0; j < FI; j++) acc = fmaf(agg[i * FI + j], sW[j * H + k], acc);
    float h = fmaxf(acc, 0.0f);
    if (POOL) {
        atomicAdd(&g[batch[i] * H + k], h);
    } else {
        ts_out[i * H + k] = __float2half(dinv[i] * h);
    }
}

// ---------------- final MLP ----------------

__global__ void k_mlp(const float* __restrict__ g, const float* __restrict__ y,
                      const float* __restrict__ fcW1, const float* __restrict__ fcb1,
                      const float* __restrict__ fcW2, const float* __restrict__ fcb2,
                      const float* __restrict__ fcW3, const float* __restrict__ fcb3,
                      float* __restrict__ out, int ngraph) {
    int i = blockIdx.x * blockDim.x + threadIdx.x;
    if (i >= ngraph) return;
    float in[H + 4];
#pragma unroll
    for (int k = 0; k < H; k++) in[k] = g[i * H + k];
#pragma unroll
    for (int k = 0; k < 4; k++) in[H + k] = y[i * 4 + k];
    float z1[H];
#pragma unroll
    for (int o = 0; o < H; o++) {
        float a = fcb1[o];
#pragma unroll
        for (int j = 0; j < H + 4; j++) a += in[j] * fcW1[j * H + o];
        z1[o] = fmaxf(a, 0.0f);
    }
    float z2[H];
#pragma unroll
    for (int o = 0; o < H; o++) {
        float a = fcb2[o];
#pragma unroll
        for (int j = 0; j < H; j++) a += z1[j] * fcW2[j * H + o];
        z2[o] = fmaxf(a, 0.0f);
    }
    float a = fcb3[0];
#pragma unroll
    for (int j = 0; j < H; j++) a += z2[j] * fcW3[j];
    out[i] = a;
}

// ---------------- launch ----------------

extern "C" void kernel_launch(void* const* d_in, const int* in_sizes, int n_in,
                              void* d_out, int out_size, void* d_ws, size_t ws_size,
                              hipStream_t stream) {
    const float* x    = (const float*)d_in[0];
    const int*   ei   = (const int*)d_in[1];   // [2, E]: src then dst
    const float* y    = (const float*)d_in[2];
    const int*   bat  = (const int*)d_in[3];
    const float* W1   = (const float*)d_in[4];
    const float* b1   = (const float*)d_in[5];
    const float* W2   = (const float*)d_in[6];
    const float* b2   = (const float*)d_in[7];
    const float* W3   = (const float*)d_in[8];
    const float* b3   = (const float*)d_in[9];
    const float* fcW1 = (const float*)d_in[10];
    const float* fcb1 = (const float*)d_in[11];
    const float* fcW2 = (const float*)d_in[12];
    const float* fcb2 = (const float*)d_in[13];
    const float* fcW3 = (const float*)d_in[14];
    const float* fcb3 = (const float*)d_in[15];
    float* out = (float*)d_out;

    const int* src = ei;
    const int* dst = ei + N_EDGES;

    const int B = 256;
    const int GH = N_GRAPHS * H;
    const int gNode16 = (N_NODES + 15) / 16;        // transform: 16 nodes/block
    const int gG4  = (N_NODES + 15) / 16;           // F=4,W=8: L=16, 16 nodes/block
    const int gG16 = (N_NODES + 7) / 8;             // F=16,W=4: L=32, 8 nodes/block

    // ---- workspace layout ----
    char* w = (char*)d_ws;
    size_t off = 0;
    int*    bucketCnt    = (int*)(w + off);    off += (size_t)NB * 4;
    int*    bucketBase   = (int*)(w + off);    off += (size_t)NB * 4;
    int*    bucketCursor = (int*)(w + off);    off += (size_t)NB * 4;
    int*    cursor       = (int*)(w + off);    off += (size_t)N_NODES * 4;
    float*  dinv         = (float*)(w + off);  off += (size_t)N_NODES * 4;
    int*    ebuf         = (int*)(w + off);    off += (size_t)N_EDGES * 4;
    int*    csr          = (int*)(w + off);    off += (size_t)N_EDGES * 4;
    __half* ts0          = (__half*)(w + off); off += (size_t)N_NODES * F_IN * 2;
    __half* ts1          = (__half*)(w + off); off += (size_t)N_NODES * H * 2;
    __half* ts2          = (__half*)(w + off); off += (size_t)N_NODES * H * 2;
    float*  agg          = (float*)(w + off);  off += (size_t)N_NODES * H * 4;
    float*  g            = (float*)(w + off);  off += (size_t)GH * 4;
    (void)ws_size;

    // ---- build ----
    k_zero_i<<<1, NB, 0, stream>>>(bucketCnt, NB);
    k_hist<<<512, B, 0, stream>>>(dst, bucketCnt, N_EDGES);
    k_scan_buckets<<<1, NB, 0, stream>>>(bucketCnt, bucketBase, bucketCursor);
    k_bucket<<<(N_EDGES + CHUNK - 1) / CHUNK, 512, 0, stream>>>(src, dst, bucketCursor,
                                                                ebuf, N_EDGES);
    k_csrify<<<NB, 1024, 0, stream>>>(ebuf, bucketBase, bucketCnt, x, csr, cursor,
                                      dinv, ts0);

    // ---- layer 1: gather x' (4 features), transform 4->16 ----
    k_gather<F_IN, 8><<<gG4, B, 0, stream>>>(ts0, dinv, csr, cursor, agg, N_NODES);
    k_transform<F_IN, false><<<gNode16, B, 0, stream>>>(agg, W1, b1, dinv, ts1,
                                                        nullptr, nullptr, N_NODES);
    // ---- layer 2 ----
    k_gather<H, 4><<<gG16, B, 0, stream>>>(ts1, dinv, csr, cursor, agg, N_NODES);
    k_transform<H, false><<<gNode16, B, 0, stream>>>(agg, W2, b2, dinv, ts2,
                                                     nullptr, nullptr, N_NODES);
    // ---- layer 3 + fused pool ----
    k_gather<H, 4><<<gG16, B, 0, stream>>>(ts2, dinv, csr, cursor, agg, N_NODES);
    k_zero_f<<<(GH + B - 1) / B, B, 0, stream>>>(g, GH);
    k_transform<H, true><<<gNode16, B, 0, stream>>>(agg, W3, b3, dinv, nullptr,
                                                    bat, g, N_NODES);

    // ---- final MLP ----
    k_mlp<<<(N_GRAPHS + B - 1) / B, B, 0, stream>>>(g, y, fcW1, fcb1, fcW2, fcb2,
                                                    fcW3, fcb3, out, N_GRAPHS);
}

// Round 9
// 230.512 us; speedup vs baseline: 3.1737x; 1.0118x over previous
//
#include <hip/hip_runtime.h>
#include <hip/hip_fp16.h>

#define N_NODES 100000
#define N_EDGES 3200000
#define N_GRAPHS 1024
#define F_IN 4
#define H 16

#define NB 256       // dst buckets
#define NPB 391      // nodes per bucket (256*391 = 100096 >= 100000)
#define CAP 13312    // per-bucket LDS fast-path capacity (mean 12512, sigma ~112)
#define CHUNK 4096   // edges per block in k_bucket
#define BEPT (CHUNK / 512)           // 8 edges per thread in k_bucket
#define EPT_C ((CAP + 1023) / 1024)  // 13 edges per thread in k_csrify

// ---------------- tiny utility kernels ----------------

__global__ void k_zero_f(float* __restrict__ p, int n) {
    int i = blockIdx.x * blockDim.x + threadIdx.x;
    if (i < n) p[i] = 0.0f;
}

__global__ void k_zero_i(int* __restrict__ p, int n) {
    int i = blockIdx.x * blockDim.x + threadIdx.x;
    if (i < n) p[i] = 0;
}

// ---------------- bucketed edge partition ----------------

__global__ void k_hist(const int* __restrict__ dst, int* __restrict__ bucketCnt, int e) {
    __shared__ int h[NB];
    for (int t = threadIdx.x; t < NB; t += blockDim.x) h[t] = 0;
    __syncthreads();
    for (int i = blockIdx.x * blockDim.x + threadIdx.x; i < e; i += gridDim.x * blockDim.x)
        atomicAdd(&h[dst[i] / NPB], 1);
    __syncthreads();
    for (int t = threadIdx.x; t < NB; t += blockDim.x) {
        int c = h[t];
        if (c) atomicAdd(&bucketCnt[t], c);
    }
}

// exclusive scan of NB bucket counts; one block of NB threads
__global__ void k_scan_buckets(const int* __restrict__ bucketCnt,
                               int* __restrict__ bucketBase,
                               int* __restrict__ bucketCursor) {
    __shared__ int sh[NB];
    int t = threadIdx.x;
    int v = bucketCnt[t];
    sh[t] = v;
    __syncthreads();
    for (int off = 1; off < NB; off <<= 1) {
        int x = (t >= off) ? sh[t - off] : 0;
        __syncthreads();
        sh[t] += x;
        __syncthreads();
    }
    int base = sh[t] - v;
    bucketBase[t] = base;
    bucketCursor[t] = base;
}

// register-staged single-pass distribute: ONE LDS atomic per edge.
// payload packed: (local_dst << 20) | src   (local_dst < 391, src < 2^20)
__global__ __launch_bounds__(512) void k_bucket(const int* __restrict__ src,
                                                const int* __restrict__ dst,
                                                int* __restrict__ bucketCursor,
                                                int* __restrict__ ebuf, int e) {
    __shared__ int cnt[NB];
    __shared__ int lbase[NB];
    int t = threadIdx.x;
    for (int q = t; q < NB; q += 512) cnt[q] = 0;
    __syncthreads();
    int e0 = blockIdx.x * CHUNK;
    int vq[BEPT], bq[BEPT], rq[BEPT];
#pragma unroll
    for (int q = 0; q < BEPT; ++q) {
        int i = e0 + t + q * 512;
        bq[q] = -1;
        if (i < e) {
            int s = src[i];
            int d = dst[i];
            int b = d / NPB;
            int l = d - b * NPB;
            vq[q] = s | (l << 20);
            bq[q] = b;
            rq[q] = atomicAdd(&cnt[b], 1);
        }
    }
    __syncthreads();
    for (int q = t; q < NB; q += 512) {
        int c = cnt[q];
        lbase[q] = c ? atomicAdd(&bucketCursor[q], c) : 0;
    }
    __syncthreads();
#pragma unroll
    for (int q = 0; q < BEPT; ++q)
        if (bq[q] >= 0) ebuf[lbase[bq[q]] + rq[q]] = vq[q];
}

// one block per bucket: group by node -> coalesced CSR + cursor + dinv + ts0.
// Register-staged fast path: ONE LDS atomic per edge.
__global__ __launch_bounds__(1024) void k_csrify(const int* __restrict__ ebuf,
                                                 const int* __restrict__ bucketBase,
                                                 const int* __restrict__ bucketCnt,
                                                 const float* __restrict__ x,
                                                 int* __restrict__ csr,
                                                 int* __restrict__ cursor,
                                                 float* __restrict__ dinv,
                                                 __half* __restrict__ ts0) {
    __shared__ int cnt[NPB];
    __shared__ int st[NPB];
    __shared__ int cnt2[NPB];
    __shared__ float sdv[NPB];
    __shared__ int sc[1024];
    __shared__ int lcsr[CAP];
    int t = threadIdx.x;
    int b = blockIdx.x;
    int base = bucketBase[b];
    int m = bucketCnt[b];
    int nbase = b * NPB;
    for (int q = t; q < NPB; q += 1024) { cnt[q] = 0; cnt2[q] = 0; }
    __syncthreads();

    bool fast = (m <= CAP);
    int vq[EPT_C], rq[EPT_C];
    if (fast) {
        // staged count: load once, rank via one atomic, keep value+rank in regs
#pragma unroll
        for (int c = 0; c < EPT_C; ++c) {
            int idx = t + c * 1024;
            vq[c] = -1;
            if (idx < m) {
                int v = ebuf[base + idx];
                vq[c] = v;
                rq[c] = atomicAdd(&cnt[v >> 20], 1);
            }
        }
    } else {
        // capacity-proof slow path: count pass
        for (int i = t; i < m; i += 1024)
            atomicAdd(&cnt[ebuf[base + i] >> 20], 1);
    }
    __syncthreads();
    // scan (NPB <= 1024): Hillis-Steele
    int v0 = (t < NPB) ? cnt[t] : 0;
    sc[t] = v0;
    __syncthreads();
    for (int off = 1; off < 1024; off <<= 1) {
        int xv = (t >= off) ? sc[t - off] : 0;
        __syncthreads();
        sc[t] += xv;
        __syncthreads();
    }
    if (t < NPB) st[t] = sc[t] - v0;
    __syncthreads();
    if (t < NPB) {
        int node = nbase + t;
        if (node < N_NODES) {
            float dv = rsqrtf((float)cnt[t] + 1.0f);
            sdv[t] = dv;
            dinv[node] = dv;
            cursor[node] = base + st[t] + cnt[t];
        }
    }
    __syncthreads();
    // prescale layer-1 input: ts0 = half(dinv * x)
    for (int idx = t; idx < NPB * F_IN; idx += 1024) {
        int q = idx >> 2;
        int node = nbase + q;
        if (node < N_NODES)
            ts0[node * F_IN + (idx & 3)] =
                __float2half(sdv[q] * x[node * F_IN + (idx & 3)]);
    }
    // place
    if (fast) {
#pragma unroll
        for (int c = 0; c < EPT_C; ++c) {
            int v = vq[c];
            if (v >= 0) lcsr[st[v >> 20] + rq[c]] = v & 0xFFFFF;
        }
        __syncthreads();
        for (int i = t; i < m; i += 1024) csr[base + i] = lcsr[i];
    } else {
        for (int i = t; i < m; i += 1024) {
            int v = ebuf[base + i];
            int l = v >> 20;
            int r = atomicAdd(&cnt2[l], 1);
            csr[base + st[l] + r] = v & 0xFFFFF;
        }
    }
}

// ---------------- CSR gather, half2 loads, WAYS-way edge split ----------------
// Lane group per node: (F/2) feature-pair lanes x WAYS edge ways.
// agg[i,:] = dinv[i] * (ts[i,:] + sum_{s in N(i)} ts[s,:])
template <int F, int WAYS>
__global__ void k_gather(const __half* __restrict__ ts, const float* __restrict__ dinv,
                         const int* __restrict__ csr, const int* __restrict__ cursor,
                         float* __restrict__ agg, int n) {
    const int FP = F / 2;            // feature pairs
    const int L = FP * WAYS;         // lanes per node
    int i = blockIdx.x * (256 / L) + threadIdx.x / L;
    int g = threadIdx.x % L;
    int k2 = g % FP;                 // feature-pair index
    int w = g / FP;                  // edge way
    if (i >= n) return;
    int start = (i == 0) ? 0 : cursor[i - 1];
    int end = cursor[i];
    float ax0 = 0.f, ay0 = 0.f, ax1 = 0.f, ay1 = 0.f;
    int j = start + w;
    for (; j + 3 * WAYS < end; j += 4 * WAYS) {
        int s0 = csr[j];
        int s1 = csr[j + WAYS];
        int s2 = csr[j + 2 * WAYS];
        int s3 = csr[j + 3 * WAYS];
        float2 f0 = __half22float2(*(const __half2*)&ts[s0 * F + 2 * k2]);
        float2 f1 = __half22float2(*(const __half2*)&ts[s1 * F + 2 * k2]);
        float2 f2 = __half22float2(*(const __half2*)&ts[s2 * F + 2 * k2]);
        float2 f3 = __half22float2(*(const __half2*)&ts[s3 * F + 2 * k2]);
        ax0 += f0.x + f2.x; ay0 += f0.y + f2.y;
        ax1 += f1.x + f3.x; ay1 += f1.y + f3.y;
    }
    for (; j < end; j += WAYS) {
        float2 f = __half22float2(*(const __half2*)&ts[csr[j] * F + 2 * k2]);
        ax0 += f.x; ay0 += f.y;
    }
    float sx = ax0 + ax1;
    float sy = ay0 + ay1;
    if (w == 0) {  // self-loop term
        float2 f = __half22float2(*(const __half2*)&ts[i * F + 2 * k2]);
        sx += f.x; sy += f.y;
    }
#pragma unroll
    for (int msk = FP; msk < L; msk <<= 1) {
        sx += __shfl_xor(sx, msk, 64);
        sy += __shfl_xor(sy, msk, 64);
    }
    if (w == 0) {
        float dv = dinv[i];
        *(float2*)&agg[i * F + 2 * k2] = make_float2(dv * sx, dv * sy);
    }
}

// ---------------- per-node transform: h = relu(agg @ W + b) ----------------
// 16 lanes per node. Non-pool: ts_out = half(dinv*h). Pool: g[batch[i]] += h.
template <int FI, bool POOL>
__global__ void k_transform(const float* __restrict__ agg, const float* __restrict__ W,
                            const float* __restrict__ bias, const float* __restrict__ dinv,
                            __half* __restrict__ ts_out, const int* __restrict__ batch,
                            float* __restrict__ g, int n) {
    __shared__ float sW[FI * H];
    for (int t = threadIdx.x; t < FI * H; t += blockDim.x) sW[t] = W[t];
    __syncthreads();
    int i = blockIdx.x * 16 + (threadIdx.x >> 4);
    int k = threadIdx.x & 15;
    if (i >= n) return;
    float acc = bias[k];
#pragma unroll
    for (int j = 0; j < FI; j++) acc = fmaf(agg[i * FI + j], sW[j * H + k], acc);
    float h = fmaxf(acc, 0.0f);
    if (POOL) {
        atomicAdd(&g[batch[i] * H + k], h);
    } else {
        ts_out[i * H + k] = __float2half(dinv[i] * h);
    }
}

// ---------------- final MLP ----------------

__global__ void k_mlp(const float* __restrict__ g, const float* __restrict__ y,
                      const float* __restrict__ fcW1, const float* __restrict__ fcb1,
                      const float* __restrict__ fcW2, const float* __restrict__ fcb2,
                      const float* __restrict__ fcW3, const float* __restrict__ fcb3,
                      float* __restrict__ out, int ngraph) {
    int i = blockIdx.x * blockDim.x + threadIdx.x;
    if (i >= ngraph) return;
    float in[H + 4];
#pragma unroll
    for (int k = 0; k < H; k++) in[k] = g[i * H + k];
#pragma unroll
    for (int k = 0; k < 4; k++) in[H + k] = y[i * 4 + k];
    float z1[H];
#pragma unroll
    for (int o = 0; o < H; o++) {
        float a = fcb1[o];
#pragma unroll
        for (int j = 0; j < H + 4; j++) a += in[j] * fcW1[j * H + o];
        z1[o] = fmaxf(a, 0.0f);
    }
    float z2[H];
#pragma unroll
    for (int o = 0; o < H; o++) {
        float a = fcb2[o];
#pragma unroll
        for (int j = 0; j < H; j++) a += z1[j] * fcW2[j * H + o];
        z2[o] = fmaxf(a, 0.0f);
    }
    float a = fcb3[0];
#pragma unroll
    for (int j = 0; j < H; j++) a += z2[j] * fcW3[j];
    out[i] = a;
}

// ---------------- launch ----------------

extern "C" void kernel_launch(void* const* d_in, const int* in_sizes, int n_in,
                              void* d_out, int out_size, void* d_ws, size_t ws_size,
                              hipStream_t stream) {
    const float* x    = (const float*)d_in[0];
    const int*   ei   = (const int*)d_in[1];   // [2, E]: src then dst
    const float* y    = (const float*)d_in[2];
    const int*   bat  = (const int*)d_in[3];
    const float* W1   = (const float*)d_in[4];
    const float* b1   = (const float*)d_in[5];
    const float* W2   = (const float*)d_in[6];
    const float* b2   = (const float*)d_in[7];
    const float* W3   = (const float*)d_in[8];
    const float* b3   = (const float*)d_in[9];
    const float* fcW1 = (const float*)d_in[10];
    const float* fcb1 = (const float*)d_in[11];
    const float* fcW2 = (const float*)d_in[12];
    const float* fcb2 = (const float*)d_in[13];
    const float* fcW3 = (const float*)d_in[14];
    const float* fcb3 = (const float*)d_in[15];
    float* out = (float*)d_out;

    const int* src = ei;
    const int* dst = ei + N_EDGES;

    const int B = 256;
    const int GH = N_GRAPHS * H;
    const int gNode16 = (N_NODES + 15) / 16;        // transform: 16 nodes/block
    const int gG4  = (N_NODES + 15) / 16;           // F=4,W=8: L=16, 16 nodes/block
    const int gG16 = (N_NODES + 7) / 8;             // F=16,W=4: L=32, 8 nodes/block

    // ---- workspace layout ----
    char* w = (char*)d_ws;
    size_t off = 0;
    int*    bucketCnt    = (int*)(w + off);    off += (size_t)NB * 4;
    int*    bucketBase   = (int*)(w + off);    off += (size_t)NB * 4;
    int*    bucketCursor = (int*)(w + off);    off += (size_t)NB * 4;
    int*    cursor       = (int*)(w + off);    off += (size_t)N_NODES * 4;
    float*  dinv         = (float*)(w + off);  off += (size_t)N_NODES * 4;
    int*    ebuf         = (int*)(w + off);    off += (size_t)N_EDGES * 4;
    int*    csr          = (int*)(w + off);    off += (size_t)N_EDGES * 4;
    __half* ts0          = (__half*)(w + off); off += (size_t)N_NODES * F_IN * 2;
    __half* ts1          = (__half*)(w + off); off += (size_t)N_NODES * H * 2;
    __half* ts2          = (__half*)(w + off); off += (size_t)N_NODES * H * 2;
    float*  agg          = (float*)(w + off);  off += (size_t)N_NODES * H * 4;
    float*  g            = (float*)(w + off);  off += (size_t)GH * 4;
    (void)ws_size;

    // ---- build ----
    k_zero_i<<<1, NB, 0, stream>>>(bucketCnt, NB);
    k_hist<<<512, B, 0, stream>>>(dst, bucketCnt, N_EDGES);
    k_scan_buckets<<<1, NB, 0, stream>>>(bucketCnt, bucketBase, bucketCursor);
    k_bucket<<<(N_EDGES + CHUNK - 1) / CHUNK, 512, 0, stream>>>(src, dst, bucketCursor,
                                                                ebuf, N_EDGES);
    k_csrify<<<NB, 1024, 0, stream>>>(ebuf, bucketBase, bucketCnt, x, csr, cursor,
                                      dinv, ts0);

    // ---- layer 1: gather x' (4 features), transform 4->16 ----
    k_gather<F_IN, 8><<<gG4, B, 0, stream>>>(ts0, dinv, csr, cursor, agg, N_NODES);
    k_transform<F_IN, false><<<gNode16, B, 0, stream>>>(agg, W1, b1, dinv, ts1,
                                                        nullptr, nullptr, N_NODES);
    // ---- layer 2 ----
    k_gather<H, 4><<<gG16, B, 0, stream>>>(ts1, dinv, csr, cursor, agg, N_NODES);
    k_transform<H, false><<<gNode16, B, 0, stream>>>(agg, W2, b2, dinv, ts2,
                                                     nullptr, nullptr, N_NODES);
    // ---- layer 3 + fused pool ----
    k_gather<H, 4><<<gG16, B, 0, stream>>>(ts2, dinv, csr, cursor, agg, N_NODES);
    k_zero_f<<<(GH + B - 1) / B, B, 0, stream>>>(g, GH);
    k_transform<H, true><<<gNode16, B, 0, stream>>>(agg, W3, b3, dinv, nullptr,
                                                    bat, g, N_NODES);

    // ---- final MLP ----
    k_mlp<<<(N_GRAPHS + B - 1) / B, B, 0, stream>>>(g, y, fcW1, fcb1, fcW2, fcb2,
                                                    fcW3, fcb3, out, N_GRAPHS);
}

// Round 10
// 205.101 us; speedup vs baseline: 3.5670x; 1.1239x over previous
//
#include <hip/hip_runtime.h>
#include <hip/hip_fp16.h>

#define N_NODES 100000
#define N_EDGES 3200000
#define N_GRAPHS 1024
#define F_IN 4
#define H 16

#define NB 256       // dst buckets
#define NPB 391      // nodes per bucket (256*391 = 100096 >= 100000)
#define CAP 13312    // per-bucket LDS fast-path capacity (mean 12512, sigma ~112)
#define CHUNK 4096   // edges per chunk in count/place
#define NBLK ((N_EDGES + CHUNK - 1) / CHUNK)   // 782
#define EPT_C ((CAP + 1023) / 1024)            // 13 edges per thread in k_csrify

// ---------------- tiny utility kernels ----------------

__global__ void k_zero_f(float* __restrict__ p, int n) {
    int i = blockIdx.x * blockDim.x + threadIdx.x;
    if (i < n) p[i] = 0.0f;
}

// ---------------- deterministic bucketed edge partition ----------------

// per-chunk LDS histogram of dst buckets -> coalesced blkCnt row
__global__ __launch_bounds__(512) void k_count(const int* __restrict__ dst,
                                               int* __restrict__ blkCnt, int e) {
    __shared__ int h[NB];
    int t = threadIdx.x;
    for (int q = t; q < NB; q += 512) h[q] = 0;
    __syncthreads();
    int e0 = blockIdx.x * CHUNK;
    int e1 = min(e0 + CHUNK, e);
    for (int i = e0 + t; i < e1; i += 512)
        atomicAdd(&h[dst[i] / NPB], 1);
    __syncthreads();
    for (int q = t; q < NB; q += 512) blkCnt[blockIdx.x * NB + q] = h[q];
}

// one block per bucket: exclusive prefix over chunks -> blkBase; total -> bucketCnt
__global__ __launch_bounds__(1024) void k_colscan(const int* __restrict__ blkCnt,
                                                  int* __restrict__ blkBase,
                                                  int* __restrict__ bucketCnt) {
    __shared__ int sc[1024];
    int b = blockIdx.x;
    int t = threadIdx.x;
    int v = (t < NBLK) ? blkCnt[t * NB + b] : 0;
    sc[t] = v;
    __syncthreads();
    for (int off = 1; off < 1024; off <<= 1) {
        int x = (t >= off) ? sc[t - off] : 0;
        __syncthreads();
        sc[t] += x;
        __syncthreads();
    }
    if (t < NBLK) blkBase[t * NB + b] = sc[t] - v;
    if (t == NBLK - 1) bucketCnt[b] = sc[t];
}

// exclusive scan of NB bucket totals; one block of NB threads
__global__ void k_scan_buckets(const int* __restrict__ bucketCnt,
                               int* __restrict__ bucketBase) {
    __shared__ int sh[NB];
    int t = threadIdx.x;
    int v = bucketCnt[t];
    sh[t] = v;
    __syncthreads();
    for (int off = 1; off < NB; off <<= 1) {
        int x = (t >= off) ? sh[t - off] : 0;
        __syncthreads();
        sh[t] += x;
        __syncthreads();
    }
    bucketBase[t] = sh[t] - v;
}

// deterministic place: no global atomics, one LDS rank-atomic per edge.
// payload packed: (local_dst << 20) | src   (local_dst < 391, src < 2^20)
__global__ __launch_bounds__(512) void k_place(const int* __restrict__ src,
                                               const int* __restrict__ dst,
                                               const int* __restrict__ bucketBase,
                                               const int* __restrict__ blkBase,
                                               int* __restrict__ ebuf, int e) {
    __shared__ int cnt[NB];
    __shared__ int lbase[NB];
    int t = threadIdx.x;
    for (int q = t; q < NB; q += 512) {
        cnt[q] = 0;
        lbase[q] = bucketBase[q] + blkBase[blockIdx.x * NB + q];
    }
    __syncthreads();
    int e0 = blockIdx.x * CHUNK;
    int e1 = min(e0 + CHUNK, e);
    for (int i = e0 + t; i < e1; i += 512) {
        int s = src[i];
        int d = dst[i];
        int b = d / NPB;
        int l = d - b * NPB;
        int r = atomicAdd(&cnt[b], 1);
        ebuf[lbase[b] + r] = s | (l << 20);
    }
}

// one block per bucket: group by node -> coalesced CSR + cursor + dinv + ts0.
// Register-staged fast path: ONE LDS atomic per edge.
__global__ __launch_bounds__(1024) void k_csrify(const int* __restrict__ ebuf,
                                                 const int* __restrict__ bucketBase,
                                                 const int* __restrict__ bucketCnt,
                                                 const float* __restrict__ x,
                                                 int* __restrict__ csr,
                                                 int* __restrict__ cursor,
                                                 float* __restrict__ dinv,
                                                 __half* __restrict__ ts0) {
    __shared__ int cnt[NPB];
    __shared__ int st[NPB];
    __shared__ int cnt2[NPB];
    __shared__ float sdv[NPB];
    __shared__ int sc[1024];
    __shared__ int lcsr[CAP];
    int t = threadIdx.x;
    int b = blockIdx.x;
    int base = bucketBase[b];
    int m = bucketCnt[b];
    int nbase = b * NPB;
    for (int q = t; q < NPB; q += 1024) { cnt[q] = 0; cnt2[q] = 0; }
    __syncthreads();

    bool fast = (m <= CAP);
    int vq[EPT_C], rq[EPT_C];
    if (fast) {
#pragma unroll
        for (int c = 0; c < EPT_C; ++c) {
            int idx = t + c * 1024;
            vq[c] = -1;
            if (idx < m) {
                int v = ebuf[base + idx];
                vq[c] = v;
                rq[c] = atomicAdd(&cnt[v >> 20], 1);
            }
        }
    } else {
        for (int i = t; i < m; i += 1024)
            atomicAdd(&cnt[ebuf[base + i] >> 20], 1);
    }
    __syncthreads();
    // scan (NPB <= 1024): Hillis-Steele
    int v0 = (t < NPB) ? cnt[t] : 0;
    sc[t] = v0;
    __syncthreads();
    for (int off = 1; off < 1024; off <<= 1) {
        int xv = (t >= off) ? sc[t - off] : 0;
        __syncthreads();
        sc[t] += xv;
        __syncthreads();
    }
    if (t < NPB) st[t] = sc[t] - v0;
    __syncthreads();
    if (t < NPB) {
        int node = nbase + t;
        if (node < N_NODES) {
            float dv = rsqrtf((float)cnt[t] + 1.0f);
            sdv[t] = dv;
            dinv[node] = dv;
            cursor[node] = base + st[t] + cnt[t];
        }
    }
    __syncthreads();
    // prescale layer-1 input: ts0 = half(dinv * x)
    for (int idx = t; idx < NPB * F_IN; idx += 1024) {
        int q = idx >> 2;
        int node = nbase + q;
        if (node < N_NODES)
            ts0[node * F_IN + (idx & 3)] =
                __float2half(sdv[q] * x[node * F_IN + (idx & 3)]);
    }
    // place
    if (fast) {
#pragma unroll
        for (int c = 0; c < EPT_C; ++c) {
            int v = vq[c];
            if (v >= 0) lcsr[st[v >> 20] + rq[c]] = v & 0xFFFFF;
        }
        __syncthreads();
        for (int i = t; i < m; i += 1024) csr[base + i] = lcsr[i];
    } else {
        for (int i = t; i < m; i += 1024) {
            int v = ebuf[base + i];
            int l = v >> 20;
            int r = atomicAdd(&cnt2[l], 1);
            csr[base + st[l] + r] = v & 0xFFFFF;
        }
    }
}

// ---------------- CSR gather, half2 loads, WAYS-way edge split ----------------
// Lane group per node: (F/2) feature-pair lanes x WAYS edge ways.
// agg[i,:] = dinv[i] * (ts[i,:] + sum_{s in N(i)} ts[s,:])
template <int F, int WAYS>
__global__ void k_gather(const __half* __restrict__ ts, const float* __restrict__ dinv,
                         const int* __restrict__ csr, const int* __restrict__ cursor,
                         float* __restrict__ agg, int n) {
    const int FP = F / 2;            // feature pairs
    const int L = FP * WAYS;         // lanes per node
    int i = blockIdx.x * (256 / L) + threadIdx.x / L;
    int g = threadIdx.x % L;
    int k2 = g % FP;                 // feature-pair index
    int w = g / FP;                  // edge way
    if (i >= n) return;
    int start = (i == 0) ? 0 : cursor[i - 1];
    int end = cursor[i];
    float ax0 = 0.f, ay0 = 0.f, ax1 = 0.f, ay1 = 0.f;
    int j = start + w;
    for (; j + 3 * WAYS < end; j += 4 * WAYS) {
        int s0 = csr[j];
        int s1 = csr[j + WAYS];
        int s2 = csr[j + 2 * WAYS];
        int s3 = csr[j + 3 * WAYS];
        float2 f0 = __half22float2(*(const __half2*)&ts[s0 * F + 2 * k2]);
        float2 f1 = __half22float2(*(const __half2*)&ts[s1 * F + 2 * k2]);
        float2 f2 = __half22float2(*(const __half2*)&ts[s2 * F + 2 * k2]);
        float2 f3 = __half22float2(*(const __half2*)&ts[s3 * F + 2 * k2]);
        ax0 += f0.x + f2.x; ay0 += f0.y + f2.y;
        ax1 += f1.x + f3.x; ay1 += f1.y + f3.y;
    }
    for (; j < end; j += WAYS) {
        float2 f = __half22float2(*(const __half2*)&ts[csr[j] * F + 2 * k2]);
        ax0 += f.x; ay0 += f.y;
    }
    float sx = ax0 + ax1;
    float sy = ay0 + ay1;
    if (w == 0) {  // self-loop term
        float2 f = __half22float2(*(const __half2*)&ts[i * F + 2 * k2]);
        sx += f.x; sy += f.y;
    }
#pragma unroll
    for (int msk = FP; msk < L; msk <<= 1) {
        sx += __shfl_xor(sx, msk, 64);
        sy += __shfl_xor(sy, msk, 64);
    }
    if (w == 0) {
        float dv = dinv[i];
        *(float2*)&agg[i * F + 2 * k2] = make_float2(dv * sx, dv * sy);
    }
}

// ---------------- per-node transform: h = relu(agg @ W + b) ----------------
// 16 lanes per node. Non-pool: ts_out = half(dinv*h). Pool: g[batch[i]] += h.
template <int FI, bool POOL>
__global__ void k_transform(const float* __restrict__ agg, const float* __restrict__ W,
                            const float* __restrict__ bias, const float* __restrict__ dinv,
                            __half* __restrict__ ts_out, const int* __restrict__ batch,
                            float* __restrict__ g, int n) {
    __shared__ float sW[FI * H];
    for (int t = threadIdx.x; t < FI * H; t += blockDim.x) sW[t] = W[t];
    __syncthreads();
    int i = blockIdx.x * 16 + (threadIdx.x >> 4);
    int k = threadIdx.x & 15;
    if (i >= n) return;
    float acc = bias[k];
#pragma unroll
    for (int j = 0; j < FI; j++) acc = fmaf(agg[i * FI + j], sW[j * H + k], acc);
    float h = fmaxf(acc, 0.0f);
    if (POOL) {
        atomicAdd(&g[batch[i] * H + k], h);
    } else {
        ts_out[i * H + k] = __float2half(dinv[i] * h);
    }
}

// ---------------- final MLP ----------------

__global__ void k_mlp(const float* __restrict__ g, const float* __restrict__ y,
                      const float* __restrict__ fcW1, const float* __restrict__ fcb1,
                      const float* __restrict__ fcW2, const float* __restrict__ fcb2,
                      const float* __restrict__ fcW3, const float* __restrict__ fcb3,
                      float* __restrict__ out, int ngraph) {
    int i = blockIdx.x * blockDim.x + threadIdx.x;
    if (i >= ngraph) return;
    float in[H + 4];
#pragma unroll
    for (int k = 0; k < H; k++) in[k] = g[i * H + k];
#pragma unroll
    for (int k = 0; k < 4; k++) in[H + k] = y[i * 4 + k];
    float z1[H];
#pragma unroll
    for (int o = 0; o < H; o++) {
        float a = fcb1[o];
#pragma unroll
        for (int j = 0; j < H + 4; j++) a += in[j] * fcW1[j * H + o];
        z1[o] = fmaxf(a, 0.0f);
    }
    float z2[H];
#pragma unroll
    for (int o = 0; o < H; o++) {
        float a = fcb2[o];
#pragma unroll
        for (int j = 0; j < H; j++) a += z1[j] * fcW2[j * H + o];
        z2[o] = fmaxf(a, 0.0f);
    }
    float a = fcb3[0];
#pragma unroll
    for (int j = 0; j < H; j++) a += z2[j] * fcW3[j];
    out[i] = a;
}

// ---------------- launch ----------------

extern "C" void kernel_launch(void* const* d_in, const int* in_sizes, int n_in,
                              void* d_out, int out_size, void* d_ws, size_t ws_size,
                              hipStream_t stream) {
    const float* x    = (const float*)d_in[0];
    const int*   ei   = (const int*)d_in[1];   // [2, E]: src then dst
    const float* y    = (const float*)d_in[2];
    const int*   bat  = (const int*)d_in[3];
    const float* W1   = (const float*)d_in[4];
    const float* b1   = (const float*)d_in[5];
    const float* W2   = (const float*)d_in[6];
    const float* b2   = (const float*)d_in[7];
    const float* W3   = (const float*)d_in[8];
    const float* b3   = (const float*)d_in[9];
    const float* fcW1 = (const float*)d_in[10];
    const float* fcb1 = (const float*)d_in[11];
    const float* fcW2 = (const float*)d_in[12];
    const float* fcb2 = (const float*)d_in[13];
    const float* fcW3 = (const float*)d_in[14];
    const float* fcb3 = (const float*)d_in[15];
    float* out = (float*)d_out;

    const int* src = ei;
    const int* dst = ei + N_EDGES;

    const int B = 256;
    const int GH = N_GRAPHS * H;
    const int gNode16 = (N_NODES + 15) / 16;        // transform: 16 nodes/block
    const int gG4  = (N_NODES + 15) / 16;           // F=4,W=8: L=16, 16 nodes/block
    const int gG16 = (N_NODES + 7) / 8;             // F=16,W=4: L=32, 8 nodes/block

    // ---- workspace layout ----
    char* w = (char*)d_ws;
    size_t off = 0;
    int*    bucketCnt    = (int*)(w + off);    off += (size_t)NB * 4;
    int*    bucketBase   = (int*)(w + off);    off += (size_t)NB * 4;
    int*    blkCnt       = (int*)(w + off);    off += (size_t)NBLK * NB * 4;
    int*    blkBase      = (int*)(w + off);    off += (size_t)NBLK * NB * 4;
    int*    cursor       = (int*)(w + off);    off += (size_t)N_NODES * 4;
    float*  dinv         = (float*)(w + off);  off += (size_t)N_NODES * 4;
    int*    ebuf         = (int*)(w + off);    off += (size_t)N_EDGES * 4;
    int*    csr          = (int*)(w + off);    off += (size_t)N_EDGES * 4;
    __half* ts0          = (__half*)(w + off); off += (size_t)N_NODES * F_IN * 2;
    __half* ts1          = (__half*)(w + off); off += (size_t)N_NODES * H * 2;
    __half* ts2          = (__half*)(w + off); off += (size_t)N_NODES * H * 2;
    float*  agg          = (float*)(w + off);  off += (size_t)N_NODES * H * 4;
    float*  g            = (float*)(w + off);  off += (size_t)GH * 4;
    (void)ws_size;

    // ---- build (deterministic, zero global atomics) ----
    k_count<<<NBLK, 512, 0, stream>>>(dst, blkCnt, N_EDGES);
    k_colscan<<<NB, 1024, 0, stream>>>(blkCnt, blkBase, bucketCnt);
    k_scan_buckets<<<1, NB, 0, stream>>>(bucketCnt, bucketBase);
    k_place<<<NBLK, 512, 0, stream>>>(src, dst, bucketBase, blkBase, ebuf, N_EDGES);
    k_csrify<<<NB, 1024, 0, stream>>>(ebuf, bucketBase, bucketCnt, x, csr, cursor,
                                      dinv, ts0);

    // ---- layer 1: gather x' (4 features), transform 4->16 ----
    k_gather<F_IN, 8><<<gG4, B, 0, stream>>>(ts0, dinv, csr, cursor, agg, N_NODES);
    k_transform<F_IN, false><<<gNode16, B, 0, stream>>>(agg, W1, b1, dinv, ts1,
                                                        nullptr, nullptr, N_NODES);
    // ---- layer 2 ----
    k_gather<H, 4><<<gG16, B, 0, stream>>>(ts1, dinv, csr, cursor, agg, N_NODES);
    k_transform<H, false><<<gNode16, B, 0, stream>>>(agg, W2, b2, dinv, ts2,
                                                     nullptr, nullptr, N_NODES);
    // ---- layer 3 + fused pool ----
    k_gather<H, 4><<<gG16, B, 0, stream>>>(ts2, dinv, csr, cursor, agg, N_NODES);
    k_zero_f<<<(GH + B - 1) / B, B, 0, stream>>>(g, GH);
    k_transform<H, true><<<gNode16, B, 0, stream>>>(agg, W3, b3, dinv, nullptr,
                                                    bat, g, N_NODES);

    // ---- final MLP ----
    k_mlp<<<(N_GRAPHS + B - 1) / B, B, 0, stream>>>(g, y, fcW1, fcb1, fcW2, fcb2,
                                                    fcW3, fcb3, out, N_GRAPHS);
}

// Round 11
// 196.836 us; speedup vs baseline: 3.7167x; 1.0420x over previous
//
#include <hip/hip_runtime.h>
#include <hip/hip_fp16.h>

#define N_NODES 100000
#define N_EDGES 3200000
#define N_GRAPHS 1024
#define F_IN 4
#define H 16

#define NB 256       // dst buckets
#define NPB 391      // nodes per bucket (256*391 = 100096 >= 100000)
#define CAP 13312    // per-bucket LDS fast-path capacity (mean 12512, sigma ~112)
#define CHUNK 4096   // edges per chunk in count/place
#define NBLK ((N_EDGES + CHUNK - 1) / CHUNK)   // 782
#define BEPT (CHUNK / 512)                     // 8 edges per thread in k_place
#define EPT_C ((CAP + 1023) / 1024)            // 13 edges per thread in k_csrify

// ---------------- tiny utility kernels ----------------

__global__ void k_zero_f(float* __restrict__ p, int n) {
    int i = blockIdx.x * blockDim.x + threadIdx.x;
    if (i < n) p[i] = 0.0f;
}

// ---------------- deterministic bucketed edge partition ----------------

// per-chunk LDS histogram of dst buckets -> coalesced blkCnt row
__global__ __launch_bounds__(512) void k_count(const int* __restrict__ dst,
                                               int* __restrict__ blkCnt, int e) {
    __shared__ int h[NB];
    int t = threadIdx.x;
    for (int q = t; q < NB; q += 512) h[q] = 0;
    __syncthreads();
    int e0 = blockIdx.x * CHUNK;
    int e1 = min(e0 + CHUNK, e);
    for (int i = e0 + t; i < e1; i += 512)
        atomicAdd(&h[dst[i] / NPB], 1);
    __syncthreads();
    for (int q = t; q < NB; q += 512) blkCnt[blockIdx.x * NB + q] = h[q];
}

// one block per bucket: exclusive prefix over chunks -> blkBase; total -> bucketCnt
__global__ __launch_bounds__(1024) void k_colscan(const int* __restrict__ blkCnt,
                                                  int* __restrict__ blkBase,
                                                  int* __restrict__ bucketCnt) {
    __shared__ int sc[1024];
    int b = blockIdx.x;
    int t = threadIdx.x;
    int v = (t < NBLK) ? blkCnt[t * NB + b] : 0;
    sc[t] = v;
    __syncthreads();
    for (int off = 1; off < 1024; off <<= 1) {
        int x = (t >= off) ? sc[t - off] : 0;
        __syncthreads();
        sc[t] += x;
        __syncthreads();
    }
    if (t < NBLK) blkBase[t * NB + b] = sc[t] - v;
    if (t == NBLK - 1) bucketCnt[b] = sc[t];
}

// exclusive scan of NB bucket totals; one block of NB threads
__global__ void k_scan_buckets(const int* __restrict__ bucketCnt,
                               int* __restrict__ bucketBase) {
    __shared__ int sh[NB];
    int t = threadIdx.x;
    int v = bucketCnt[t];
    sh[t] = v;
    __syncthreads();
    for (int off = 1; off < NB; off <<= 1) {
        int x = (t >= off) ? sh[t - off] : 0;
        __syncthreads();
        sh[t] += x;
        __syncthreads();
    }
    bucketBase[t] = sh[t] - v;
}

// deterministic place with LDS sort: scatter happens in LDS, global writes
// are coalesced runs. payload: (local_dst << 20) | src
__global__ __launch_bounds__(512) void k_place(const int* __restrict__ src,
                                               const int* __restrict__ dst,
                                               const int* __restrict__ bucketBase,
                                               const int* __restrict__ blkBase,
                                               int* __restrict__ ebuf, int e) {
    __shared__ int cnt[NB];
    __shared__ int st[NB];
    __shared__ int lbase[NB];
    __shared__ int sc[NB];
    __shared__ int lsort[CHUNK];
    __shared__ unsigned short bof[CHUNK];
    int t = threadIdx.x;
    for (int q = t; q < NB; q += 512) {
        cnt[q] = 0;
        lbase[q] = bucketBase[q] + blkBase[blockIdx.x * NB + q];
    }
    __syncthreads();
    int e0 = blockIdx.x * CHUNK;
    int e1 = min(e0 + CHUNK, e);
    int m = e1 - e0;
    // phase 1: load + rank (one LDS atomic per edge)
    int vq[BEPT], bq[BEPT], rq[BEPT];
#pragma unroll
    for (int q = 0; q < BEPT; ++q) {
        int i = e0 + t + q * 512;
        bq[q] = -1;
        if (i < e) {
            int s = src[i];
            int d = dst[i];
            int b = d / NPB;
            int l = d - b * NPB;
            vq[q] = s | (l << 20);
            bq[q] = b;
            rq[q] = atomicAdd(&cnt[b], 1);
        }
    }
    __syncthreads();
    // phase 2: block-local exclusive scan of cnt -> st
    if (t < NB) sc[t] = cnt[t];
    __syncthreads();
    for (int off = 1; off < NB; off <<= 1) {
        int x = (t < NB && t >= off) ? sc[t - off] : 0;
        __syncthreads();
        if (t < NB) sc[t] += x;
        __syncthreads();
    }
    if (t < NB) st[t] = sc[t] - cnt[t];
    __syncthreads();
    // phase 3: scatter into LDS-sorted order
#pragma unroll
    for (int q = 0; q < BEPT; ++q) {
        if (bq[q] >= 0) {
            int pos = st[bq[q]] + rq[q];
            lsort[pos] = vq[q];
            bof[pos] = (unsigned short)bq[q];
        }
    }
    __syncthreads();
    // phase 4: coalesced flush (consecutive lanes -> consecutive addrs per run)
    for (int i = t; i < m; i += 512) {
        int b2 = bof[i];
        ebuf[lbase[b2] + i - st[b2]] = lsort[i];
    }
}

// one block per bucket: group by node -> coalesced CSR + cursor + dinv + ts0.
// Register-staged fast path: ONE LDS atomic per edge.
__global__ __launch_bounds__(1024) void k_csrify(const int* __restrict__ ebuf,
                                                 const int* __restrict__ bucketBase,
                                                 const int* __restrict__ bucketCnt,
                                                 const float* __restrict__ x,
                                                 int* __restrict__ csr,
                                                 int* __restrict__ cursor,
                                                 float* __restrict__ dinv,
                                                 __half* __restrict__ ts0) {
    __shared__ int cnt[NPB];
    __shared__ int st[NPB];
    __shared__ int cnt2[NPB];
    __shared__ float sdv[NPB];
    __shared__ int sc[1024];
    __shared__ int lcsr[CAP];
    int t = threadIdx.x;
    int b = blockIdx.x;
    int base = bucketBase[b];
    int m = bucketCnt[b];
    int nbase = b * NPB;
    for (int q = t; q < NPB; q += 1024) { cnt[q] = 0; cnt2[q] = 0; }
    __syncthreads();

    bool fast = (m <= CAP);
    int vq[EPT_C], rq[EPT_C];
    if (fast) {
#pragma unroll
        for (int c = 0; c < EPT_C; ++c) {
            int idx = t + c * 1024;
            vq[c] = -1;
            if (idx < m) {
                int v = ebuf[base + idx];
                vq[c] = v;
                rq[c] = atomicAdd(&cnt[v >> 20], 1);
            }
        }
    } else {
        for (int i = t; i < m; i += 1024)
            atomicAdd(&cnt[ebuf[base + i] >> 20], 1);
    }
    __syncthreads();
    // scan (NPB <= 1024): Hillis-Steele
    int v0 = (t < NPB) ? cnt[t] : 0;
    sc[t] = v0;
    __syncthreads();
    for (int off = 1; off < 1024; off <<= 1) {
        int xv = (t >= off) ? sc[t - off] : 0;
        __syncthreads();
        sc[t] += xv;
        __syncthreads();
    }
    if (t < NPB) st[t] = sc[t] - v0;
    __syncthreads();
    if (t < NPB) {
        int node = nbase + t;
        if (node < N_NODES) {
            float dv = rsqrtf((float)cnt[t] + 1.0f);
            sdv[t] = dv;
            dinv[node] = dv;
            cursor[node] = base + st[t] + cnt[t];
        }
    }
    __syncthreads();
    // prescale layer-1 input: ts0 = half(dinv * x)
    for (int idx = t; idx < NPB * F_IN; idx += 1024) {
        int q = idx >> 2;
        int node = nbase + q;
        if (node < N_NODES)
            ts0[node * F_IN + (idx & 3)] =
                __float2half(sdv[q] * x[node * F_IN + (idx & 3)]);
    }
    // place
    if (fast) {
#pragma unroll
        for (int c = 0; c < EPT_C; ++c) {
            int v = vq[c];
            if (v >= 0) lcsr[st[v >> 20] + rq[c]] = v & 0xFFFFF;
        }
        __syncthreads();
        for (int i = t; i < m; i += 1024) csr[base + i] = lcsr[i];
    } else {
        for (int i = t; i < m; i += 1024) {
            int v = ebuf[base + i];
            int l = v >> 20;
            int r = atomicAdd(&cnt2[l], 1);
            csr[base + st[l] + r] = v & 0xFFFFF;
        }
    }
}

// ---------------- CSR gather, half2 loads, WAYS-way edge split ----------------
// Lane group per node: (F/2) feature-pair lanes x WAYS edge ways.
// agg[i,:] = dinv[i] * (ts[i,:] + sum_{s in N(i)} ts[s,:])
template <int F, int WAYS>
__global__ void k_gather(const __half* __restrict__ ts, const float* __restrict__ dinv,
                         const int* __restrict__ csr, const int* __restrict__ cursor,
                         float* __restrict__ agg, int n) {
    const int FP = F / 2;            // feature pairs
    const int L = FP * WAYS;         // lanes per node
    int i = blockIdx.x * (256 / L) + threadIdx.x / L;
    int g = threadIdx.x % L;
    int k2 = g % FP;                 // feature-pair index
    int w = g / FP;                  // edge way
    if (i >= n) return;
    int start = (i == 0) ? 0 : cursor[i - 1];
    int end = cursor[i];
    float ax0 = 0.f, ay0 = 0.f, ax1 = 0.f, ay1 = 0.f;
    int j = start + w;
    for (; j + 3 * WAYS < end; j += 4 * WAYS) {
        int s0 = csr[j];
        int s1 = csr[j + WAYS];
        int s2 = csr[j + 2 * WAYS];
        int s3 = csr[j + 3 * WAYS];
        float2 f0 = __half22float2(*(const __half2*)&ts[s0 * F + 2 * k2]);
        float2 f1 = __half22float2(*(const __half2*)&ts[s1 * F + 2 * k2]);
        float2 f2 = __half22float2(*(const __half2*)&ts[s2 * F + 2 * k2]);
        float2 f3 = __half22float2(*(const __half2*)&ts[s3 * F + 2 * k2]);
        ax0 += f0.x + f2.x; ay0 += f0.y + f2.y;
        ax1 += f1.x + f3.x; ay1 += f1.y + f3.y;
    }
    for (; j < end; j += WAYS) {
        float2 f = __half22float2(*(const __half2*)&ts[csr[j] * F + 2 * k2]);
        ax0 += f.x; ay0 += f.y;
    }
    float sx = ax0 + ax1;
    float sy = ay0 + ay1;
    if (w == 0) {  // self-loop term
        float2 f = __half22float2(*(const __half2*)&ts[i * F + 2 * k2]);
        sx += f.x; sy += f.y;
    }
#pragma unroll
    for (int msk = FP; msk < L; msk <<= 1) {
        sx += __shfl_xor(sx, msk, 64);
        sy += __shfl_xor(sy, msk, 64);
    }
    if (w == 0) {
        float dv = dinv[i];
        *(float2*)&agg[i * F + 2 * k2] = make_float2(dv * sx, dv * sy);
    }
}

// ---------------- per-node transform: h = relu(agg @ W + b) ----------------
// 16 lanes per node. Non-pool: ts_out = half(dinv*h). Pool: g[batch[i]] += h.
template <int FI, bool POOL>
__global__ void k_transform(const float* __restrict__ agg, const float* __restrict__ W,
                            const float* __restrict__ bias, const float* __restrict__ dinv,
                            __half* __restrict__ ts_out, const int* __restrict__ batch,
                            float* __restrict__ g, int n) {
    __shared__ float sW[FI * H];
    for (int t = threadIdx.x; t < FI * H; t += blockDim.x) sW[t] = W[t];
    __syncthreads();
    int i = blockIdx.x * 16 + (threadIdx.x >> 4);
    int k = threadIdx.x & 15;
    if (i >= n) return;
    float acc = bias[k];
#pragma unroll
    for (int j = 0; j < FI; j++) acc = fmaf(agg[i * FI + j], sW[j * H + k], acc);
    float h = fmaxf(acc, 0.0f);
    if (POOL) {
        atomicAdd(&g[batch[i] * H + k], h);
    } else {
        ts_out[i * H + k] = __float2half(dinv[i] * h);
    }
}

// ---------------- final MLP ----------------

__global__ void k_mlp(const float* __restrict__ g, const float* __restrict__ y,
                      const float* __restrict__ fcW1, const float* __restrict__ fcb1,
                      const float* __restrict__ fcW2, const float* __restrict__ fcb2,
                      const float* __restrict__ fcW3, const float* __restrict__ fcb3,
                      float* __restrict__ out, int ngraph) {
    int i = blockIdx.x * blockDim.x + threadIdx.x;
    if (i >= ngraph) return;
    float in[H + 4];
#pragma unroll
    for (int k = 0; k < H; k++) in[k] = g[i * H + k];
#pragma unroll
    for (int k = 0; k < 4; k++) in[H + k] = y[i * 4 + k];
    float z1[H];
#pragma unroll
    for (int o = 0; o < H; o++) {
        float a = fcb1[o];
#pragma unroll
        for (int j = 0; j < H + 4; j++) a += in[j] * fcW1[j * H + o];
        z1[o] = fmaxf(a, 0.0f);
    }
    float z2[H];
#pragma unroll
    for (int o = 0; o < H; o++) {
        float a = fcb2[o];
#pragma unroll
        for (int j = 0; j < H; j++) a += z1[j] * fcW2[j * H + o];
        z2[o] = fmaxf(a, 0.0f);
    }
    float a = fcb3[0];
#pragma unroll
    for (int j = 0; j < H; j++) a += z2[j] * fcW3[j];
    out[i] = a;
}

// ---------------- launch ----------------

extern "C" void kernel_launch(void* const* d_in, const int* in_sizes, int n_in,
                              void* d_out, int out_size, void* d_ws, size_t ws_size,
                              hipStream_t stream) {
    const float* x    = (const float*)d_in[0];
    const int*   ei   = (const int*)d_in[1];   // [2, E]: src then dst
    const float* y    = (const float*)d_in[2];
    const int*   bat  = (const int*)d_in[3];
    const float* W1   = (const float*)d_in[4];
    const float* b1   = (const float*)d_in[5];
    const float* W2   = (const float*)d_in[6];
    const float* b2   = (const float*)d_in[7];
    const float* W3   = (const float*)d_in[8];
    const float* b3   = (const float*)d_in[9];
    const float* fcW1 = (const float*)d_in[10];
    const float* fcb1 = (const float*)d_in[11];
    const float* fcW2 = (const float*)d_in[12];
    const float* fcb2 = (const float*)d_in[13];
    const float* fcW3 = (const float*)d_in[14];
    const float* fcb3 = (const float*)d_in[15];
    float* out = (float*)d_out;

    const int* src = ei;
    const int* dst = ei + N_EDGES;

    const int B = 256;
    const int GH = N_GRAPHS * H;
    const int gNode16 = (N_NODES + 15) / 16;        // transform: 16 nodes/block
    const int gG4  = (N_NODES + 15) / 16;           // F=4,W=8: L=16, 16 nodes/block
    const int gG16 = (N_NODES + 7) / 8;             // F=16,W=4: L=32, 8 nodes/block

    // ---- workspace layout ----
    char* w = (char*)d_ws;
    size_t off = 0;
    int*    bucketCnt    = (int*)(w + off);    off += (size_t)NB * 4;
    int*    bucketBase   = (int*)(w + off);    off += (size_t)NB * 4;
    int*    blkCnt       = (int*)(w + off);    off += (size_t)NBLK * NB * 4;
    int*    blkBase      = (int*)(w + off);    off += (size_t)NBLK * NB * 4;
    int*    cursor       = (int*)(w + off);    off += (size_t)N_NODES * 4;
    float*  dinv         = (float*)(w + off);  off += (size_t)N_NODES * 4;
    int*    ebuf         = (int*)(w + off);    off += (size_t)N_EDGES * 4;
    int*    csr          = (int*)(w + off);    off += (size_t)N_EDGES * 4;
    __half* ts0          = (__half*)(w + off); off += (size_t)N_NODES * F_IN * 2;
    __half* ts1          = (__half*)(w + off); off += (size_t)N_NODES * H * 2;
    __half* ts2          = (__half*)(w + off); off += (size_t)N_NODES * H * 2;
    float*  agg          = (float*)(w + off);  off += (size_t)N_NODES * H * 4;
    float*  g            = (float*)(w + off);  off += (size_t)GH * 4;
    (void)ws_size;

    // ---- build (deterministic, zero global atomics, coalesced writes) ----
    k_count<<<NBLK, 512, 0, stream>>>(dst, blkCnt, N_EDGES);
    k_colscan<<<NB, 1024, 0, stream>>>(blkCnt, blkBase, bucketCnt);
    k_scan_buckets<<<1, NB, 0, stream>>>(bucketCnt, bucketBase);
    k_place<<<NBLK, 512, 0, stream>>>(src, dst, bucketBase, blkBase, ebuf, N_EDGES);
    k_csrify<<<NB, 1024, 0, stream>>>(ebuf, bucketBase, bucketCnt, x, csr, cursor,
                                      dinv, ts0);

    // ---- layer 1: gather x' (4 features), transform 4->16 ----
    k_gather<F_IN, 8><<<gG4, B, 0, stream>>>(ts0, dinv, csr, cursor, agg, N_NODES);
    k_transform<F_IN, false><<<gNode16, B, 0, stream>>>(agg, W1, b1, dinv, ts1,
                                                        nullptr, nullptr, N_NODES);
    // ---- layer 2 ----
    k_gather<H, 4><<<gG16, B, 0, stream>>>(ts1, dinv, csr, cursor, agg, N_NODES);
    k_transform<H, false><<<gNode16, B, 0, stream>>>(agg, W2, b2, dinv, ts2,
                                                     nullptr, nullptr, N_NODES);
    // ---- layer 3 + fused pool ----
    k_gather<H, 4><<<gG16, B, 0, stream>>>(ts2, dinv, csr, cursor, agg, N_NODES);
    k_zero_f<<<(GH + B - 1) / B, B, 0, stream>>>(g, GH);
    k_transform<H, true><<<gNode16, B, 0, stream>>>(agg, W3, b3, dinv, nullptr,
                                                    bat, g, N_NODES);

    // ---- final MLP ----
    k_mlp<<<(N_GRAPHS + B - 1) / B, B, 0, stream>>>(g, y, fcW1, fcb1, fcW2, fcb2,
                                                    fcW3, fcb3, out, N_GRAPHS);
}

// Round 12
// 187.654 us; speedup vs baseline: 3.8986x; 1.0489x over previous
//
#include <hip/hip_runtime.h>
#include <hip/hip_fp16.h>

#define N_NODES 100000
#define N_EDGES 3200000
#define N_GRAPHS 1024
#define F_IN 4
#define H 16

#define NB 256       // dst buckets
#define NPB 391      // nodes per bucket (256*391 = 100096 >= 100000)
#define CAP 13312    // per-bucket LDS fast-path capacity (mean 12512, sigma ~112)
#define CHUNK 4096   // edges per chunk in count/place
#define NBLK ((N_EDGES + CHUNK - 1) / CHUNK)   // 782
#define BEPT (CHUNK / 512)                     // 8 edges per thread in k_place
#define EPT_C ((CAP + 1023) / 1024)            // 13 edges per thread in k_csrify

// ---------------- helpers ----------------

__device__ __forceinline__ int lane_id() { return threadIdx.x & 63; }

__device__ __forceinline__ int wave_incl_scan(int v) {
#pragma unroll
    for (int d = 1; d < 64; d <<= 1) {
        int x = __shfl_up(v, d, 64);
        if (lane_id() >= d) v += x;
    }
    return v;
}

// ---------------- tiny utility kernels ----------------

__global__ void k_zero_f(float* __restrict__ p, int n) {
    int i = blockIdx.x * blockDim.x + threadIdx.x;
    if (i < n) p[i] = 0.0f;
}

// ---------------- deterministic bucketed edge partition ----------------

// per-chunk LDS histogram of dst buckets -> coalesced blkCnt row
__global__ __launch_bounds__(512) void k_count(const int* __restrict__ dst,
                                               int* __restrict__ blkCnt, int e) {
    __shared__ int h[NB];
    int t = threadIdx.x;
    for (int q = t; q < NB; q += 512) h[q] = 0;
    __syncthreads();
    int e0 = blockIdx.x * CHUNK;
    int e1 = min(e0 + CHUNK, e);
    for (int i = e0 + t; i < e1; i += 512)
        atomicAdd(&h[dst[i] / NPB], 1);
    __syncthreads();
    for (int q = t; q < NB; q += 512) blkCnt[blockIdx.x * NB + q] = h[q];
}

// one block per bucket: exclusive prefix over chunks -> blkBase; total -> bucketCnt
__global__ __launch_bounds__(1024) void k_colscan(const int* __restrict__ blkCnt,
                                                  int* __restrict__ blkBase,
                                                  int* __restrict__ bucketCnt) {
    __shared__ int ws[16];
    __shared__ int wb[16];
    int b = blockIdx.x;
    int t = threadIdx.x;
    int v = (t < NBLK) ? blkCnt[t * NB + b] : 0;
    int incl = wave_incl_scan(v);
    if (lane_id() == 63) ws[t >> 6] = incl;
    __syncthreads();
    if (t == 0) {
        int acc = 0;
#pragma unroll
        for (int q = 0; q < 16; ++q) { wb[q] = acc; acc += ws[q]; }
    }
    __syncthreads();
    int excl = incl - v + wb[t >> 6];
    if (t < NBLK) blkBase[t * NB + b] = excl;
    if (t == NBLK - 1) bucketCnt[b] = excl + v;
}

// exclusive scan of NB bucket totals; one block of NB threads
__global__ void k_scan_buckets(const int* __restrict__ bucketCnt,
                               int* __restrict__ bucketBase) {
    __shared__ int ws[4];
    __shared__ int wb[4];
    int t = threadIdx.x;
    int v = bucketCnt[t];
    int incl = wave_incl_scan(v);
    if (lane_id() == 63) ws[t >> 6] = incl;
    __syncthreads();
    if (t == 0) {
        int acc = 0;
#pragma unroll
        for (int q = 0; q < 4; ++q) { wb[q] = acc; acc += ws[q]; }
    }
    __syncthreads();
    bucketBase[t] = incl - v + wb[t >> 6];
}

// deterministic place with LDS sort: scatter happens in LDS, global writes
// are coalesced runs. payload: (local_dst << 20) | src
__global__ __launch_bounds__(512) void k_place(const int* __restrict__ src,
                                               const int* __restrict__ dst,
                                               const int* __restrict__ bucketBase,
                                               const int* __restrict__ blkBase,
                                               int* __restrict__ ebuf, int e) {
    __shared__ int cnt[NB];
    __shared__ int st[NB];
    __shared__ int lbase[NB];
    __shared__ int ws[4];
    __shared__ int wb[4];
    __shared__ int lsort[CHUNK];
    __shared__ unsigned short bof[CHUNK];
    int t = threadIdx.x;
    for (int q = t; q < NB; q += 512) {
        cnt[q] = 0;
        lbase[q] = bucketBase[q] + blkBase[blockIdx.x * NB + q];
    }
    __syncthreads();
    int e0 = blockIdx.x * CHUNK;
    int e1 = min(e0 + CHUNK, e);
    int m = e1 - e0;
    // phase 1: load + rank (one LDS atomic per edge)
    int vq[BEPT], bq[BEPT], rq[BEPT];
#pragma unroll
    for (int q = 0; q < BEPT; ++q) {
        int i = e0 + t + q * 512;
        bq[q] = -1;
        if (i < e) {
            int s = src[i];
            int d = dst[i];
            int b = d / NPB;
            int l = d - b * NPB;
            vq[q] = s | (l << 20);
            bq[q] = b;
            rq[q] = atomicAdd(&cnt[b], 1);
        }
    }
    __syncthreads();
    // phase 2: exclusive scan of cnt -> st (wave shfl scan, 2 barriers)
    int v = (t < NB) ? cnt[t] : 0;
    int incl = wave_incl_scan(v);
    if (t < NB && lane_id() == 63) ws[t >> 6] = incl;
    __syncthreads();
    if (t == 0) {
        int acc = 0;
#pragma unroll
        for (int q = 0; q < 4; ++q) { wb[q] = acc; acc += ws[q]; }
    }
    __syncthreads();
    if (t < NB) st[t] = incl - v + wb[t >> 6];
    __syncthreads();
    // phase 3: scatter into LDS-sorted order
#pragma unroll
    for (int q = 0; q < BEPT; ++q) {
        if (bq[q] >= 0) {
            int pos = st[bq[q]] + rq[q];
            lsort[pos] = vq[q];
            bof[pos] = (unsigned short)bq[q];
        }
    }
    __syncthreads();
    // phase 4: coalesced flush (consecutive lanes -> consecutive addrs per run)
    for (int i = t; i < m; i += 512) {
        int b2 = bof[i];
        ebuf[lbase[b2] + i - st[b2]] = lsort[i];
    }
}

// one block per bucket: group by node -> coalesced CSR + cursor + dinv + ts0.
// Register-staged fast path: ONE LDS atomic per edge; wave-shfl scan.
__global__ __launch_bounds__(1024) void k_csrify(const int* __restrict__ ebuf,
                                                 const int* __restrict__ bucketBase,
                                                 const int* __restrict__ bucketCnt,
                                                 const float* __restrict__ x,
                                                 int* __restrict__ csr,
                                                 int* __restrict__ cursor,
                                                 float* __restrict__ dinv,
                                                 __half* __restrict__ ts0) {
    __shared__ int cnt[NPB];
    __shared__ int st[NPB];
    __shared__ int cnt2[NPB];
    __shared__ float sdv[NPB];
    __shared__ int ws[8];
    __shared__ int wb[8];
    __shared__ int lcsr[CAP];
    int t = threadIdx.x;
    int b = blockIdx.x;
    int base = bucketBase[b];
    int m = bucketCnt[b];
    int nbase = b * NPB;
    for (int q = t; q < NPB; q += 1024) { cnt[q] = 0; cnt2[q] = 0; }
    __syncthreads();

    bool fast = (m <= CAP);
    int vq[EPT_C], rq[EPT_C];
    if (fast) {
#pragma unroll
        for (int c = 0; c < EPT_C; ++c) {
            int idx = t + c * 1024;
            vq[c] = -1;
            if (idx < m) {
                int v = ebuf[base + idx];
                vq[c] = v;
                rq[c] = atomicAdd(&cnt[v >> 20], 1);
            }
        }
    } else {
        for (int i = t; i < m; i += 1024)
            atomicAdd(&cnt[ebuf[base + i] >> 20], 1);
    }
    __syncthreads();
    // exclusive scan of cnt[NPB] via wave shfl scan (waves 0-6 hold elements)
    int v0 = (t < NPB) ? cnt[t] : 0;
    int incl = wave_incl_scan(v0);
    if (t < 448 && lane_id() == 63) ws[t >> 6] = incl;
    __syncthreads();
    if (t == 0) {
        int acc = 0;
#pragma unroll
        for (int q = 0; q < 7; ++q) { wb[q] = acc; acc += ws[q]; }
    }
    __syncthreads();
    if (t < NPB) {
        int s = incl - v0 + wb[t >> 6];
        st[t] = s;
        int node = nbase + t;
        if (node < N_NODES) {
            float dv = rsqrtf((float)cnt[t] + 1.0f);
            sdv[t] = dv;
            dinv[node] = dv;
            cursor[node] = base + s + cnt[t];
        }
    }
    __syncthreads();
    // prescale layer-1 input: ts0 = half(dinv * x)
    for (int idx = t; idx < NPB * F_IN; idx += 1024) {
        int q = idx >> 2;
        int node = nbase + q;
        if (node < N_NODES)
            ts0[node * F_IN + (idx & 3)] =
                __float2half(sdv[q] * x[node * F_IN + (idx & 3)]);
    }
    // place
    if (fast) {
#pragma unroll
        for (int c = 0; c < EPT_C; ++c) {
            int v = vq[c];
            if (v >= 0) lcsr[st[v >> 20] + rq[c]] = v & 0xFFFFF;
        }
        __syncthreads();
        for (int i = t; i < m; i += 1024) csr[base + i] = lcsr[i];
    } else {
        for (int i = t; i < m; i += 1024) {
            int v = ebuf[base + i];
            int l = v >> 20;
            int r = atomicAdd(&cnt2[l], 1);
            csr[base + st[l] + r] = v & 0xFFFFF;
        }
    }
}

// ---------------- CSR gather (F=4): half2 loads, 8-way edge split ----------------
template <int F, int WAYS>
__global__ void k_gather(const __half* __restrict__ ts, const float* __restrict__ dinv,
                         const int* __restrict__ csr, const int* __restrict__ cursor,
                         float* __restrict__ agg, int n) {
    const int FP = F / 2;            // feature pairs
    const int L = FP * WAYS;         // lanes per node
    int i = blockIdx.x * (256 / L) + threadIdx.x / L;
    int g = threadIdx.x % L;
    int k2 = g % FP;                 // feature-pair index
    int w = g / FP;                  // edge way
    if (i >= n) return;
    int start = (i == 0) ? 0 : cursor[i - 1];
    int end = cursor[i];
    float ax0 = 0.f, ay0 = 0.f, ax1 = 0.f, ay1 = 0.f;
    int j = start + w;
    for (; j + WAYS < end; j += 2 * WAYS) {
        int s0 = csr[j];
        int s1 = csr[j + WAYS];
        float2 f0 = __half22float2(*(const __half2*)&ts[s0 * F + 2 * k2]);
        float2 f1 = __half22float2(*(const __half2*)&ts[s1 * F + 2 * k2]);
        ax0 += f0.x; ay0 += f0.y;
        ax1 += f1.x; ay1 += f1.y;
    }
    for (; j < end; j += WAYS) {
        float2 f = __half22float2(*(const __half2*)&ts[csr[j] * F + 2 * k2]);
        ax0 += f.x; ay0 += f.y;
    }
    float sx = ax0 + ax1;
    float sy = ay0 + ay1;
    if (w == 0) {  // self-loop term
        float2 f = __half22float2(*(const __half2*)&ts[i * F + 2 * k2]);
        sx += f.x; sy += f.y;
    }
#pragma unroll
    for (int msk = FP; msk < L; msk <<= 1) {
        sx += __shfl_xor(sx, msk, 64);
        sy += __shfl_xor(sy, msk, 64);
    }
    if (w == 0) {
        float dv = dinv[i];
        *(float2*)&agg[i * F + 2 * k2] = make_float2(dv * sx, dv * sy);
    }
}

// ---------------- CSR gather (F=16): 8B half4 loads, 8-way edge split ----------------
// 32 lanes/node: 4 feature-quad lanes x 8 ways. agg = dinv*(self + sum ts[src]).
union h4u { float2 f2; __half2 h2[2]; };

__global__ void k_gather16(const __half* __restrict__ ts, const float* __restrict__ dinv,
                           const int* __restrict__ csr, const int* __restrict__ cursor,
                           float* __restrict__ agg, int n) {
    int i = blockIdx.x * 8 + threadIdx.x / 32;
    int g = threadIdx.x & 31;
    int k4 = g & 3;                  // feature quad (4 features)
    int w = g >> 2;                  // edge way (0..7)
    if (i >= n) return;
    int start = (i == 0) ? 0 : cursor[i - 1];
    int end = cursor[i];
    float ax0 = 0.f, ay0 = 0.f, az0 = 0.f, aw0 = 0.f;
    float ax1 = 0.f, ay1 = 0.f, az1 = 0.f, aw1 = 0.f;
    int j = start + w;
    for (; j + 8 < end; j += 16) {
        int s0 = csr[j];
        int s1 = csr[j + 8];
        h4u u0, u1;
        u0.f2 = *(const float2*)&ts[s0 * H + 4 * k4];
        u1.f2 = *(const float2*)&ts[s1 * H + 4 * k4];
        float2 l0 = __half22float2(u0.h2[0]);
        float2 h0 = __half22float2(u0.h2[1]);
        float2 l1 = __half22float2(u1.h2[0]);
        float2 h1 = __half22float2(u1.h2[1]);
        ax0 += l0.x; ay0 += l0.y; az0 += h0.x; aw0 += h0.y;
        ax1 += l1.x; ay1 += l1.y; az1 += h1.x; aw1 += h1.y;
    }
    for (; j < end; j += 8) {
        h4u u;
        u.f2 = *(const float2*)&ts[csr[j] * H + 4 * k4];
        float2 l = __half22float2(u.h2[0]);
        float2 h = __half22float2(u.h2[1]);
        ax0 += l.x; ay0 += l.y; az0 += h.x; aw0 += h.y;
    }
    float sx = ax0 + ax1, sy = ay0 + ay1, sz = az0 + az1, sw = aw0 + aw1;
    if (w == 0) {  // self-loop term
        h4u u;
        u.f2 = *(const float2*)&ts[i * H + 4 * k4];
        float2 l = __half22float2(u.h2[0]);
        float2 h = __half22float2(u.h2[1]);
        sx += l.x; sy += l.y; sz += h.x; sw += h.y;
    }
#pragma unroll
    for (int msk = 4; msk < 32; msk <<= 1) {
        sx += __shfl_xor(sx, msk, 64);
        sy += __shfl_xor(sy, msk, 64);
        sz += __shfl_xor(sz, msk, 64);
        sw += __shfl_xor(sw, msk, 64);
    }
    if (w == 0) {
        float dv = dinv[i];
        *(float4*)&agg[i * H + 4 * k4] = make_float4(dv * sx, dv * sy, dv * sz, dv * sw);
    }
}

// ---------------- per-node transform: h = relu(agg @ W + b) ----------------
// 16 lanes per node. Non-pool: ts_out = half(dinv*h). Pool: g[batch[i]] += h.
template <int FI, bool POOL>
__global__ void k_transform(const float* __restrict__ agg, const float* __restrict__ W,
                            const float* __restrict__ bias, const float* __restrict__ dinv,
                            __half* __restrict__ ts_out, const int* __restrict__ batch,
                            float* __restrict__ g, int n) {
    __shared__ float sW[FI * H];
    for (int t = threadIdx.x; t < FI * H; t += blockDim.x) sW[t] = W[t];
    __syncthreads();
    int i = blockIdx.x * 16 + (threadIdx.x >> 4);
    int k = threadIdx.x & 15;
    if (i >= n) return;
    float acc = bias[k];
#pragma unroll
    for (int j = 0; j < FI; j++) acc = fmaf(agg[i * FI + j], sW[j * H + k], acc);
    float h = fmaxf(acc, 0.0f);
    if (POOL) {
        atomicAdd(&g[batch[i] * H + k], h);
    } else {
        ts_out[i * H + k] = __float2half(dinv[i] * h);
    }
}

// ---------------- final MLP ----------------

__global__ void k_mlp(const float* __restrict__ g, const float* __restrict__ y,
                      const float* __restrict__ fcW1, const float* __restrict__ fcb1,
                      const float* __restrict__ fcW2, const float* __restrict__ fcb2,
                      const float* __restrict__ fcW3, const float* __restrict__ fcb3,
                      float* __restrict__ out, int ngraph) {
    int i = blockIdx.x * blockDim.x + threadIdx.x;
    if (i >= ngraph) return;
    float in[H + 4];
#pragma unroll
    for (int k = 0; k < H; k++) in[k] = g[i * H + k];
#pragma unroll
    for (int k = 0; k < 4; k++) in[H + k] = y[i * 4 + k];
    float z1[H];
#pragma unroll
    for (int o = 0; o < H; o++) {
        float a = fcb1[o];
#pragma unroll
        for (int j = 0; j < H + 4; j++) a += in[j] * fcW1[j * H + o];
        z1[o] = fmaxf(a, 0.0f);
    }
    float z2[H];
#pragma unroll
    for (int o = 0; o < H; o++) {
        float a = fcb2[o];
#pragma unroll
        for (int j = 0; j < H; j++) a += z1[j] * fcW2[j * H + o];
        z2[o] = fmaxf(a, 0.0f);
    }
    float a = fcb3[0];
#pragma unroll
    for (int j = 0; j < H; j++) a += z2[j] * fcW3[j];
    out[i] = a;
}

// ---------------- launch ----------------

extern "C" void kernel_launch(void* const* d_in, const int* in_sizes, int n_in,
                              void* d_out, int out_size, void* d_ws, size_t ws_size,
                              hipStream_t stream) {
    const float* x    = (const float*)d_in[0];
    const int*   ei   = (const int*)d_in[1];   // [2, E]: src then dst
    const float* y    = (const float*)d_in[2];
    const int*   bat  = (const int*)d_in[3];
    const float* W1   = (const float*)d_in[4];
    const float* b1   = (const float*)d_in[5];
    const float* W2   = (const float*)d_in[6];
    const float* b2   = (const float*)d_in[7];
    const float* W3   = (const float*)d_in[8];
    const float* b3   = (const float*)d_in[9];
    const float* fcW1 = (const float*)d_in[10];
    const float* fcb1 = (const float*)d_in[11];
    const float* fcW2 = (const float*)d_in[12];
    const float* fcb2 = (const float*)d_in[13];
    const float* fcW3 = (const float*)d_in[14];
    const float* fcb3 = (const float*)d_in[15];
    float* out = (float*)d_out;

    const int* src = ei;
    const int* dst = ei + N_EDGES;

    const int B = 256;
    const int GH = N_GRAPHS * H;
    const int gNode16 = (N_NODES + 15) / 16;        // transform: 16 nodes/block
    const int gG4  = (N_NODES + 15) / 16;           // F=4,W=8: L=16, 16 nodes/block
    const int gG16 = (N_NODES + 7) / 8;             // gather16: 8 nodes/block

    // ---- workspace layout ----
    char* w = (char*)d_ws;
    size_t off = 0;
    int*    bucketCnt    = (int*)(w + off);    off += (size_t)NB * 4;
    int*    bucketBase   = (int*)(w + off);    off += (size_t)NB * 4;
    int*    blkCnt       = (int*)(w + off);    off += (size_t)NBLK * NB * 4;
    int*    blkBase      = (int*)(w + off);    off += (size_t)NBLK * NB * 4;
    int*    cursor       = (int*)(w + off);    off += (size_t)N_NODES * 4;
    float*  dinv         = (float*)(w + off);  off += (size_t)N_NODES * 4;
    int*    ebuf         = (int*)(w + off);    off += (size_t)N_EDGES * 4;
    int*    csr          = (int*)(w + off);    off += (size_t)N_EDGES * 4;
    __half* ts0          = (__half*)(w + off); off += (size_t)N_NODES * F_IN * 2;
    __half* ts1          = (__half*)(w + off); off += (size_t)N_NODES * H * 2;
    __half* ts2          = (__half*)(w + off); off += (size_t)N_NODES * H * 2;
    float*  agg          = (float*)(w + off);  off += (size_t)N_NODES * H * 4;
    float*  g            = (float*)(w + off);  off += (size_t)GH * 4;
    (void)ws_size;

    // ---- build (deterministic, zero global atomics, coalesced writes) ----
    k_count<<<NBLK, 512, 0, stream>>>(dst, blkCnt, N_EDGES);
    k_colscan<<<NB, 1024, 0, stream>>>(blkCnt, blkBase, bucketCnt);
    k_scan_buckets<<<1, NB, 0, stream>>>(bucketCnt, bucketBase);
    k_place<<<NBLK, 512, 0, stream>>>(src, dst, bucketBase, blkBase, ebuf, N_EDGES);
    k_csrify<<<NB, 1024, 0, stream>>>(ebuf, bucketBase, bucketCnt, x, csr, cursor,
                                      dinv, ts0);

    // ---- layer 1: gather x' (4 features), transform 4->16 ----
    k_gather<F_IN, 8><<<gG4, B, 0, stream>>>(ts0, dinv, csr, cursor, agg, N_NODES);
    k_transform<F_IN, false><<<gNode16, B, 0, stream>>>(agg, W1, b1, dinv, ts1,
                                                        nullptr, nullptr, N_NODES);
    // ---- layer 2 ----
    k_gather16<<<gG16, B, 0, stream>>>(ts1, dinv, csr, cursor, agg, N_NODES);
    k_transform<H, false><<<gNode16, B, 0, stream>>>(agg, W2, b2, dinv, ts2,
                                                     nullptr, nullptr, N_NODES);
    // ---- layer 3 + fused pool ----
    k_gather16<<<gG16, B, 0, stream>>>(ts2, dinv, csr, cursor, agg, N_NODES);
    k_zero_f<<<(GH + B - 1) / B, B, 0, stream>>>(g, GH);
    k_transform<H, true><<<gNode16, B, 0, stream>>>(agg, W3, b3, dinv, nullptr,
                                                    bat, g, N_NODES);

    // ---- final MLP ----
    k_mlp<<<(N_GRAPHS + B - 1) / B, B, 0, stream>>>(g, y, fcW1, fcb1, fcW2, fcb2,
                                                    fcW3, fcb3, out, N_GRAPHS);
}

// Round 13
// 185.598 us; speedup vs baseline: 3.9418x; 1.0111x over previous
//
#include <hip/hip_runtime.h>
#include <hip/hip_fp16.h>

#define N_NODES 100000
#define N_EDGES 3200000
#define N_GRAPHS 1024
#define F_IN 4
#define H 16

#define NB 256       // dst buckets
#define NPB 391      // nodes per bucket (256*391 = 100096 >= 100000)
#define CAP 13312    // per-bucket LDS fast-path capacity (mean 12512, sigma ~112)
#define CHUNK 4096   // edges per chunk in count/place
#define NBLK ((N_EDGES + CHUNK - 1) / CHUNK)   // 782
#define BEPT (CHUNK / 512)                     // 8 edges per thread in k_place
#define EPT_C ((CAP + 1023) / 1024)            // 13 edges per thread in k_csrify

// ---------------- helpers ----------------

__device__ __forceinline__ int lane_id() { return threadIdx.x & 63; }

__device__ __forceinline__ int wave_incl_scan(int v) {
#pragma unroll
    for (int d = 1; d < 64; d <<= 1) {
        int x = __shfl_up(v, d, 64);
        if (lane_id() >= d) v += x;
    }
    return v;
}

union h4u { float2 f2; __half2 h2[2]; };
union h8u { float4 f4; __half2 h2[4]; };

// ---------------- tiny utility kernels ----------------

__global__ void k_zero_f(float* __restrict__ p, int n) {
    int i = blockIdx.x * blockDim.x + threadIdx.x;
    if (i < n) p[i] = 0.0f;
}

// ---------------- deterministic bucketed edge partition ----------------

__global__ __launch_bounds__(512) void k_count(const int* __restrict__ dst,
                                               int* __restrict__ blkCnt, int e) {
    __shared__ int h[NB];
    int t = threadIdx.x;
    for (int q = t; q < NB; q += 512) h[q] = 0;
    __syncthreads();
    int e0 = blockIdx.x * CHUNK;
    int e1 = min(e0 + CHUNK, e);
    for (int i = e0 + t; i < e1; i += 512)
        atomicAdd(&h[dst[i] / NPB], 1);
    __syncthreads();
    for (int q = t; q < NB; q += 512) blkCnt[blockIdx.x * NB + q] = h[q];
}

__global__ __launch_bounds__(1024) void k_colscan(const int* __restrict__ blkCnt,
                                                  int* __restrict__ blkBase,
                                                  int* __restrict__ bucketCnt) {
    __shared__ int ws[16];
    __shared__ int wb[16];
    int b = blockIdx.x;
    int t = threadIdx.x;
    int v = (t < NBLK) ? blkCnt[t * NB + b] : 0;
    int incl = wave_incl_scan(v);
    if (lane_id() == 63) ws[t >> 6] = incl;
    __syncthreads();
    if (t == 0) {
        int acc = 0;
#pragma unroll
        for (int q = 0; q < 16; ++q) { wb[q] = acc; acc += ws[q]; }
    }
    __syncthreads();
    int excl = incl - v + wb[t >> 6];
    if (t < NBLK) blkBase[t * NB + b] = excl;
    if (t == NBLK - 1) bucketCnt[b] = excl + v;
}

__global__ void k_scan_buckets(const int* __restrict__ bucketCnt,
                               int* __restrict__ bucketBase) {
    __shared__ int ws[4];
    __shared__ int wb[4];
    int t = threadIdx.x;
    int v = bucketCnt[t];
    int incl = wave_incl_scan(v);
    if (lane_id() == 63) ws[t >> 6] = incl;
    __syncthreads();
    if (t == 0) {
        int acc = 0;
#pragma unroll
        for (int q = 0; q < 4; ++q) { wb[q] = acc; acc += ws[q]; }
    }
    __syncthreads();
    bucketBase[t] = incl - v + wb[t >> 6];
}

// deterministic place with LDS sort; payload: (local_dst << 20) | src
__global__ __launch_bounds__(512) void k_place(const int* __restrict__ src,
                                               const int* __restrict__ dst,
                                               const int* __restrict__ bucketBase,
                                               const int* __restrict__ blkBase,
                                               int* __restrict__ ebuf, int e) {
    __shared__ int cnt[NB];
    __shared__ int st[NB];
    __shared__ int lbase[NB];
    __shared__ int ws[4];
    __shared__ int wb[4];
    __shared__ int lsort[CHUNK];
    __shared__ unsigned short bof[CHUNK];
    int t = threadIdx.x;
    for (int q = t; q < NB; q += 512) {
        cnt[q] = 0;
        lbase[q] = bucketBase[q] + blkBase[blockIdx.x * NB + q];
    }
    __syncthreads();
    int e0 = blockIdx.x * CHUNK;
    int e1 = min(e0 + CHUNK, e);
    int m = e1 - e0;
    int vq[BEPT], bq[BEPT], rq[BEPT];
#pragma unroll
    for (int q = 0; q < BEPT; ++q) {
        int i = e0 + t + q * 512;
        bq[q] = -1;
        if (i < e) {
            int s = src[i];
            int d = dst[i];
            int b = d / NPB;
            int l = d - b * NPB;
            vq[q] = s | (l << 20);
            bq[q] = b;
            rq[q] = atomicAdd(&cnt[b], 1);
        }
    }
    __syncthreads();
    int v = (t < NB) ? cnt[t] : 0;
    int incl = wave_incl_scan(v);
    if (t < NB && lane_id() == 63) ws[t >> 6] = incl;
    __syncthreads();
    if (t == 0) {
        int acc = 0;
#pragma unroll
        for (int q = 0; q < 4; ++q) { wb[q] = acc; acc += ws[q]; }
    }
    __syncthreads();
    if (t < NB) st[t] = incl - v + wb[t >> 6];
    __syncthreads();
#pragma unroll
    for (int q = 0; q < BEPT; ++q) {
        if (bq[q] >= 0) {
            int pos = st[bq[q]] + rq[q];
            lsort[pos] = vq[q];
            bof[pos] = (unsigned short)bq[q];
        }
    }
    __syncthreads();
    for (int i = t; i < m; i += 512) {
        int b2 = bof[i];
        ebuf[lbase[b2] + i - st[b2]] = lsort[i];
    }
}

// one block per bucket: group by node -> coalesced CSR + cursor + dinv + ts0.
__global__ __launch_bounds__(1024) void k_csrify(const int* __restrict__ ebuf,
                                                 const int* __restrict__ bucketBase,
                                                 const int* __restrict__ bucketCnt,
                                                 const float* __restrict__ x,
                                                 int* __restrict__ csr,
                                                 int* __restrict__ cursor,
                                                 float* __restrict__ dinv,
                                                 __half* __restrict__ ts0) {
    __shared__ int cnt[NPB];
    __shared__ int st[NPB];
    __shared__ int cnt2[NPB];
    __shared__ float sdv[NPB];
    __shared__ int ws[8];
    __shared__ int wb[8];
    __shared__ int lcsr[CAP];
    int t = threadIdx.x;
    int b = blockIdx.x;
    int base = bucketBase[b];
    int m = bucketCnt[b];
    int nbase = b * NPB;
    for (int q = t; q < NPB; q += 1024) { cnt[q] = 0; cnt2[q] = 0; }
    __syncthreads();

    bool fast = (m <= CAP);
    int vq[EPT_C], rq[EPT_C];
    if (fast) {
#pragma unroll
        for (int c = 0; c < EPT_C; ++c) {
            int idx = t + c * 1024;
            vq[c] = -1;
            if (idx < m) {
                int v = ebuf[base + idx];
                vq[c] = v;
                rq[c] = atomicAdd(&cnt[v >> 20], 1);
            }
        }
    } else {
        for (int i = t; i < m; i += 1024)
            atomicAdd(&cnt[ebuf[base + i] >> 20], 1);
    }
    __syncthreads();
    int v0 = (t < NPB) ? cnt[t] : 0;
    int incl = wave_incl_scan(v0);
    if (t < 448 && lane_id() == 63) ws[t >> 6] = incl;
    __syncthreads();
    if (t == 0) {
        int acc = 0;
#pragma unroll
        for (int q = 0; q < 7; ++q) { wb[q] = acc; acc += ws[q]; }
    }
    __syncthreads();
    if (t < NPB) {
        int s = incl - v0 + wb[t >> 6];
        st[t] = s;
        int node = nbase + t;
        if (node < N_NODES) {
            float dv = rsqrtf((float)cnt[t] + 1.0f);
            sdv[t] = dv;
            dinv[node] = dv;
            cursor[node] = base + s + cnt[t];
        }
    }
    __syncthreads();
    for (int idx = t; idx < NPB * F_IN; idx += 1024) {
        int q = idx >> 2;
        int node = nbase + q;
        if (node < N_NODES)
            ts0[node * F_IN + (idx & 3)] =
                __float2half(sdv[q] * x[node * F_IN + (idx & 3)]);
    }
    if (fast) {
#pragma unroll
        for (int c = 0; c < EPT_C; ++c) {
            int v = vq[c];
            if (v >= 0) lcsr[st[v >> 20] + rq[c]] = v & 0xFFFFF;
        }
        __syncthreads();
        for (int i = t; i < m; i += 1024) csr[base + i] = lcsr[i];
    } else {
        for (int i = t; i < m; i += 1024) {
            int v = ebuf[base + i];
            int l = v >> 20;
            int r = atomicAdd(&cnt2[l], 1);
            csr[base + st[l] + r] = v & 0xFFFFF;
        }
    }
}

// ---------------- fused layer 1: gather(F=4) + transform 4->16 via LDS ----------------
// 16 nodes/block; gather: 16 lanes/node (2 feat-pair x 8 ways); transform: 256 thr.
__global__ __launch_bounds__(256) void k_fused1(const __half* __restrict__ ts,
                                                const float* __restrict__ dinv,
                                                const int* __restrict__ csr,
                                                const int* __restrict__ cursor,
                                                const float* __restrict__ W,
                                                const float* __restrict__ bias,
                                                __half* __restrict__ ts_out, int n) {
    __shared__ float sW[F_IN * H];
    __shared__ float sagg[16][F_IN];
    __shared__ float sdv[16];
    int t = threadIdx.x;
    if (t < F_IN * H) sW[t] = W[t];
    int i0 = blockIdx.x * 16;
    int i = i0 + t / 16;
    int g = t & 15;
    int k2 = g & 1;
    int w = g >> 1;
    if (i < n) {
        int start = (i == 0) ? 0 : cursor[i - 1];
        int end = cursor[i];
        float ax0 = 0.f, ay0 = 0.f, ax1 = 0.f, ay1 = 0.f;
        int j = start + w;
        for (; j + 8 < end; j += 16) {
            int s0 = csr[j];
            int s1 = csr[j + 8];
            float2 f0 = __half22float2(*(const __half2*)&ts[s0 * F_IN + 2 * k2]);
            float2 f1 = __half22float2(*(const __half2*)&ts[s1 * F_IN + 2 * k2]);
            ax0 += f0.x; ay0 += f0.y;
            ax1 += f1.x; ay1 += f1.y;
        }
        for (; j < end; j += 8) {
            float2 f = __half22float2(*(const __half2*)&ts[csr[j] * F_IN + 2 * k2]);
            ax0 += f.x; ay0 += f.y;
        }
        float sx = ax0 + ax1;
        float sy = ay0 + ay1;
        if (w == 0) {
            float2 f = __half22float2(*(const __half2*)&ts[i * F_IN + 2 * k2]);
            sx += f.x; sy += f.y;
        }
#pragma unroll
        for (int msk = 2; msk < 16; msk <<= 1) {
            sx += __shfl_xor(sx, msk, 64);
            sy += __shfl_xor(sy, msk, 64);
        }
        if (w == 0) {
            float dv = dinv[i];
            int nl = t / 16;
            sagg[nl][2 * k2] = dv * sx;
            sagg[nl][2 * k2 + 1] = dv * sy;
            if (k2 == 0) sdv[nl] = dv;
        }
    }
    __syncthreads();
    // transform: 16 nodes x 16 outputs
    int nl = t >> 4;
    int k = t & 15;
    int node = i0 + nl;
    if (node < n) {
        float acc = bias[k];
#pragma unroll
        for (int j = 0; j < F_IN; j++) acc = fmaf(sagg[nl][j], sW[j * H + k], acc);
        float h = fmaxf(acc, 0.0f);
        ts_out[node * H + k] = __float2half(sdv[nl] * h);
    }
}

// ---------------- fused layer (F=16): gather (16B loads) + transform via LDS ----------------
// 8 nodes/block; gather: 32 lanes/node (2 feat-oct x 16 ways); transform: 128 thr.
template <bool POOL>
__global__ __launch_bounds__(256) void k_fused16(const __half* __restrict__ ts,
                                                 const float* __restrict__ dinv,
                                                 const int* __restrict__ csr,
                                                 const int* __restrict__ cursor,
                                                 const float* __restrict__ W,
                                                 const float* __restrict__ bias,
                                                 __half* __restrict__ ts_out,
                                                 const int* __restrict__ batch,
                                                 float* __restrict__ g, int n) {
    __shared__ float sW[H * H];
    __shared__ float sagg[8][H];
    __shared__ float sdv[8];
    int t = threadIdx.x;
    sW[t] = W[t];
    int i0 = blockIdx.x * 8;
    int i = i0 + t / 32;
    int lg = t & 31;
    int k8 = lg & 1;                 // feature-oct (8 features, 16B)
    int w = lg >> 1;                 // edge way (0..15)
    if (i < n) {
        int start = (i == 0) ? 0 : cursor[i - 1];
        int end = cursor[i];
        float a[8] = {0.f, 0.f, 0.f, 0.f, 0.f, 0.f, 0.f, 0.f};
        float b2[8] = {0.f, 0.f, 0.f, 0.f, 0.f, 0.f, 0.f, 0.f};
        int j = start + w;
        for (; j + 16 < end; j += 32) {
            int s0 = csr[j];
            int s1 = csr[j + 16];
            h8u u0, u1;
            u0.f4 = *(const float4*)&ts[s0 * H + 8 * k8];
            u1.f4 = *(const float4*)&ts[s1 * H + 8 * k8];
#pragma unroll
            for (int q = 0; q < 4; ++q) {
                float2 f0 = __half22float2(u0.h2[q]);
                float2 f1 = __half22float2(u1.h2[q]);
                a[2 * q] += f0.x; a[2 * q + 1] += f0.y;
                b2[2 * q] += f1.x; b2[2 * q + 1] += f1.y;
            }
        }
        for (; j < end; j += 16) {
            h8u u;
            u.f4 = *(const float4*)&ts[csr[j] * H + 8 * k8];
#pragma unroll
            for (int q = 0; q < 4; ++q) {
                float2 f = __half22float2(u.h2[q]);
                a[2 * q] += f.x; a[2 * q + 1] += f.y;
            }
        }
#pragma unroll
        for (int q = 0; q < 8; ++q) a[q] += b2[q];
        if (w == 0) {  // self-loop term
            h8u u;
            u.f4 = *(const float4*)&ts[i * H + 8 * k8];
#pragma unroll
            for (int q = 0; q < 4; ++q) {
                float2 f = __half22float2(u.h2[q]);
                a[2 * q] += f.x; a[2 * q + 1] += f.y;
            }
        }
#pragma unroll
        for (int msk = 2; msk < 32; msk <<= 1) {
#pragma unroll
            for (int q = 0; q < 8; ++q) a[q] += __shfl_xor(a[q], msk, 64);
        }
        if (w == 0) {
            float dv = dinv[i];
            int nl = t / 32;
#pragma unroll
            for (int q = 0; q < 8; ++q) sagg[nl][8 * k8 + q] = dv * a[q];
            if (k8 == 0) sdv[nl] = dv;
        }
    }
    __syncthreads();
    // transform: 8 nodes x 16 outputs on threads 0..127
    if (t < 128) {
        int nl = t >> 4;
        int k = t & 15;
        int node = i0 + nl;
        if (node < n) {
            float acc = bias[k];
#pragma unroll
            for (int j = 0; j < H; j++) acc = fmaf(sagg[nl][j], sW[j * H + k], acc);
            float h = fmaxf(acc, 0.0f);
            if (POOL) {
                atomicAdd(&g[batch[node] * H + k], h);
            } else {
                ts_out[node * H + k] = __float2half(sdv[nl] * h);
            }
        }
    }
}

// ---------------- final MLP ----------------

__global__ void k_mlp(const float* __restrict__ g, const float* __restrict__ y,
                      const float* __restrict__ fcW1, const float* __restrict__ fcb1,
                      const float* __restrict__ fcW2, const float* __restrict__ fcb2,
                      const float* __restrict__ fcW3, const float* __restrict__ fcb3,
                      float* __restrict__ out, int ngraph) {
    int i = blockIdx.x * blockDim.x + threadIdx.x;
    if (i >= ngraph) return;
    float in[H + 4];
#pragma unroll
    for (int k = 0; k < H; k++) in[k] = g[i * H + k];
#pragma unroll
    for (int k = 0; k < 4; k++) in[H + k] = y[i * 4 + k];
    float z1[H];
#pragma unroll
    for (int o = 0; o < H; o++) {
        float a = fcb1[o];
#pragma unroll
        for (int j = 0; j < H + 4; j++) a += in[j] * fcW1[j * H + o];
        z1[o] = fmaxf(a, 0.0f);
    }
    float z2[H];
#pragma unroll
    for (int o = 0; o < H; o++) {
        float a = fcb2[o];
#pragma unroll
        for (int j = 0; j < H; j++) a += z1[j] * fcW2[j * H + o];
        z2[o] = fmaxf(a, 0.0f);
    }
    float a = fcb3[0];
#pragma unroll
    for (int j = 0; j < H; j++) a += z2[j] * fcW3[j];
    out[i] = a;
}

// ---------------- launch ----------------

extern "C" void kernel_launch(void* const* d_in, const int* in_sizes, int n_in,
                              void* d_out, int out_size, void* d_ws, size_t ws_size,
                              hipStream_t stream) {
    const float* x    = (const float*)d_in[0];
    const int*   ei   = (const int*)d_in[1];   // [2, E]: src then dst
    const float* y    = (const float*)d_in[2];
    const int*   bat  = (const int*)d_in[3];
    const float* W1   = (const float*)d_in[4];
    const float* b1   = (const float*)d_in[5];
    const float* W2   = (const float*)d_in[6];
    const float* b2   = (const float*)d_in[7];
    const float* W3   = (const float*)d_in[8];
    const float* b3   = (const float*)d_in[9];
    const float* fcW1 = (const float*)d_in[10];
    const float* fcb1 = (const float*)d_in[11];
    const float* fcW2 = (const float*)d_in[12];
    const float* fcb2 = (const float*)d_in[13];
    const float* fcW3 = (const float*)d_in[14];
    const float* fcb3 = (const float*)d_in[15];
    float* out = (float*)d_out;

    const int* src = ei;
    const int* dst = ei + N_EDGES;

    const int B = 256;
    const int GH = N_GRAPHS * H;
    const int gF1  = (N_NODES + 15) / 16;   // fused1: 16 nodes/block
    const int gF16 = (N_NODES + 7) / 8;     // fused16: 8 nodes/block

    // ---- workspace layout ----
    char* w = (char*)d_ws;
    size_t off = 0;
    int*    bucketCnt    = (int*)(w + off);    off += (size_t)NB * 4;
    int*    bucketBase   = (int*)(w + off);    off += (size_t)NB * 4;
    int*    blkCnt       = (int*)(w + off);    off += (size_t)NBLK * NB * 4;
    int*    blkBase      = (int*)(w + off);    off += (size_t)NBLK * NB * 4;
    int*    cursor       = (int*)(w + off);    off += (size_t)N_NODES * 4;
    float*  dinv         = (float*)(w + off);  off += (size_t)N_NODES * 4;
    int*    ebuf         = (int*)(w + off);    off += (size_t)N_EDGES * 4;
    int*    csr          = (int*)(w + off);    off += (size_t)N_EDGES * 4;
    __half* ts0          = (__half*)(w + off); off += (size_t)N_NODES * F_IN * 2;
    __half* ts1          = (__half*)(w + off); off += (size_t)N_NODES * H * 2;
    __half* ts2          = (__half*)(w + off); off += (size_t)N_NODES * H * 2;
    float*  g            = (float*)(w + off);  off += (size_t)GH * 4;
    (void)ws_size;

    // ---- build (deterministic, zero global atomics, coalesced writes) ----
    k_count<<<NBLK, 512, 0, stream>>>(dst, blkCnt, N_EDGES);
    k_colscan<<<NB, 1024, 0, stream>>>(blkCnt, blkBase, bucketCnt);
    k_scan_buckets<<<1, NB, 0, stream>>>(bucketCnt, bucketBase);
    k_place<<<NBLK, 512, 0, stream>>>(src, dst, bucketBase, blkBase, ebuf, N_EDGES);
    k_csrify<<<NB, 1024, 0, stream>>>(ebuf, bucketBase, bucketCnt, x, csr, cursor,
                                      dinv, ts0);

    // ---- fused layers ----
    k_fused1<<<gF1, B, 0, stream>>>(ts0, dinv, csr, cursor, W1, b1, ts1, N_NODES);
    k_fused16<false><<<gF16, B, 0, stream>>>(ts1, dinv, csr, cursor, W2, b2, ts2,
                                             nullptr, nullptr, N_NODES);
    k_zero_f<<<(GH + B - 1) / B, B, 0, stream>>>(g, GH);
    k_fused16<true><<<gF16, B, 0, stream>>>(ts2, dinv, csr, cursor, W3, b3, nullptr,
                                            bat, g, N_NODES);

    // ---- final MLP ----
    k_mlp<<<(N_GRAPHS + B - 1) / B, B, 0, stream>>>(g, y, fcW1, fcb1, fcW2, fcb2,
                                                    fcW3, fcb3, out, N_GRAPHS);
}

// Round 14
// 165.157 us; speedup vs baseline: 4.4296x; 1.1238x over previous
//
#include <hip/hip_runtime.h>
#include <hip/hip_fp16.h>

#define N_NODES 100000
#define N_EDGES 3200000
#define N_GRAPHS 1024
#define F_IN 4
#define H 16

#define NB 256       // dst buckets
#define NPB 391      // nodes per bucket (256*391 = 100096 >= 100000)
#define CAP 13312    // per-bucket LDS fast-path capacity (mean 12512, sigma ~112)
#define CHUNK 4096   // edges per chunk in count/place
#define NBLK ((N_EDGES + CHUNK - 1) / CHUNK)   // 782
#define BEPT (CHUNK / 512)                     // 8 edges per thread in k_place
#define EPT_C ((CAP + 1023) / 1024)            // 13 edges per thread in k_csrify

// ---------------- helpers ----------------

__device__ __forceinline__ int lane_id() { return threadIdx.x & 63; }

__device__ __forceinline__ int wave_incl_scan(int v) {
#pragma unroll
    for (int d = 1; d < 64; d <<= 1) {
        int x = __shfl_up(v, d, 64);
        if (lane_id() >= d) v += x;
    }
    return v;
}

union h4u { float2 f2; __half2 h2[2]; };
union h8u { float4 f4; __half2 h2[4]; };

// ---------------- deterministic bucketed edge partition ----------------

__global__ __launch_bounds__(512) void k_count(const int* __restrict__ dst,
                                               int* __restrict__ blkCnt, int e) {
    __shared__ int h[NB];
    int t = threadIdx.x;
    for (int q = t; q < NB; q += 512) h[q] = 0;
    __syncthreads();
    int e0 = blockIdx.x * CHUNK;
    int e1 = min(e0 + CHUNK, e);
    for (int i = e0 + t; i < e1; i += 512)
        atomicAdd(&h[dst[i] / NPB], 1);
    __syncthreads();
    for (int q = t; q < NB; q += 512) blkCnt[blockIdx.x * NB + q] = h[q];
}

// one block per bucket: exclusive prefix over chunks -> blkBase; total -> bucketCnt.
// Also zeroes the pool buffer g (16384 floats; 64 per block).
__global__ __launch_bounds__(1024) void k_colscan(const int* __restrict__ blkCnt,
                                                  int* __restrict__ blkBase,
                                                  int* __restrict__ bucketCnt,
                                                  float* __restrict__ g) {
    __shared__ int ws[16];
    __shared__ int wb[16];
    int b = blockIdx.x;
    int t = threadIdx.x;
    if (t < 64) g[b * 64 + t] = 0.0f;
    int v = (t < NBLK) ? blkCnt[t * NB + b] : 0;
    int incl = wave_incl_scan(v);
    if (lane_id() == 63) ws[t >> 6] = incl;
    __syncthreads();
    if (t == 0) {
        int acc = 0;
#pragma unroll
        for (int q = 0; q < 16; ++q) { wb[q] = acc; acc += ws[q]; }
    }
    __syncthreads();
    int excl = incl - v + wb[t >> 6];
    if (t < NBLK) blkBase[t * NB + b] = excl;
    if (t == NBLK - 1) bucketCnt[b] = excl + v;
}

// deterministic place with LDS sort; bucketBase computed inline from bucketCnt.
// payload: (local_dst << 20) | src
__global__ __launch_bounds__(512) void k_place(const int* __restrict__ src,
                                               const int* __restrict__ dst,
                                               const int* __restrict__ bucketCnt,
                                               const int* __restrict__ blkBase,
                                               int* __restrict__ ebuf, int e) {
    __shared__ int cnt[NB];
    __shared__ int st[NB];
    __shared__ int lbase[NB];
    __shared__ int ws[4];
    __shared__ int wb[4];
    __shared__ int lsort[CHUNK];
    __shared__ unsigned short bof[CHUNK];
    int t = threadIdx.x;
    for (int q = t; q < NB; q += 512) cnt[q] = 0;
    // inline exclusive scan of bucketCnt -> global bucket base
    int vb = (t < NB) ? bucketCnt[t] : 0;
    int ib = wave_incl_scan(vb);
    if (t < NB && lane_id() == 63) ws[t >> 6] = ib;
    __syncthreads();
    if (t == 0) {
        int acc = 0;
#pragma unroll
        for (int q = 0; q < 4; ++q) { wb[q] = acc; acc += ws[q]; }
    }
    __syncthreads();
    if (t < NB) lbase[t] = ib - vb + wb[t >> 6] + blkBase[blockIdx.x * NB + t];
    __syncthreads();
    int e0 = blockIdx.x * CHUNK;
    int e1 = min(e0 + CHUNK, e);
    int m = e1 - e0;
    // phase 1: load + rank (one LDS atomic per edge)
    int vq[BEPT], bq[BEPT], rq[BEPT];
#pragma unroll
    for (int q = 0; q < BEPT; ++q) {
        int i = e0 + t + q * 512;
        bq[q] = -1;
        if (i < e) {
            int s = src[i];
            int d = dst[i];
            int b = d / NPB;
            int l = d - b * NPB;
            vq[q] = s | (l << 20);
            bq[q] = b;
            rq[q] = atomicAdd(&cnt[b], 1);
        }
    }
    __syncthreads();
    // phase 2: exclusive scan of cnt -> st
    int v = (t < NB) ? cnt[t] : 0;
    int incl = wave_incl_scan(v);
    if (t < NB && lane_id() == 63) ws[t >> 6] = incl;
    __syncthreads();
    if (t == 0) {
        int acc = 0;
#pragma unroll
        for (int q = 0; q < 4; ++q) { wb[q] = acc; acc += ws[q]; }
    }
    __syncthreads();
    if (t < NB) st[t] = incl - v + wb[t >> 6];
    __syncthreads();
    // phase 3: scatter into LDS-sorted order
#pragma unroll
    for (int q = 0; q < BEPT; ++q) {
        if (bq[q] >= 0) {
            int pos = st[bq[q]] + rq[q];
            lsort[pos] = vq[q];
            bof[pos] = (unsigned short)bq[q];
        }
    }
    __syncthreads();
    // phase 4: coalesced flush
    for (int i = t; i < m; i += 512) {
        int b2 = bof[i];
        ebuf[lbase[b2] + i - st[b2]] = lsort[i];
    }
}

// one block per bucket: group by node -> coalesced CSR + cursor + dinv + ts0.
// bucketBase computed inline.
__global__ __launch_bounds__(1024) void k_csrify(const int* __restrict__ ebuf,
                                                 const int* __restrict__ bucketCnt,
                                                 const float* __restrict__ x,
                                                 int* __restrict__ csr,
                                                 int* __restrict__ cursor,
                                                 float* __restrict__ dinv,
                                                 __half* __restrict__ ts0) {
    __shared__ int cnt[NPB];
    __shared__ int st[NPB];
    __shared__ int cnt2[NPB];
    __shared__ float sdv[NPB];
    __shared__ int ws[8];
    __shared__ int wb[8];
    __shared__ int sbase;
    __shared__ int lcsr[CAP];
    int t = threadIdx.x;
    int b = blockIdx.x;
    int m = bucketCnt[b];
    int nbase = b * NPB;
    for (int q = t; q < NPB; q += 1024) { cnt[q] = 0; cnt2[q] = 0; }
    // inline bucket base: exclusive scan of bucketCnt, keep element b
    int vb = (t < NB) ? bucketCnt[t] : 0;
    int ibx = wave_incl_scan(vb);
    if (t < NB && lane_id() == 63) ws[t >> 6] = ibx;
    __syncthreads();
    if (t == 0) {
        int acc = 0;
#pragma unroll
        for (int q = 0; q < 4; ++q) { wb[q] = acc; acc += ws[q]; }
    }
    __syncthreads();
    if (t == b) sbase = ibx - vb + wb[t >> 6];
    __syncthreads();
    int base = sbase;

    bool fast = (m <= CAP);
    int vq[EPT_C], rq[EPT_C];
    if (fast) {
#pragma unroll
        for (int c = 0; c < EPT_C; ++c) {
            int idx = t + c * 1024;
            vq[c] = -1;
            if (idx < m) {
                int v = ebuf[base + idx];
                vq[c] = v;
                rq[c] = atomicAdd(&cnt[v >> 20], 1);
            }
        }
    } else {
        for (int i = t; i < m; i += 1024)
            atomicAdd(&cnt[ebuf[base + i] >> 20], 1);
    }
    __syncthreads();
    int v0 = (t < NPB) ? cnt[t] : 0;
    int incl = wave_incl_scan(v0);
    if (t < 448 && lane_id() == 63) ws[t >> 6] = incl;
    __syncthreads();
    if (t == 0) {
        int acc = 0;
#pragma unroll
        for (int q = 0; q < 7; ++q) { wb[q] = acc; acc += ws[q]; }
    }
    __syncthreads();
    if (t < NPB) {
        int s = incl - v0 + wb[t >> 6];
        st[t] = s;
        int node = nbase + t;
        if (node < N_NODES) {
            float dv = rsqrtf((float)cnt[t] + 1.0f);
            sdv[t] = dv;
            dinv[node] = dv;
            cursor[node] = base + s + cnt[t];
        }
    }
    __syncthreads();
    // prescale layer-1 input: ts0 = half(dinv * x)
    for (int idx = t; idx < NPB * F_IN; idx += 1024) {
        int q = idx >> 2;
        int node = nbase + q;
        if (node < N_NODES)
            ts0[node * F_IN + (idx & 3)] =
                __float2half(sdv[q] * x[node * F_IN + (idx & 3)]);
    }
    if (fast) {
#pragma unroll
        for (int c = 0; c < EPT_C; ++c) {
            int v = vq[c];
            if (v >= 0) lcsr[st[v >> 20] + rq[c]] = v & 0xFFFFF;
        }
        __syncthreads();
        for (int i = t; i < m; i += 1024) csr[base + i] = lcsr[i];
    } else {
        for (int i = t; i < m; i += 1024) {
            int v = ebuf[base + i];
            int l = v >> 20;
            int r = atomicAdd(&cnt2[l], 1);
            csr[base + st[l] + r] = v & 0xFFFFF;
        }
    }
}

// ---------------- fused layer 1: gather(F=4) + transform via LDS ----------------
// 64 nodes/block; 4 lanes/node = 4 edge ways, each lane loads full 8B rows,
// 4-deep unrolled independent loads.
__global__ __launch_bounds__(256) void k_fused1(const __half* __restrict__ ts,
                                                const float* __restrict__ dinv,
                                                const int* __restrict__ csr,
                                                const int* __restrict__ cursor,
                                                const float* __restrict__ W,
                                                const float* __restrict__ bias,
                                                __half* __restrict__ ts_out, int n) {
    __shared__ float sW[F_IN * H];
    __shared__ float sagg[64][F_IN];
    __shared__ float sdv[64];
    int t = threadIdx.x;
    if (t < F_IN * H) sW[t] = W[t];
    int i0 = blockIdx.x * 64;
    int i = i0 + (t >> 2);
    int w = t & 3;
    if (i < n) {
        int start = (i == 0) ? 0 : cursor[i - 1];
        int end = cursor[i];
        float a[F_IN] = {0.f, 0.f, 0.f, 0.f};
        float b[F_IN] = {0.f, 0.f, 0.f, 0.f};
        int j = start + w;
        for (; j + 12 < end; j += 16) {
            int s0 = csr[j];
            int s1 = csr[j + 4];
            int s2 = csr[j + 8];
            int s3 = csr[j + 12];
            h4u u0, u1, u2, u3;
            u0.f2 = *(const float2*)&ts[s0 * F_IN];
            u1.f2 = *(const float2*)&ts[s1 * F_IN];
            u2.f2 = *(const float2*)&ts[s2 * F_IN];
            u3.f2 = *(const float2*)&ts[s3 * F_IN];
#pragma unroll
            for (int q = 0; q < 2; ++q) {
                float2 f0 = __half22float2(u0.h2[q]);
                float2 f1 = __half22float2(u1.h2[q]);
                float2 f2 = __half22float2(u2.h2[q]);
                float2 f3 = __half22float2(u3.h2[q]);
                a[2 * q] += f0.x + f2.x; a[2 * q + 1] += f0.y + f2.y;
                b[2 * q] += f1.x + f3.x; b[2 * q + 1] += f1.y + f3.y;
            }
        }
        for (; j < end; j += 4) {
            h4u u;
            u.f2 = *(const float2*)&ts[csr[j] * F_IN];
#pragma unroll
            for (int q = 0; q < 2; ++q) {
                float2 f = __half22float2(u.h2[q]);
                a[2 * q] += f.x; a[2 * q + 1] += f.y;
            }
        }
#pragma unroll
        for (int q = 0; q < F_IN; ++q) a[q] += b[q];
        if (w == 0) {  // self-loop
            h4u u;
            u.f2 = *(const float2*)&ts[i * F_IN];
#pragma unroll
            for (int q = 0; q < 2; ++q) {
                float2 f = __half22float2(u.h2[q]);
                a[2 * q] += f.x; a[2 * q + 1] += f.y;
            }
        }
#pragma unroll
        for (int msk = 1; msk < 4; msk <<= 1) {
#pragma unroll
            for (int q = 0; q < F_IN; ++q) a[q] += __shfl_xor(a[q], msk, 64);
        }
        if (w == 0) {
            float dv = dinv[i];
            int nl = t >> 2;
#pragma unroll
            for (int q = 0; q < F_IN; ++q) sagg[nl][q] = dv * a[q];
            sdv[nl] = dv;
        }
    }
    __syncthreads();
    // transform: 64 nodes x 16 outputs
    for (int idx = t; idx < 64 * H; idx += 256) {
        int nl = idx >> 4;
        int k = idx & 15;
        int node = i0 + nl;
        if (node < n) {
            float acc = bias[k];
#pragma unroll
            for (int j = 0; j < F_IN; j++) acc = fmaf(sagg[nl][j], sW[j * H + k], acc);
            float h = fmaxf(acc, 0.0f);
            ts_out[node * H + k] = __float2half(sdv[nl] * h);
        }
    }
}

// ---------------- fused layer (F=16): gather + transform via LDS ----------------
// 32 nodes/block; 8 lanes/node = 2 feature-halves x 4 edge ways; 4-deep
// unrolled independent 16B loads per lane.
template <bool POOL>
__global__ __launch_bounds__(256) void k_fused16(const __half* __restrict__ ts,
                                                 const float* __restrict__ dinv,
                                                 const int* __restrict__ csr,
                                                 const int* __restrict__ cursor,
                                                 const float* __restrict__ W,
                                                 const float* __restrict__ bias,
                                                 __half* __restrict__ ts_out,
                                                 const int* __restrict__ batch,
                                                 float* __restrict__ g, int n) {
    __shared__ float sW[H * H];
    __shared__ float sagg[32][H];
    __shared__ float sdv[32];
    int t = threadIdx.x;
    sW[t] = W[t];
    int i0 = blockIdx.x * 32;
    int i = i0 + (t >> 3);
    int lg = t & 7;
    int k8 = lg & 1;                 // feature half (8 features = 16B)
    int w = lg >> 1;                 // edge way (0..3)
    if (i < n) {
        int start = (i == 0) ? 0 : cursor[i - 1];
        int end = cursor[i];
        float a[8] = {0.f, 0.f, 0.f, 0.f, 0.f, 0.f, 0.f, 0.f};
        float b[8] = {0.f, 0.f, 0.f, 0.f, 0.f, 0.f, 0.f, 0.f};
        int j = start + w;
        for (; j + 12 < end; j += 16) {
            int s0 = csr[j];
            int s1 = csr[j + 4];
            int s2 = csr[j + 8];
            int s3 = csr[j + 12];
            h8u u0, u1, u2, u3;
            u0.f4 = *(const float4*)&ts[s0 * H + 8 * k8];
            u1.f4 = *(const float4*)&ts[s1 * H + 8 * k8];
            u2.f4 = *(const float4*)&ts[s2 * H + 8 * k8];
            u3.f4 = *(const float4*)&ts[s3 * H + 8 * k8];
#pragma unroll
            for (int q = 0; q < 4; ++q) {
                float2 f0 = __half22float2(u0.h2[q]);
                float2 f1 = __half22float2(u1.h2[q]);
                float2 f2 = __half22float2(u2.h2[q]);
                float2 f3 = __half22float2(u3.h2[q]);
                a[2 * q] += f0.x + f2.x; a[2 * q + 1] += f0.y + f2.y;
                b[2 * q] += f1.x + f3.x; b[2 * q + 1] += f1.y + f3.y;
            }
        }
        for (; j < end; j += 4) {
            h8u u;
            u.f4 = *(const float4*)&ts[csr[j] * H + 8 * k8];
#pragma unroll
            for (int q = 0; q < 4; ++q) {
                float2 f = __half22float2(u.h2[q]);
                a[2 * q] += f.x; a[2 * q + 1] += f.y;
            }
        }
#pragma unroll
        for (int q = 0; q < 8; ++q) a[q] += b[q];
        if (w == 0) {  // self-loop
            h8u u;
            u.f4 = *(const float4*)&ts[i * H + 8 * k8];
#pragma unroll
            for (int q = 0; q < 4; ++q) {
                float2 f = __half22float2(u.h2[q]);
                a[2 * q] += f.x; a[2 * q + 1] += f.y;
            }
        }
#pragma unroll
        for (int msk = 2; msk < 8; msk <<= 1) {
#pragma unroll
            for (int q = 0; q < 8; ++q) a[q] += __shfl_xor(a[q], msk, 64);
        }
        if (w == 0) {
            float dv = dinv[i];
            int nl = t >> 3;
#pragma unroll
            for (int q = 0; q < 8; ++q) sagg[nl][8 * k8 + q] = dv * a[q];
            if (k8 == 0) sdv[nl] = dv;
        }
    }
    __syncthreads();
    // transform: 32 nodes x 16 outputs (2 passes over 256 threads)
    for (int idx = t; idx < 32 * H; idx += 256) {
        int nl = idx >> 4;
        int k = idx & 15;
        int node = i0 + nl;
        if (node < n) {
            float acc = bias[k];
#pragma unroll
            for (int j = 0; j < H; j++) acc = fmaf(sagg[nl][j], sW[j * H + k], acc);
            float h = fmaxf(acc, 0.0f);
            if (POOL) {
                atomicAdd(&g[batch[node] * H + k], h);
            } else {
                ts_out[node * H + k] = __float2half(sdv[nl] * h);
            }
        }
    }
}

// ---------------- final MLP ----------------

__global__ void k_mlp(const float* __restrict__ g, const float* __restrict__ y,
                      const float* __restrict__ fcW1, const float* __restrict__ fcb1,
                      const float* __restrict__ fcW2, const float* __restrict__ fcb2,
                      const float* __restrict__ fcW3, const float* __restrict__ fcb3,
                      float* __restrict__ out, int ngraph) {
    int i = blockIdx.x * blockDim.x + threadIdx.x;
    if (i >= ngraph) return;
    float in[H + 4];
#pragma unroll
    for (int k = 0; k < H; k++) in[k] = g[i * H + k];
#pragma unroll
    for (int k = 0; k < 4; k++) in[H + k] = y[i * 4 + k];
    float z1[H];
#pragma unroll
    for (int o = 0; o < H; o++) {
        float a = fcb1[o];
#pragma unroll
        for (int j = 0; j < H + 4; j++) a += in[j] * fcW1[j * H + o];
        z1[o] = fmaxf(a, 0.0f);
    }
    float z2[H];
#pragma unroll
    for (int o = 0; o < H; o++) {
        float a = fcb2[o];
#pragma unroll
        for (int j = 0; j < H; j++) a += z1[j] * fcW2[j * H + o];
        z2[o] = fmaxf(a, 0.0f);
    }
    float a = fcb3[0];
#pragma unroll
    for (int j = 0; j < H; j++) a += z2[j] * fcW3[j];
    out[i] = a;
}

// ---------------- launch ----------------

extern "C" void kernel_launch(void* const* d_in, const int* in_sizes, int n_in,
                              void* d_out, int out_size, void* d_ws, size_t ws_size,
                              hipStream_t stream) {
    const float* x    = (const float*)d_in[0];
    const int*   ei   = (const int*)d_in[1];   // [2, E]: src then dst
    const float* y    = (const float*)d_in[2];
    const int*   bat  = (const int*)d_in[3];
    const float* W1   = (const float*)d_in[4];
    const float* b1   = (const float*)d_in[5];
    const float* W2   = (const float*)d_in[6];
    const float* b2   = (const float*)d_in[7];
    const float* W3   = (const float*)d_in[8];
    const float* b3   = (const float*)d_in[9];
    const float* fcW1 = (const float*)d_in[10];
    const float* fcb1 = (const float*)d_in[11];
    const float* fcW2 = (const float*)d_in[12];
    const float* fcb2 = (const float*)d_in[13];
    const float* fcW3 = (const float*)d_in[14];
    const float* fcb3 = (const float*)d_in[15];
    float* out = (float*)d_out;

    const int* src = ei;
    const int* dst = ei + N_EDGES;

    const int B = 256;
    const int GH = N_GRAPHS * H;
    const int gF1  = (N_NODES + 63) / 64;   // fused1: 64 nodes/block
    const int gF16 = (N_NODES + 31) / 32;   // fused16: 32 nodes/block

    // ---- workspace layout ----
    char* w = (char*)d_ws;
    size_t off = 0;
    int*    bucketCnt    = (int*)(w + off);    off += (size_t)NB * 4;
    int*    blkCnt       = (int*)(w + off);    off += (size_t)NBLK * NB * 4;
    int*    blkBase      = (int*)(w + off);    off += (size_t)NBLK * NB * 4;
    int*    cursor       = (int*)(w + off);    off += (size_t)N_NODES * 4;
    float*  dinv         = (float*)(w + off);  off += (size_t)N_NODES * 4;
    int*    ebuf         = (int*)(w + off);    off += (size_t)N_EDGES * 4;
    int*    csr          = (int*)(w + off);    off += (size_t)N_EDGES * 4;
    __half* ts0          = (__half*)(w + off); off += (size_t)N_NODES * F_IN * 2;
    __half* ts1          = (__half*)(w + off); off += (size_t)N_NODES * H * 2;
    __half* ts2          = (__half*)(w + off); off += (size_t)N_NODES * H * 2;
    float*  g            = (float*)(w + off);  off += (size_t)GH * 4;
    (void)ws_size;

    // ---- build ----
    k_count<<<NBLK, 512, 0, stream>>>(dst, blkCnt, N_EDGES);
    k_colscan<<<NB, 1024, 0, stream>>>(blkCnt, blkBase, bucketCnt, g);
    k_place<<<NBLK, 512, 0, stream>>>(src, dst, bucketCnt, blkBase, ebuf, N_EDGES);
    k_csrify<<<NB, 1024, 0, stream>>>(ebuf, bucketCnt, x, csr, cursor, dinv, ts0);

    // ---- fused layers ----
    k_fused1<<<gF1, B, 0, stream>>>(ts0, dinv, csr, cursor, W1, b1, ts1, N_NODES);
    k_fused16<false><<<gF16, B, 0, stream>>>(ts1, dinv, csr, cursor, W2, b2, ts2,
                                             nullptr, nullptr, N_NODES);
    k_fused16<true><<<gF16, B, 0, stream>>>(ts2, dinv, csr, cursor, W3, b3, nullptr,
                                            bat, g, N_NODES);

    // ---- final MLP ----
    k_mlp<<<(N_GRAPHS + B - 1) / B, B, 0, stream>>>(g, y, fcW1, fcb1, fcW2, fcb2,
                                                    fcW3, fcb3, out, N_GRAPHS);
}

// Round 15
// 162.720 us; speedup vs baseline: 4.4960x; 1.0150x over previous
//
#include <hip/hip_runtime.h>
#include <hip/hip_fp16.h>

#define N_NODES 100000
#define N_EDGES 3200000
#define N_GRAPHS 1024
#define F_IN 4
#define H 16

#define NB 256       // dst buckets
#define NPB 391      // nodes per bucket (256*391 = 100096 >= 100000)
#define CAP 13312    // per-bucket LDS fast-path capacity (mean 12512, sigma ~112)
#define CHUNK 4096   // edges per chunk in count/place
#define NBLK ((N_EDGES + CHUNK - 1) / CHUNK)   // 782
#define BEPT (CHUNK / 512)                     // 8 edges per thread in k_place
#define EPT_C ((CAP + 1023) / 1024)            // 13 edges per thread in k_csrify

// ---------------- helpers ----------------

__device__ __forceinline__ int lane_id() { return threadIdx.x & 63; }

__device__ __forceinline__ int wave_incl_scan(int v) {
#pragma unroll
    for (int d = 1; d < 64; d <<= 1) {
        int x = __shfl_up(v, d, 64);
        if (lane_id() >= d) v += x;
    }
    return v;
}

union h4u { float2 f2; __half2 h2[2]; };
union h8u { float4 f4; __half2 h2[4]; };

// ---------------- deterministic bucketed edge partition ----------------

__global__ __launch_bounds__(512) void k_count(const int* __restrict__ dst,
                                               int* __restrict__ blkCnt, int e) {
    __shared__ int h[NB];
    int t = threadIdx.x;
    for (int q = t; q < NB; q += 512) h[q] = 0;
    __syncthreads();
    int e0 = blockIdx.x * CHUNK;
    int e1 = min(e0 + CHUNK, e);
    for (int i = e0 + t; i < e1; i += 512)
        atomicAdd(&h[dst[i] / NPB], 1);
    __syncthreads();
    for (int q = t; q < NB; q += 512) blkCnt[blockIdx.x * NB + q] = h[q];
}

// one block per bucket: exclusive prefix over chunks -> blkBase; total -> bucketCnt.
// Also zeroes the pool buffer g (16384 floats; 64 per block).
__global__ __launch_bounds__(1024) void k_colscan(const int* __restrict__ blkCnt,
                                                  int* __restrict__ blkBase,
                                                  int* __restrict__ bucketCnt,
                                                  float* __restrict__ g) {
    __shared__ int ws[16];
    __shared__ int wb[16];
    int b = blockIdx.x;
    int t = threadIdx.x;
    if (t < 64) g[b * 64 + t] = 0.0f;
    int v = (t < NBLK) ? blkCnt[t * NB + b] : 0;
    int incl = wave_incl_scan(v);
    if (lane_id() == 63) ws[t >> 6] = incl;
    __syncthreads();
    if (t == 0) {
        int acc = 0;
#pragma unroll
        for (int q = 0; q < 16; ++q) { wb[q] = acc; acc += ws[q]; }
    }
    __syncthreads();
    int excl = incl - v + wb[t >> 6];
    if (t < NBLK) blkBase[t * NB + b] = excl;
    if (t == NBLK - 1) bucketCnt[b] = excl + v;
}

// deterministic place with LDS sort; bucketBase computed inline from bucketCnt.
// payload: (local_dst << 20) | src
__global__ __launch_bounds__(512) void k_place(const int* __restrict__ src,
                                               const int* __restrict__ dst,
                                               const int* __restrict__ bucketCnt,
                                               const int* __restrict__ blkBase,
                                               int* __restrict__ ebuf, int e) {
    __shared__ int cnt[NB];
    __shared__ int st[NB];
    __shared__ int lbase[NB];
    __shared__ int ws[4];
    __shared__ int wb[4];
    __shared__ int lsort[CHUNK];
    __shared__ unsigned short bof[CHUNK];
    int t = threadIdx.x;
    for (int q = t; q < NB; q += 512) cnt[q] = 0;
    int vb = (t < NB) ? bucketCnt[t] : 0;
    int ib = wave_incl_scan(vb);
    if (t < NB && lane_id() == 63) ws[t >> 6] = ib;
    __syncthreads();
    if (t == 0) {
        int acc = 0;
#pragma unroll
        for (int q = 0; q < 4; ++q) { wb[q] = acc; acc += ws[q]; }
    }
    __syncthreads();
    if (t < NB) lbase[t] = ib - vb + wb[t >> 6] + blkBase[blockIdx.x * NB + t];
    __syncthreads();
    int e0 = blockIdx.x * CHUNK;
    int e1 = min(e0 + CHUNK, e);
    int m = e1 - e0;
    int vq[BEPT], bq[BEPT], rq[BEPT];
#pragma unroll
    for (int q = 0; q < BEPT; ++q) {
        int i = e0 + t + q * 512;
        bq[q] = -1;
        if (i < e) {
            int s = src[i];
            int d = dst[i];
            int b = d / NPB;
            int l = d - b * NPB;
            vq[q] = s | (l << 20);
            bq[q] = b;
            rq[q] = atomicAdd(&cnt[b], 1);
        }
    }
    __syncthreads();
    int v = (t < NB) ? cnt[t] : 0;
    int incl = wave_incl_scan(v);
    if (t < NB && lane_id() == 63) ws[t >> 6] = incl;
    __syncthreads();
    if (t == 0) {
        int acc = 0;
#pragma unroll
        for (int q = 0; q < 4; ++q) { wb[q] = acc; acc += ws[q]; }
    }
    __syncthreads();
    if (t < NB) st[t] = incl - v + wb[t >> 6];
    __syncthreads();
#pragma unroll
    for (int q = 0; q < BEPT; ++q) {
        if (bq[q] >= 0) {
            int pos = st[bq[q]] + rq[q];
            lsort[pos] = vq[q];
            bof[pos] = (unsigned short)bq[q];
        }
    }
    __syncthreads();
    for (int i = t; i < m; i += 512) {
        int b2 = bof[i];
        ebuf[lbase[b2] + i - st[b2]] = lsort[i];
    }
}

// one block per bucket: group by node -> coalesced CSR + cursor + dinv + ts0.
__global__ __launch_bounds__(1024) void k_csrify(const int* __restrict__ ebuf,
                                                 const int* __restrict__ bucketCnt,
                                                 const float* __restrict__ x,
                                                 int* __restrict__ csr,
                                                 int* __restrict__ cursor,
                                                 float* __restrict__ dinv,
                                                 __half* __restrict__ ts0) {
    __shared__ int cnt[NPB];
    __shared__ int st[NPB];
    __shared__ int cnt2[NPB];
    __shared__ float sdv[NPB];
    __shared__ int ws[8];
    __shared__ int wb[8];
    __shared__ int sbase;
    __shared__ int lcsr[CAP];
    int t = threadIdx.x;
    int b = blockIdx.x;
    int m = bucketCnt[b];
    int nbase = b * NPB;
    for (int q = t; q < NPB; q += 1024) { cnt[q] = 0; cnt2[q] = 0; }
    int vb = (t < NB) ? bucketCnt[t] : 0;
    int ibx = wave_incl_scan(vb);
    if (t < NB && lane_id() == 63) ws[t >> 6] = ibx;
    __syncthreads();
    if (t == 0) {
        int acc = 0;
#pragma unroll
        for (int q = 0; q < 4; ++q) { wb[q] = acc; acc += ws[q]; }
    }
    __syncthreads();
    if (t == b) sbase = ibx - vb + wb[t >> 6];
    __syncthreads();
    int base = sbase;

    bool fast = (m <= CAP);
    int vq[EPT_C], rq[EPT_C];
    if (fast) {
#pragma unroll
        for (int c = 0; c < EPT_C; ++c) {
            int idx = t + c * 1024;
            vq[c] = -1;
            if (idx < m) {
                int v = ebuf[base + idx];
                vq[c] = v;
                rq[c] = atomicAdd(&cnt[v >> 20], 1);
            }
        }
    } else {
        for (int i = t; i < m; i += 1024)
            atomicAdd(&cnt[ebuf[base + i] >> 20], 1);
    }
    __syncthreads();
    int v0 = (t < NPB) ? cnt[t] : 0;
    int incl = wave_incl_scan(v0);
    if (t < 448 && lane_id() == 63) ws[t >> 6] = incl;
    __syncthreads();
    if (t == 0) {
        int acc = 0;
#pragma unroll
        for (int q = 0; q < 7; ++q) { wb[q] = acc; acc += ws[q]; }
    }
    __syncthreads();
    if (t < NPB) {
        int s = incl - v0 + wb[t >> 6];
        st[t] = s;
        int node = nbase + t;
        if (node < N_NODES) {
            float dv = rsqrtf((float)cnt[t] + 1.0f);
            sdv[t] = dv;
            dinv[node] = dv;
            cursor[node] = base + s + cnt[t];
        }
    }
    __syncthreads();
    for (int idx = t; idx < NPB * F_IN; idx += 1024) {
        int q = idx >> 2;
        int node = nbase + q;
        if (node < N_NODES)
            ts0[node * F_IN + (idx & 3)] =
                __float2half(sdv[q] * x[node * F_IN + (idx & 3)]);
    }
    if (fast) {
#pragma unroll
        for (int c = 0; c < EPT_C; ++c) {
            int v = vq[c];
            if (v >= 0) lcsr[st[v >> 20] + rq[c]] = v & 0xFFFFF;
        }
        __syncthreads();
        for (int i = t; i < m; i += 1024) csr[base + i] = lcsr[i];
    } else {
        for (int i = t; i < m; i += 1024) {
            int v = ebuf[base + i];
            int l = v >> 20;
            int r = atomicAdd(&cnt2[l], 1);
            csr[base + st[l] + r] = v & 0xFFFFF;
        }
    }
}

// ---------------- fused layer 1: gather(F=4) + transform via LDS ----------------
// 32 nodes/block; 8 lanes/node = 8 edge ways, full 8B rows, 6-deep batch.
__global__ __launch_bounds__(256) void k_fused1(const __half* __restrict__ ts,
                                                const float* __restrict__ dinv,
                                                const int* __restrict__ csr,
                                                const int* __restrict__ cursor,
                                                const float* __restrict__ W,
                                                const float* __restrict__ bias,
                                                __half* __restrict__ ts_out, int n) {
    __shared__ float sW[F_IN * H];
    __shared__ float sagg[32][F_IN];
    __shared__ float sdv[32];
    int t = threadIdx.x;
    if (t < F_IN * H) sW[t] = W[t];
    int i0 = blockIdx.x * 32;
    int i = i0 + (t >> 3);
    int w = t & 7;
    if (i < n) {
        int start = (i == 0) ? 0 : cursor[i - 1];
        int end = cursor[i];
        float a[F_IN] = {0.f, 0.f, 0.f, 0.f};
        int j = start + w;
        // 6-deep predicated batch: all csr loads, then all feature loads
        int ss[6];
#pragma unroll
        for (int q = 0; q < 6; ++q) {
            int jj = j + 8 * q;
            ss[q] = (jj < end) ? csr[jj] : -1;
        }
        h4u u[6];
#pragma unroll
        for (int q = 0; q < 6; ++q)
            if (ss[q] >= 0) u[q].f2 = *(const float2*)&ts[ss[q] * F_IN];
#pragma unroll
        for (int q = 0; q < 6; ++q) {
            if (ss[q] >= 0) {
#pragma unroll
                for (int p = 0; p < 2; ++p) {
                    float2 f = __half22float2(u[q].h2[p]);
                    a[2 * p] += f.x; a[2 * p + 1] += f.y;
                }
            }
        }
        // rare tail (per-way deg > 6 <=> deg > 48)
        for (j += 48; j < end; j += 8) {
            h4u uu;
            uu.f2 = *(const float2*)&ts[csr[j] * F_IN];
#pragma unroll
            for (int p = 0; p < 2; ++p) {
                float2 f = __half22float2(uu.h2[p]);
                a[2 * p] += f.x; a[2 * p + 1] += f.y;
            }
        }
        if (w == 0) {  // self-loop
            h4u uu;
            uu.f2 = *(const float2*)&ts[i * F_IN];
#pragma unroll
            for (int p = 0; p < 2; ++p) {
                float2 f = __half22float2(uu.h2[p]);
                a[2 * p] += f.x; a[2 * p + 1] += f.y;
            }
        }
#pragma unroll
        for (int msk = 1; msk < 8; msk <<= 1) {
#pragma unroll
            for (int q = 0; q < F_IN; ++q) a[q] += __shfl_xor(a[q], msk, 64);
        }
        if (w == 0) {
            float dv = dinv[i];
            int nl = t >> 3;
#pragma unroll
            for (int q = 0; q < F_IN; ++q) sagg[nl][q] = dv * a[q];
            sdv[nl] = dv;
        }
    }
    __syncthreads();
    // transform: 32 nodes x 16 outputs (2 passes)
    for (int idx = t; idx < 32 * H; idx += 256) {
        int nl = idx >> 4;
        int k = idx & 15;
        int node = i0 + nl;
        if (node < n) {
            float acc = bias[k];
#pragma unroll
            for (int jj = 0; jj < F_IN; jj++) acc = fmaf(sagg[nl][jj], sW[jj * H + k], acc);
            float h = fmaxf(acc, 0.0f);
            ts_out[node * H + k] = __float2half(sdv[nl] * h);
        }
    }
}

// ---------------- fused layer (F=16): gather + transform via LDS ----------------
// 16 nodes/block; 16 lanes/node = 2 feature-halves x 8 edge ways; 6-deep
// predicated batch of independent 16B loads.
template <bool POOL>
__global__ __launch_bounds__(256) void k_fused16(const __half* __restrict__ ts,
                                                 const float* __restrict__ dinv,
                                                 const int* __restrict__ csr,
                                                 const int* __restrict__ cursor,
                                                 const float* __restrict__ W,
                                                 const float* __restrict__ bias,
                                                 __half* __restrict__ ts_out,
                                                 const int* __restrict__ batch,
                                                 float* __restrict__ g, int n) {
    __shared__ float sW[H * H];
    __shared__ float sagg[16][H];
    __shared__ float sdv[16];
    int t = threadIdx.x;
    sW[t] = W[t];
    int i0 = blockIdx.x * 16;
    int i = i0 + (t >> 4);
    int lg = t & 15;
    int k8 = lg & 1;                 // feature half (8 features = 16B)
    int w = lg >> 1;                 // edge way (0..7)
    if (i < n) {
        int start = (i == 0) ? 0 : cursor[i - 1];
        int end = cursor[i];
        float a[8] = {0.f, 0.f, 0.f, 0.f, 0.f, 0.f, 0.f, 0.f};
        int j = start + w;
        // 6-deep predicated batch
        int ss[6];
#pragma unroll
        for (int q = 0; q < 6; ++q) {
            int jj = j + 8 * q;
            ss[q] = (jj < end) ? csr[jj] : -1;
        }
        h8u u[6];
#pragma unroll
        for (int q = 0; q < 6; ++q)
            if (ss[q] >= 0) u[q].f4 = *(const float4*)&ts[ss[q] * H + 8 * k8];
#pragma unroll
        for (int q = 0; q < 6; ++q) {
            if (ss[q] >= 0) {
#pragma unroll
                for (int p = 0; p < 4; ++p) {
                    float2 f = __half22float2(u[q].h2[p]);
                    a[2 * p] += f.x; a[2 * p + 1] += f.y;
                }
            }
        }
        // rare tail (deg > 48)
        for (j += 48; j < end; j += 8) {
            h8u uu;
            uu.f4 = *(const float4*)&ts[csr[j] * H + 8 * k8];
#pragma unroll
            for (int p = 0; p < 4; ++p) {
                float2 f = __half22float2(uu.h2[p]);
                a[2 * p] += f.x; a[2 * p + 1] += f.y;
            }
        }
        if (w == 0) {  // self-loop
            h8u uu;
            uu.f4 = *(const float4*)&ts[i * H + 8 * k8];
#pragma unroll
            for (int p = 0; p < 4; ++p) {
                float2 f = __half22float2(uu.h2[p]);
                a[2 * p] += f.x; a[2 * p + 1] += f.y;
            }
        }
        // sum across the 8 ways (bits 1..3 of lg)
#pragma unroll
        for (int msk = 2; msk < 16; msk <<= 1) {
#pragma unroll
            for (int q = 0; q < 8; ++q) a[q] += __shfl_xor(a[q], msk, 64);
        }
        if (w == 0) {
            float dv = dinv[i];
            int nl = t >> 4;
#pragma unroll
            for (int q = 0; q < 8; ++q) sagg[nl][8 * k8 + q] = dv * a[q];
            if (k8 == 0) sdv[nl] = dv;
        }
    }
    __syncthreads();
    // transform: 16 nodes x 16 outputs
    int nl = t >> 4;
    int k = t & 15;
    int node = i0 + nl;
    if (node < n) {
        float acc = bias[k];
#pragma unroll
        for (int jj = 0; jj < H; jj++) acc = fmaf(sagg[nl][jj], sW[jj * H + k], acc);
        float h = fmaxf(acc, 0.0f);
        if (POOL) {
            atomicAdd(&g[batch[node] * H + k], h);
        } else {
            ts_out[node * H + k] = __float2half(sdv[nl] * h);
        }
    }
}

// ---------------- final MLP ----------------

__global__ void k_mlp(const float* __restrict__ g, const float* __restrict__ y,
                      const float* __restrict__ fcW1, const float* __restrict__ fcb1,
                      const float* __restrict__ fcW2, const float* __restrict__ fcb2,
                      const float* __restrict__ fcW3, const float* __restrict__ fcb3,
                      float* __restrict__ out, int ngraph) {
    int i = blockIdx.x * blockDim.x + threadIdx.x;
    if (i >= ngraph) return;
    float in[H + 4];
#pragma unroll
    for (int k = 0; k < H; k++) in[k] = g[i * H + k];
#pragma unroll
    for (int k = 0; k < 4; k++) in[H + k] = y[i * 4 + k];
    float z1[H];
#pragma unroll
    for (int o = 0; o < H; o++) {
        float a = fcb1[o];
#pragma unroll
        for (int j = 0; j < H + 4; j++) a += in[j] * fcW1[j * H + o];
        z1[o] = fmaxf(a, 0.0f);
    }
    float z2[H];
#pragma unroll
    for (int o = 0; o < H; o++) {
        float a = fcb2[o];
#pragma unroll
        for (int j = 0; j < H; j++) a += z1[j] * fcW2[j * H + o];
        z2[o] = fmaxf(a, 0.0f);
    }
    float a = fcb3[0];
#pragma unroll
    for (int j = 0; j < H; j++) a += z2[j] * fcW3[j];
    out[i] = a;
}

// ---------------- launch ----------------

extern "C" void kernel_launch(void* const* d_in, const int* in_sizes, int n_in,
                              void* d_out, int out_size, void* d_ws, size_t ws_size,
                              hipStream_t stream) {
    const float* x    = (const float*)d_in[0];
    const int*   ei   = (const int*)d_in[1];   // [2, E]: src then dst
    const float* y    = (const float*)d_in[2];
    const int*   bat  = (const int*)d_in[3];
    const float* W1   = (const float*)d_in[4];
    const float* b1   = (const float*)d_in[5];
    const float* W2   = (const float*)d_in[6];
    const float* b2   = (const float*)d_in[7];
    const float* W3   = (const float*)d_in[8];
    const float* b3   = (const float*)d_in[9];
    const float* fcW1 = (const float*)d_in[10];
    const float* fcb1 = (const float*)d_in[11];
    const float* fcW2 = (const float*)d_in[12];
    const float* fcb2 = (const float*)d_in[13];
    const float* fcW3 = (const float*)d_in[14];
    const float* fcb3 = (const float*)d_in[15];
    float* out = (float*)d_out;

    const int* src = ei;
    const int* dst = ei + N_EDGES;

    const int B = 256;
    const int GH = N_GRAPHS * H;
    const int gF1  = (N_NODES + 31) / 32;   // fused1: 32 nodes/block
    const int gF16 = (N_NODES + 15) / 16;   // fused16: 16 nodes/block

    // ---- workspace layout ----
    char* w = (char*)d_ws;
    size_t off = 0;
    int*    bucketCnt    = (int*)(w + off);    off += (size_t)NB * 4;
    int*    blkCnt       = (int*)(w + off);    off += (size_t)NBLK * NB * 4;
    int*    blkBase      = (int*)(w + off);    off += (size_t)NBLK * NB * 4;
    int*    cursor       = (int*)(w + off);    off += (size_t)N_NODES * 4;
    float*  dinv         = (float*)(w + off);  off += (size_t)N_NODES * 4;
    int*    ebuf         = (int*)(w + off);    off += (size_t)N_EDGES * 4;
    int*    csr          = (int*)(w + off);    off += (size_t)N_EDGES * 4;
    __half* ts0          = (__half*)(w + off); off += (size_t)N_NODES * F_IN * 2;
    __half* ts1          = (__half*)(w + off); off += (size_t)N_NODES * H * 2;
    __half* ts2          = (__half*)(w + off); off += (size_t)N_NODES * H * 2;
    float*  g            = (float*)(w + off);  off += (size_t)GH * 4;
    (void)ws_size;

    // ---- build ----
    k_count<<<NBLK, 512, 0, stream>>>(dst, blkCnt, N_EDGES);
    k_colscan<<<NB, 1024, 0, stream>>>(blkCnt, blkBase, bucketCnt, g);
    k_place<<<NBLK, 512, 0, stream>>>(src, dst, bucketCnt, blkBase, ebuf, N_EDGES);
    k_csrify<<<NB, 1024, 0, stream>>>(ebuf, bucketCnt, x, csr, cursor, dinv, ts0);

    // ---- fused layers ----
    k_fused1<<<gF1, B, 0, stream>>>(ts0, dinv, csr, cursor, W1, b1, ts1, N_NODES);
    k_fused16<false><<<gF16, B, 0, stream>>>(ts1, dinv, csr, cursor, W2, b2, ts2,
                                             nullptr, nullptr, N_NODES);
    k_fused16<true><<<gF16, B, 0, stream>>>(ts2, dinv, csr, cursor, W3, b3, nullptr,
                                            bat, g, N_NODES);

    // ---- final MLP ----
    k_mlp<<<(N_GRAPHS + B - 1) / B, B, 0, stream>>>(g, y, fcW1, fcb1, fcW2, fcb2,
                                                    fcW3, fcb3, out, N_GRAPHS);
}